// Round 1
// baseline (2798.164 us; speedup 1.0000x reference)
//
#include <hip/hip_runtime.h>
#include <stdint.h>

// ---------------------------------------------------------------------------
// Round 14: implicit-deform GEMM (k_mfma_dt). The B operand (im2col of the
// deform-sampled feature) is built inside the GEMM per K-step from per-block
// LDS sid/wgt tables instead of being materialized to HBM by k_im2col2.
// Removes ~1 GB/iter of cols round-trip traffic (FETCH_SIZE was 200 MB per
// big GEMM) and 6 im2col dispatches. A-path / MFMA / epilogue identical to
// the r12/r13-proven k_mfma_nt; sampling arithmetic identical to k_im2col2,
// so outputs are bit-identical. stsn x3, wxf deform, wx adaptive, s_net 1+2
// all routed through k_mfma_dt; encoders/branch/s3 keep im2col_g + gemm_sk.
// ---------------------------------------------------------------------------

typedef unsigned short ushort_t;
typedef __attribute__((ext_vector_type(8))) short bf16x8;
typedef __attribute__((ext_vector_type(4))) float f32x4;

#define BN 2
#define HH 48
#define WWD 48
#define HW 2304

__device__ __forceinline__ float b2f(ushort_t h) {
  union { uint32_t u; float f; } v; v.u = ((uint32_t)h) << 16; return v.f;
}
__device__ __forceinline__ ushort_t f2b(float f) {
  union { float f; uint32_t u; } v; v.f = f;
  uint32_t u = v.u;
  uint32_t r = (u + 0x7fffu + ((u >> 16) & 1u)) >> 16;
  return (ushort_t)r;
}
__device__ __forceinline__ void split_bf(float v, ushort_t& hi, ushort_t& lo) {
  hi = f2b(v);
  lo = f2b(v - b2f(hi));
}

// ---------------- elementwise / packing kernels ----------------------------

__global__ void k_split_xy(const float* __restrict__ in, float* __restrict__ xf,
                           float* __restrict__ yf) {
  int idx = blockIdx.x * blockDim.x + threadIdx.x;
  const int tot = BN * 256 * HW;
  if (idx >= tot) return;
  int b = idx / (256 * HW);
  int r = idx - b * (256 * HW);
  xf[idx] = in[(size_t)(2 * b) * (256 * HW) + r];
  yf[idx] = in[(size_t)(2 * b + 1) * (256 * HW) + r];
}

// batch-4 concat: feat4[bb] = concat(xy4[bb], xy4[2+(bb&1)])
__global__ void k_concat512_4(const float* __restrict__ xy4,
                              float* __restrict__ feat) {
  int idx = blockIdx.x * blockDim.x + threadIdx.x;
  const int tot = 4 * 512 * HW;
  if (idx >= tot) return;
  int bb = idx / (512 * HW);
  int r = idx - bb * (512 * HW);
  int c = r / HW;
  int n = r - c * HW;
  feat[idx] = (c < 256)
                  ? xy4[((size_t)bb * 256 + c) * HW + n]
                  : xy4[((size_t)(2 + (bb & 1)) * 256 + (c - 256)) * HW + n];
}

__global__ void k_relu(float* __restrict__ p, int n) {
  int idx = blockIdx.x * blockDim.x + threadIdx.x;
  if (idx < n) p[idx] = fmaxf(p[idx], 0.f);
}

__global__ void k_mean(const float* __restrict__ src, float* __restrict__ dst,
                       int Mtot, int N) {
  int idx = blockIdx.x * blockDim.x + threadIdx.x;
  if (idx >= Mtot) return;
  const float* p = src + (size_t)idx * N;
  float s = 0.f;
  for (int i = 0; i < N; ++i) s += p[i];
  dst[idx] = s / (float)N;
}

__global__ void k_w2b(const float* __restrict__ w, ushort_t* __restrict__ ohi,
                      ushort_t* __restrict__ olo, int n) {
  int idx = blockIdx.x * blockDim.x + threadIdx.x;
  if (idx < n) split_bf(w[idx], ohi[idx], olo[idx]);
}

// z-merged conversions (same element count per z)
__global__ void k_w2bz3(const float* __restrict__ p0, const float* __restrict__ p1,
                        const float* __restrict__ p2, ushort_t* __restrict__ h0,
                        ushort_t* __restrict__ h1, ushort_t* __restrict__ h2,
                        ushort_t* __restrict__ l0, ushort_t* __restrict__ l1,
                        ushort_t* __restrict__ l2, int n) {
  int idx = blockIdx.x * blockDim.x + threadIdx.x;
  if (idx >= n) return;
  int z = blockIdx.z;
  const float* p = (z == 0) ? p0 : (z == 1) ? p1 : p2;
  ushort_t* h = (z == 0) ? h0 : (z == 1) ? h1 : h2;
  ushort_t* l = (z == 0) ? l0 : (z == 1) ? l1 : l2;
  split_bf(p[idx], h[idx], l[idx]);
}

__global__ void k_w2bz4(const float* __restrict__ p0, const float* __restrict__ p1,
                        const float* __restrict__ p2, const float* __restrict__ p3,
                        ushort_t* __restrict__ h0, ushort_t* __restrict__ h1,
                        ushort_t* __restrict__ h2, ushort_t* __restrict__ h3,
                        ushort_t* __restrict__ l0, ushort_t* __restrict__ l1,
                        ushort_t* __restrict__ l2, ushort_t* __restrict__ l3,
                        int n) {
  int idx = blockIdx.x * blockDim.x + threadIdx.x;
  if (idx >= n) return;
  int z = blockIdx.z;
  const float* p = (z == 0) ? p0 : (z == 1) ? p1 : (z == 2) ? p2 : p3;
  ushort_t* h = (z == 0) ? h0 : (z == 1) ? h1 : (z == 2) ? h2 : h3;
  ushort_t* l = (z == 0) ? l0 : (z == 1) ? l1 : (z == 2) ? l2 : l3;
  split_bf(p[idx], h[idx], l[idx]);
}

__global__ void k_w2b_pad(const float* __restrict__ w, ushort_t* __restrict__ ohi,
                          ushort_t* __restrict__ olo, int M, int K, int Kpad) {
  int idx = blockIdx.x * blockDim.x + threadIdx.x;
  if (idx >= M * Kpad) return;
  int m = idx / Kpad, k = idx - m * Kpad;
  float v = (k < K) ? w[(size_t)m * K + k] : 0.f;
  split_bf(v, ohi[idx], olo[idx]);
}

__global__ void k_w2b_padz2(const float* __restrict__ p0, const float* __restrict__ p1,
                            ushort_t* __restrict__ h0, ushort_t* __restrict__ h1,
                            ushort_t* __restrict__ l0, ushort_t* __restrict__ l1,
                            int M0, int M1, int K, int Kpad) {
  int idx = blockIdx.x * blockDim.x + threadIdx.x;
  int z = blockIdx.z;
  int M = z ? M1 : M0;
  if (idx >= M * Kpad) return;
  int m = idx / Kpad, k = idx - m * Kpad;
  const float* w = z ? p1 : p0;
  ushort_t* h = z ? h1 : h0;
  ushort_t* l = z ? l1 : l0;
  float v = (k < K) ? w[(size_t)m * K + k] : 0.f;
  split_bf(v, h[idx], l[idx]);
}

__global__ void k_w2b_fw(const float* __restrict__ w, const float* __restrict__ wb,
                         const float* __restrict__ fw, ushort_t* __restrict__ ohi,
                         ushort_t* __restrict__ olo, int M, int K, int NB) {
  int idx = blockIdx.x * blockDim.x + threadIdx.x;
  int tot = NB * M * K;
  if (idx >= tot) return;
  int b = idx / (M * K);
  int r = idx - b * (M * K);
  int m = r / K;
  split_bf(fw[b * M + m] * w[r] + wb[r], ohi[idx], olo[idx]);
}

__global__ void k_w2b_fw_pad(const float* __restrict__ w, const float* __restrict__ wb,
                             const float* __restrict__ fw, ushort_t* __restrict__ ohi,
                             ushort_t* __restrict__ olo, int M, int K, int Kpad,
                             int NB) {
  int idx = blockIdx.x * blockDim.x + threadIdx.x;
  int tot = NB * M * Kpad;
  if (idx >= tot) return;
  int b = idx / (M * Kpad);
  int r = idx - b * (M * Kpad);
  int m = r / Kpad;
  int k = r - m * Kpad;
  float v = 0.f;
  if (k < K) v = fw[b * M + m] * w[(size_t)m * K + k] + wb[(size_t)m * K + k];
  split_bf(v, ohi[idx], olo[idx]);
}

__global__ void k_correlation4(const float* __restrict__ R0,
                               const float* __restrict__ T0,
                               float* __restrict__ featw) {
  int idx = blockIdx.x * blockDim.x + threadIdx.x;
  const int tot = 4 * 49 * HW;
  if (idx >= tot) return;
  int n = idx % HW;
  int t = idx / HW;
  int d = t % 49;
  int bb = t / 49;
  int pass = bb >> 1, b = bb & 1;
  int dyi = d / 7, dxi = d - dyi * 7;
  int dy = 2 * (dyi - 3), dx = 2 * (dxi - 3);
  int h = n / WWD, w = n - h * WWD;
  int hb = h + dy, wb = w + dx;
  float s = 0.f;
  if (hb >= 0 && hb < HH && wb >= 0 && wb < WWD) {
    const float* ap = R0 + ((size_t)(b * 2 + pass) * 64) * HW + n;
    const float* bp = T0 + ((size_t)(b * 2 + 1) * 64) * HW + hb * WWD + wb;
#pragma unroll 8
    for (int c = 0; c < 64; ++c) s += ap[(size_t)c * HW] * bp[(size_t)c * HW];
  }
  featw[((size_t)bb * 177 + d) * HW + n] = s * (1.f / 64.f);
}

__global__ void k_pack_enc4(const float* __restrict__ enc4,
                            float* __restrict__ featw) {
  int idx = blockIdx.x * blockDim.x + threadIdx.x;
  const int tot = 4 * 64 * HW;
  if (idx >= tot) return;
  int bb = idx / (64 * HW);
  int r = idx - bb * (64 * HW);
  featw[((size_t)bb * 177 + 49) * HW + r] = enc4[(size_t)bb * 64 * HW + r];
  featw[((size_t)bb * 177 + 113) * HW + r] =
      enc4[(size_t)(2 + (bb & 1)) * 64 * HW + r];
}

// ---------------- general im2col (any Ksz<=5/stride/pad, zero-offset) ------
__global__ __launch_bounds__(256) void k_im2col_g(
    const float* __restrict__ src, ushort_t* __restrict__ dhi,
    ushort_t* __restrict__ dlo, int C, int Hin, int Win, int Hout, int Wout,
    int Ksz, int stride, int pad, int KP) {
  __shared__ ushort_t LH[64][100];
  __shared__ ushort_t LL[64][100];
  const int b = blockIdx.z;
  const int t = threadIdx.x;
  const int nloc = t >> 2, csub = t & 3;
  const int n0 = blockIdx.x * 64;
  const int n = n0 + nloc;
  const int c = blockIdx.y * 4 + csub;
  const int N = Hout * Wout;
  const int K2 = Ksz * Ksz;
  const int h = n / Wout, w = n - (n / Wout) * Wout;
  const bool val = (c < C) && (n < N);
  const float* s = src + ((size_t)b * C + c) * Hin * Win;
  for (int q = 0; q < K2; ++q) {
    int ki = q / Ksz, kj = q - (q / Ksz) * Ksz;
    int y = h * stride + ki - pad, x = w * stride + kj - pad;
    float v = 0.f;
    if (val && y >= 0 && y < Hin && x >= 0 && x < Win) v = s[y * Win + x];
    ushort_t hi, lo;
    split_bf(v, hi, lo);
    LH[nloc][csub * K2 + q] = hi;
    LL[nloc][csub * K2 + q] = lo;
  }
  __syncthreads();
  const int Nc = gridDim.x * 64;
  const int rl = 4 * K2;
  const int kt0 = blockIdx.y * rl;
  const int nu2 = rl >> 2;
  for (int idx = t; idx < 64 * nu2; idx += 256) {
    int r = idx / nu2, ch = idx - (idx / nu2) * nu2;
    uint2 vh = *(const uint2*)&LH[r][ch * 4];
    uint2 vl = *(const uint2*)&LL[r][ch * 4];
    size_t g = ((size_t)b * Nc + n0 + r) * KP + kt0 + ch * 4;
    *(uint2*)(dhi + g) = vh;
    *(uint2*)(dlo + g) = vl;
  }
}

__global__ void k_blend(const float* __restrict__ d0, const float* __restrict__ d1,
                        const float* __restrict__ sw0, const float* __restrict__ sw1,
                        float* __restrict__ out) {
  int idx = blockIdx.x * blockDim.x + threadIdx.x;
  const int tot = BN * 256 * HW;
  if (idx >= tot) return;
  int b = idx / (256 * HW);
  int n = idx % HW;
  float s0 = sw0[b * HW + n], s1 = sw1[b * HW + n];
  const float eps = 1e-8f;
  float na = fmaxf(fabsf(s0), eps), nb = fmaxf(fabsf(s1), eps);
  float Wx = (s0 * s1) / (na * nb);
  float Wy = (s1 * s1) / (nb * nb);
  float mx = fmaxf(Wx, Wy);
  float e0 = expf(Wx - mx), e1 = expf(Wy - mx);
  float inv = 1.f / (e0 + e1);
  out[idx] = d0[idx] * (e0 * inv) + d1[idx] * (e1 * inv);
}

// ---------------- implicit-deform split-bf16 MFMA GEMM ---------------------
// C[b][M][2304] (+)= A[(b)][M][KP] * B_implicit, where B row n, col k=(c*9+q)
// is the deform-sampled (or zero-offset) 3x3-tap value of src[b][c][.] at
// pixel n, tap q. sid/wgt precomputed once per block (shared over channels).
template <int ZERO>
__global__ __launch_bounds__(256) void k_mfma_dt(
    const ushort_t* __restrict__ Ahi, const ushort_t* __restrict__ Alo,
    const float* __restrict__ src, const float* __restrict__ off,
    float* __restrict__ Cmat, int M, int C, int KP, int abatch, int kslices) {
  __shared__ ushort_t AsH[128][40];
  __shared__ ushort_t AsL[128][40];
  __shared__ ushort_t BsH[64][40];
  __shared__ ushort_t BsL[64][40];
  __shared__ short sidA[ZERO ? 576 : 2304];
  __shared__ float wgtA[ZERO ? 4 : 2304];

  const int zb = blockIdx.z;
  const int b = zb / kslices;
  const int slice = zb - b * kslices;
  const int nch = KP >> 5;
  const int cper = (nch + kslices - 1) / kslices;
  const int kbeg = slice * cper * 32;
  const int kend = min(KP, kbeg + cper * 32);
  const int n0 = blockIdx.x * 64;
  const int m0 = blockIdx.y * 128;
  const size_t aoff = abatch ? (size_t)b * M * KP : (size_t)0;
  const ushort_t* AHp = Ahi + aoff;
  const ushort_t* ALp = Alo + aoff;
  const float* sp = src + (size_t)b * C * HW;
  const int t = threadIdx.x;
  const int lane = t & 63;
  const int wv = t >> 6;
  const int wm = wv >> 1, wn = wv & 1;
  const int l15 = lane & 15, quad = lane >> 4;

  // ---- per-block sample-table precompute (identical math to k_im2col2) ----
  for (int i = t; i < 576; i += 256) {
    int r = i / 9, q = i - (i / 9) * 9;
    int n = n0 + r;
    int h = n / WWD, w = n - (n / WWD) * WWD;
    int ki = q / 3, kj = q - (q / 3) * 3;
    if (ZERO) {
      int y = h - 1 + ki, x = w - 1 + kj;
      sidA[i] = (y >= 0 && y < HH && x >= 0 && x < WWD) ? (short)(y * WWD + x)
                                                        : (short)(-1);
    } else {
      float dy = off[((size_t)(b * 9 + q) * 2 + 0) * HW + n];
      float dx = off[((size_t)(b * 9 + q) * 2 + 1) * HW + n];
      float py = (float)(h - 1 + ki) + dy;
      float px = (float)(w - 1 + kj) + dx;
      float fy = floorf(py), fx = floorf(px);
      float ay = py - fy, ax = px - fx;
      int y0 = (int)fy, x0 = (int)fx;
      int y1 = y0 + 1, x1 = x0 + 1;
      float w00 = (1.f - ay) * (1.f - ax), w01 = (1.f - ay) * ax;
      float w10 = ay * (1.f - ax), w11 = ay * ax;
      bool vy0 = (y0 >= 0 && y0 < HH), vy1 = (y1 >= 0 && y1 < HH);
      bool vx0 = (x0 >= 0 && x0 < WWD), vx1 = (x1 >= 0 && x1 < WWD);
      int cy0 = min(max(y0, 0), HH - 1), cy1 = min(max(y1, 0), HH - 1);
      int cx0 = min(max(x0, 0), WWD - 1), cx1 = min(max(x1, 0), WWD - 1);
      sidA[i * 4 + 0] = (short)(cy0 * WWD + cx0);
      sidA[i * 4 + 1] = (short)(cy0 * WWD + cx1);
      sidA[i * 4 + 2] = (short)(cy1 * WWD + cx0);
      sidA[i * 4 + 3] = (short)(cy1 * WWD + cx1);
      wgtA[i * 4 + 0] = (vy0 && vx0) ? w00 : 0.f;
      wgtA[i * 4 + 1] = (vy0 && vx1) ? w01 : 0.f;
      wgtA[i * 4 + 2] = (vy1 && vx0) ? w10 : 0.f;
      wgtA[i * 4 + 3] = (vy1 && vx1) ? w11 : 0.f;
    }
  }
  __syncthreads();

  const int arow = t >> 1;
  const int acnk = (t & 1) * 2;
  const int pixr = t >> 2;
  const int kc = t & 3;

  f32x4 acc[4][2];
  const f32x4 z4 = {0.f, 0.f, 0.f, 0.f};
#pragma unroll
  for (int i = 0; i < 4; ++i)
#pragma unroll
    for (int j = 0; j < 2; ++j) acc[i][j] = z4;

  const bool aval = (m0 + arow) < M;
  const uint4 zero16 = {0u, 0u, 0u, 0u};

  for (int k0 = kbeg; k0 < kend; k0 += 32) {
    // A staging (identical to k_mfma_nt)
    const size_t arow_off = (size_t)(m0 + arow) * KP + k0;
    uint4 ah0 = aval ? *(const uint4*)(AHp + arow_off + acnk * 8) : zero16;
    uint4 ah1 = aval ? *(const uint4*)(AHp + arow_off + (acnk + 1) * 8) : zero16;
    uint4 al0 = aval ? *(const uint4*)(ALp + arow_off + acnk * 8) : zero16;
    uint4 al1 = aval ? *(const uint4*)(ALp + arow_off + (acnk + 1) * 8) : zero16;

    // B staging: implicit im2col, 8 k-values per thread
    union { ushort_t u[8]; uint4 v; } ph, pl;
    {
      int k = k0 + kc * 8;
      int c = k / 9;
      int q = k - c * 9;
#pragma unroll
      for (int j = 0; j < 8; ++j) {
        float v = 0.f;
        if (c < C) {
          const float* s = sp + (size_t)c * HW;
          if (ZERO) {
            int s0 = sidA[pixr * 9 + q];
            v = (s0 >= 0) ? s[s0] : 0.f;
          } else {
            int e = (pixr * 9 + q) * 4;
            v = wgtA[e + 0] * s[sidA[e + 0]] + wgtA[e + 1] * s[sidA[e + 1]] +
                wgtA[e + 2] * s[sidA[e + 2]] + wgtA[e + 3] * s[sidA[e + 3]];
          }
        }
        split_bf(v, ph.u[j], pl.u[j]);
        ++q;
        if (q == 9) { q = 0; ++c; }
      }
    }

    *(uint4*)&AsH[arow][acnk * 8] = ah0;
    *(uint4*)&AsH[arow][(acnk + 1) * 8] = ah1;
    *(uint4*)&AsL[arow][acnk * 8] = al0;
    *(uint4*)&AsL[arow][(acnk + 1) * 8] = al1;
    *(uint4*)&BsH[pixr][kc * 8] = ph.v;
    *(uint4*)&BsL[pixr][kc * 8] = pl.v;
    __syncthreads();

    bf16x8 afh[4], afl[4], bfh[2], bfl[2];
#pragma unroll
    for (int mt = 0; mt < 4; ++mt) {
      afh[mt] = *(const bf16x8*)&AsH[wm * 64 + mt * 16 + l15][quad * 8];
      afl[mt] = *(const bf16x8*)&AsL[wm * 64 + mt * 16 + l15][quad * 8];
    }
#pragma unroll
    for (int nt = 0; nt < 2; ++nt) {
      bfh[nt] = *(const bf16x8*)&BsH[wn * 32 + nt * 16 + l15][quad * 8];
      bfl[nt] = *(const bf16x8*)&BsL[wn * 32 + nt * 16 + l15][quad * 8];
    }
#pragma unroll
    for (int mt = 0; mt < 4; ++mt)
#pragma unroll
      for (int nt = 0; nt < 2; ++nt) {
        acc[mt][nt] = __builtin_amdgcn_mfma_f32_16x16x32_bf16(
            afh[mt], bfh[nt], acc[mt][nt], 0, 0, 0);
        acc[mt][nt] = __builtin_amdgcn_mfma_f32_16x16x32_bf16(
            afh[mt], bfl[nt], acc[mt][nt], 0, 0, 0);
        acc[mt][nt] = __builtin_amdgcn_mfma_f32_16x16x32_bf16(
            afl[mt], bfh[nt], acc[mt][nt], 0, 0, 0);
      }
    __syncthreads();
  }

  float* Cp = Cmat + (size_t)b * M * HW;
#pragma unroll
  for (int mt = 0; mt < 4; ++mt) {
#pragma unroll
    for (int nt = 0; nt < 2; ++nt) {
#pragma unroll
      for (int reg = 0; reg < 4; ++reg) {
        int m = m0 + wm * 64 + mt * 16 + quad * 4 + reg;
        if (m >= M) continue;
        int n = n0 + wn * 32 + nt * 16 + l15;
        if (kslices > 1) {
          atomicAdd(&Cp[(size_t)m * HW + n], acc[mt][nt][reg]);
        } else {
          Cp[(size_t)m * HW + n] = acc[mt][nt][reg];
        }
      }
    }
  }
}

// ---------------- off-conv MFMA: implicit zero-offset im2col (3x3 p1) ------
__global__ __launch_bounds__(256) void k_off_mfma(
    const ushort_t* __restrict__ Ahi, const ushort_t* __restrict__ Alo,
    const float* __restrict__ src, float* __restrict__ Cmat,
    int M, int C, int kslices) {
  const int N = HW;
  const int K = C * 9;
  __shared__ ushort_t BsH[64][40];
  __shared__ ushort_t BsL[64][40];
  __shared__ int spix[64][10];
  const int zb = blockIdx.z;
  const int b = zb / kslices;
  const int slice = zb - b * kslices;
  const int Kc = K / kslices;
  const int kbeg = slice * Kc;
  const int n0 = blockIdx.x * 64;
  const int t = threadIdx.x;
  const int lane = t & 63;
  const int wv = t >> 6;
  const int l15 = lane & 15, quad = lane >> 4;
  const float* sp = src + (size_t)b * C * HW;

  for (int i = t; i < 64 * 9; i += 256) {
    int r = i / 9, q = i - (i / 9) * 9;
    int n = n0 + r;
    int h = n / WWD, w = n - (n / WWD) * WWD;
    int ki = q / 3, kj = q - (q / 3) * 3;
    int y = h - 1 + ki, x = w - 1 + kj;
    spix[r][q] = (y >= 0 && y < HH && x >= 0 && x < WWD) ? (y * WWD + x) : -1;
  }
  __syncthreads();

  const int srow = t >> 2;
  const int scnk = t & 3;

  f32x4 acc[2];
  const f32x4 z4 = {0.f, 0.f, 0.f, 0.f};
  acc[0] = z4;
  acc[1] = z4;
  const uint4 zero16 = {0u, 0u, 0u, 0u};

  for (int k0 = kbeg; k0 < kbeg + Kc; k0 += 32) {
    {
      int k = k0 + scnk * 8;
      int c = k / 9;
      int q = k - c * 9;
#pragma unroll
      for (int j = 0; j < 8; ++j) {
        int ix = spix[srow][q];
        float v = (ix >= 0) ? sp[(size_t)c * HW + ix] : 0.f;
        ushort_t hi, lo;
        split_bf(v, hi, lo);
        BsH[srow][scnk * 8 + j] = hi;
        BsL[srow][scnk * 8 + j] = lo;
        ++q;
        if (q == 9) { q = 0; ++c; }
      }
    }
    __syncthreads();

    bf16x8 afh[2], afl[2], bfh, bfl;
#pragma unroll
    for (int mt = 0; mt < 2; ++mt) {
      int m = mt * 16 + l15;
      bool v = m < M;
      uint4 ah = v ? *(const uint4*)(Ahi + (size_t)m * K + k0 + quad * 8) : zero16;
      uint4 al = v ? *(const uint4*)(Alo + (size_t)m * K + k0 + quad * 8) : zero16;
      afh[mt] = *(const bf16x8*)&ah;
      afl[mt] = *(const bf16x8*)&al;
    }
    bfh = *(const bf16x8*)&BsH[wv * 16 + l15][quad * 8];
    bfl = *(const bf16x8*)&BsL[wv * 16 + l15][quad * 8];
#pragma unroll
    for (int mt = 0; mt < 2; ++mt) {
      acc[mt] = __builtin_amdgcn_mfma_f32_16x16x32_bf16(afh[mt], bfh, acc[mt], 0, 0, 0);
      acc[mt] = __builtin_amdgcn_mfma_f32_16x16x32_bf16(afh[mt], bfl, acc[mt], 0, 0, 0);
      acc[mt] = __builtin_amdgcn_mfma_f32_16x16x32_bf16(afl[mt], bfh, acc[mt], 0, 0, 0);
    }
    __syncthreads();
  }

  float* Cp = Cmat + (size_t)b * M * N;
#pragma unroll
  for (int mt = 0; mt < 2; ++mt)
#pragma unroll
    for (int reg = 0; reg < 4; ++reg) {
      int m = mt * 16 + quad * 4 + reg;
      if (m >= M) continue;
      int n = n0 + wv * 16 + l15;
      atomicAdd(&Cp[(size_t)m * N + n], acc[mt][reg]);
    }
}

// ---------------- split-bf16 M32-tile GEMM over cols -----------------------
__global__ __launch_bounds__(256) void k_gemm_sk(
    const ushort_t* __restrict__ Ahi, const ushort_t* __restrict__ Alo,
    const ushort_t* __restrict__ Bhi, const ushort_t* __restrict__ Blo,
    const float* __restrict__ bias, float* __restrict__ Cmat,
    int M, int N, int Nc, int KP, int kslices, int relu) {
  __shared__ ushort_t BsH[64][40];
  __shared__ ushort_t BsL[64][40];
  const int zb = blockIdx.z;
  const int b = zb / kslices;
  const int slice = zb - b * kslices;
  const int nch = KP >> 5;
  const int cper = (nch + kslices - 1) / kslices;
  const int kbeg = slice * cper * 32;
  const int kend = min(KP, kbeg + cper * 32);
  const int n0 = blockIdx.x * 64;
  const int m0 = blockIdx.y * 32;
  const int t = threadIdx.x;
  const int lane = t & 63;
  const int wv = t >> 6;
  const int l15 = lane & 15, quad = lane >> 4;
  const ushort_t* BHp = Bhi + ((size_t)b * Nc + n0) * KP;
  const ushort_t* BLp = Blo + ((size_t)b * Nc + n0) * KP;
  const int srow = t >> 2, scnk = t & 3;

  f32x4 acc[2];
  const f32x4 z4 = {0.f, 0.f, 0.f, 0.f};
  acc[0] = z4;
  acc[1] = z4;
  const uint4 zero16 = {0u, 0u, 0u, 0u};

  for (int k0 = kbeg; k0 < kend; k0 += 32) {
    const size_t bo = (size_t)srow * KP + k0 + scnk * 8;
    uint4 bh = *(const uint4*)(BHp + bo);
    uint4 bl = *(const uint4*)(BLp + bo);
    *(uint4*)&BsH[srow][scnk * 8] = bh;
    *(uint4*)&BsL[srow][scnk * 8] = bl;
    __syncthreads();

    bf16x8 afh[2], afl[2], bfh, bfl;
#pragma unroll
    for (int mt = 0; mt < 2; ++mt) {
      int m = m0 + mt * 16 + l15;
      bool v = m < M;
      uint4 ah = v ? *(const uint4*)(Ahi + (size_t)m * KP + k0 + quad * 8) : zero16;
      uint4 al = v ? *(const uint4*)(Alo + (size_t)m * KP + k0 + quad * 8) : zero16;
      afh[mt] = *(const bf16x8*)&ah;
      afl[mt] = *(const bf16x8*)&al;
    }
    bfh = *(const bf16x8*)&BsH[wv * 16 + l15][quad * 8];
    bfl = *(const bf16x8*)&BsL[wv * 16 + l15][quad * 8];
#pragma unroll
    for (int mt = 0; mt < 2; ++mt) {
      acc[mt] = __builtin_amdgcn_mfma_f32_16x16x32_bf16(afh[mt], bfh, acc[mt], 0, 0, 0);
      acc[mt] = __builtin_amdgcn_mfma_f32_16x16x32_bf16(afh[mt], bfl, acc[mt], 0, 0, 0);
      acc[mt] = __builtin_amdgcn_mfma_f32_16x16x32_bf16(afl[mt], bfh, acc[mt], 0, 0, 0);
    }
    __syncthreads();
  }

  float* Cp = Cmat + (size_t)b * M * N;
  const int n = n0 + wv * 16 + l15;
  if (n < N) {
#pragma unroll
    for (int mt = 0; mt < 2; ++mt)
#pragma unroll
      for (int reg = 0; reg < 4; ++reg) {
        int m = m0 + mt * 16 + quad * 4 + reg;
        if (m >= M) continue;
        if (kslices > 1) {
          atomicAdd(&Cp[(size_t)m * N + n], acc[mt][reg]);
        } else {
          float v = acc[mt][reg];
          if (bias != nullptr) v += bias[m];
          if (relu) v = fmaxf(v, 0.f);
          Cp[(size_t)m * N + n] = v;
        }
      }
  }
}

// ---------------------------------------------------------------------------

extern "C" void kernel_launch(void* const* d_in, const int* in_sizes, int n_in,
                              void* d_out, int out_size, void* d_ws, size_t ws_size,
                              hipStream_t stream) {
  (void)in_sizes; (void)n_in; (void)out_size;

  const float* R0     = (const float*)d_in[0];
  const float* T0     = (const float*)d_in[1];
  const float* inp    = (const float*)d_in[2];
  const float* enc0_w = (const float*)d_in[3];
  const float* enc0_b = (const float*)d_in[4];
  const float* enc1_w = (const float*)d_in[5];
  const float* enc1_b = (const float*)d_in[6];
  const float* off_w[4] = {(const float*)d_in[7], (const float*)d_in[8],
                           (const float*)d_in[9], (const float*)d_in[10]};
  const float* def_w[3] = {(const float*)d_in[11], (const float*)d_in[12],
                           (const float*)d_in[13]};
  const float* w0a = (const float*)d_in[14];
  const float* w0b = (const float*)d_in[15];
  const float* w0c = (const float*)d_in[16];
  const float* w1a = (const float*)d_in[17];
  const float* w1b = (const float*)d_in[18];
  const float* w1c = (const float*)d_in[19];
  const float* wx_w  = (const float*)d_in[20];
  const float* wx_b  = (const float*)d_in[21];
  const float* wxf_w = (const float*)d_in[22];
  const float* wxf_b = (const float*)d_in[23];
  const float* s1w = (const float*)d_in[24];
  const float* s2w = (const float*)d_in[25];
  const float* s3w = (const float*)d_in[26];

  float* ws = (float*)d_ws;
  size_t used = 0;
  auto alloc = [&](size_t n) { float* p = ws + used; used += n; return p; };

  float* xy4     = alloc(2359296);
  float* xf      = xy4;
  float* yf      = xy4 + 1179648;
  float* enc4    = alloc(589824);
  float* xenc    = enc4;
  float* yenc    = enc4 + 294912;
  float* offsets4= alloc(165888);
  float* featw4  = alloc(1631232);
  float* featw24 = alloc(1631232);
  float* wb1     = alloc(147456);
  float* wb2     = alloc(36864);
  float* wb3     = alloc(36864);
  float* fw1     = alloc(1024);
  float* fw2     = alloc(1024);
  float* deform4 = alloc(2359296);
  float* sn1     = alloc(1179648);
  float* sn2     = alloc(589824);
  float* sw4     = alloc(9216);
  ushort_t *defw_h[3], *defw_l[3];
  for (int i = 0; i < 3; ++i) {
    defw_h[i] = (ushort_t*)alloc(1179648);
    defw_l[i] = (ushort_t*)alloc(1179648);
  }
  ushort_t *offw_h[4], *offw_l[4];
  for (int i = 0; i < 4; ++i) {
    offw_h[i] = (ushort_t*)alloc(41472);
    offw_l[i] = (ushort_t*)alloc(41472);
  }
  ushort_t* wxf_h = (ushort_t*)alloc(1179648);
  ushort_t* wxf_l = (ushort_t*)alloc(1179648);
  ushort_t* s1w_h = (ushort_t*)alloc(147456);
  ushort_t* s1w_l = (ushort_t*)alloc(147456);
  ushort_t* s2w_h = (ushort_t*)alloc(36864);
  ushort_t* s2w_l = (ushort_t*)alloc(36864);
  ushort_t* w0a_h = (ushort_t*)alloc(144384);
  ushort_t* w0a_l = (ushort_t*)alloc(144384);
  ushort_t* w1a_h = (ushort_t*)alloc(144384);
  ushort_t* w1a_l = (ushort_t*)alloc(144384);
  ushort_t* w0b_h = (ushort_t*)alloc(51200);
  ushort_t* w0b_l = (ushort_t*)alloc(51200);
  ushort_t* w1b_h = (ushort_t*)alloc(51200);
  ushort_t* w1b_l = (ushort_t*)alloc(51200);
  ushort_t* w0c_h = (ushort_t*)alloc(50976);
  ushort_t* w0c_l = (ushort_t*)alloc(50976);
  ushort_t* w1c_h = (ushort_t*)alloc(73728);
  ushort_t* w1c_l = (ushort_t*)alloc(73728);
  ushort_t* e0w_h = (ushort_t*)alloc(8192);
  ushort_t* e0w_l = (ushort_t*)alloc(8192);
  ushort_t* e1w_h = (ushort_t*)alloc(8192);
  ushort_t* e1w_l = (ushort_t*)alloc(8192);
  ushort_t* s3w_h = (ushort_t*)alloc(288);
  ushort_t* s3w_l = (ushort_t*)alloc(288);
  ushort_t* wxad_h = (ushort_t*)alloc(577728);
  ushort_t* wxad_l = (ushort_t*)alloc(577728);
  float* featA = alloc(4718592);
  float* featB = alloc(4718592);
  float* offbN = alloc(165888);
  ushort_t* cols_h = (ushort_t*)alloc(5197824);
  ushort_t* cols_l = (ushort_t*)alloc(5197824);
  if (used * sizeof(float) > ws_size) return;

  auto mfma_dt = [&](const ushort_t* Ah, const ushort_t* Al, const float* srcf,
                     const float* offp, float* Cmat, int M, int C, int KP,
                     int abatch, int ks, int nb) {
    if (ks > 1)
      hipMemsetAsync(Cmat, 0, (size_t)nb * M * HW * sizeof(float), stream);
    dim3 grid(36, (M + 127) / 128, nb * ks);
    if (offp)
      k_mfma_dt<0><<<grid, 256, 0, stream>>>(Ah, Al, srcf, offp, Cmat, M, C,
                                             KP, abatch, ks);
    else
      k_mfma_dt<1><<<grid, 256, 0, stream>>>(Ah, Al, srcf, nullptr, Cmat, M, C,
                                             KP, abatch, ks);
  };
  auto off_conv = [&](const ushort_t* Ah, const ushort_t* Al, const float* src,
                      float* Cmat, int C, int nb) {
    hipMemsetAsync(Cmat, 0, (size_t)nb * 18 * HW * sizeof(float), stream);
    dim3 grid(36, 1, nb * 8);
    k_off_mfma<<<grid, 256, 0, stream>>>(Ah, Al, src, Cmat, 18, C, 8);
  };
  auto im2col_g = [&](const float* src, int C, int Hin, int Win, int Hout,
                      int Wout, int Ksz, int stridec, int pad, int KP, int nb) {
    dim3 grid((Hout * Wout + 63) / 64, (C + 3) / 4, nb);
    k_im2col_g<<<grid, 256, 0, stream>>>(src, cols_h, cols_l, C, Hin, Win, Hout,
                                         Wout, Ksz, stridec, pad, KP);
  };
  auto gemm_sk = [&](const ushort_t* Ah, const ushort_t* Al, const float* bias,
                     float* Cmat, int M, int N, int KP, int kslices, int relu,
                     int nb) {
    int Nc = ((N + 63) / 64) * 64;
    if (kslices > 1)
      hipMemsetAsync(Cmat, 0, (size_t)nb * M * N * sizeof(float), stream);
    dim3 grid(Nc / 64, (M + 31) / 32, nb * kslices);
    k_gemm_sk<<<grid, 256, 0, stream>>>(Ah, Al, cols_h, cols_l, bias, Cmat, M,
                                        N, Nc, KP, kslices, relu);
  };

  // ---- weight conversions (merged) ----
  k_w2bz3<<<dim3((2359296 + 255) / 256, 1, 3), 256, 0, stream>>>(
      def_w[0], def_w[1], def_w[2], defw_h[0], defw_h[1], defw_h[2],
      defw_l[0], defw_l[1], defw_l[2], 2359296);
  k_w2bz4<<<dim3((82944 + 255) / 256, 1, 4), 256, 0, stream>>>(
      off_w[0], off_w[1], off_w[2], off_w[3], offw_h[0], offw_h[1], offw_h[2],
      offw_h[3], offw_l[0], offw_l[1], offw_l[2], offw_l[3], 82944);
  k_w2b<<<(294912 + 255) / 256, 256, 0, stream>>>(s1w, s1w_h, s1w_l, 294912);
  k_w2b<<<(73728 + 255) / 256, 256, 0, stream>>>(s2w, s2w_h, s2w_l, 73728);
  k_w2b_padz2<<<dim3((64 * 4512 + 255) / 256, 1, 2), 256, 0, stream>>>(
      w0a, w1a, w0a_h, w1a_h, w0a_l, w1a_l, 64, 64, 4425, 4512);
  k_w2b_padz2<<<dim3((64 * 1600 + 255) / 256, 1, 2), 256, 0, stream>>>(
      w0b, w1b, w0b_h, w1b_h, w0b_l, w1b_l, 64, 64, 1600, 1600);
  k_w2b_padz2<<<dim3((256 * 576 + 255) / 256, 1, 2), 256, 0, stream>>>(
      w0c, w1c, w0c_h, w1c_h, w0c_l, w1c_l, 177, 256, 576, 576);
  k_w2b_padz2<<<dim3((64 * 256 + 255) / 256, 1, 2), 256, 0, stream>>>(
      enc0_w, enc1_w, e0w_h, e1w_h, e0w_l, e1w_l, 64, 64, 256, 256);
  k_w2b_pad<<<(576 + 255) / 256, 256, 0, stream>>>(s3w, s3w_h, s3w_l, 1, 576, 576);

  // ---- split + encoders ----
  k_split_xy<<<4608, 256, 0, stream>>>(inp, xf, yf);
  im2col_g(xf, 256, 48, 48, 48, 48, 1, 1, 0, 256, BN);
  gemm_sk(e0w_h, e0w_l, enc0_b, xenc, 64, 2304, 256, 1, 0, BN);
  im2col_g(yf, 256, 48, 48, 48, 48, 1, 1, 0, 256, BN);
  gemm_sk(e1w_h, e1w_l, enc1_b, yenc, 64, 2304, 256, 1, 0, BN);

  // ---- stsn_offset: batch-4 implicit-deform chain ----
  k_concat512_4<<<(4 * 512 * HW) / 256, 256, 0, stream>>>(xy4, featA);
  {
    float* cur = featA;
    float* nxt = featB;
    for (int i = 0; i < 3; ++i) {
      off_conv(offw_h[i], offw_l[i], cur, offbN, 512, 4);
      mfma_dt(defw_h[i], defw_l[i], cur, offbN, nxt, 512, 512, 4608, 0, 4, 4);
      float* tmp = cur; cur = nxt; nxt = tmp;
    }
    off_conv(offw_h[3], offw_l[3], cur, offsets4, 512, 4);
  }

  // ---- astsn_weight + adaptive deform conv (batch-4) ----
  auto branch = [&](const float* fin, const ushort_t* wah, const ushort_t* wal,
                    const ushort_t* wbh, const ushort_t* wbl,
                    const ushort_t* wch, const ushort_t* wcl, int Mout,
                    float* fwout) {
    im2col_g(fin, 177, 48, 48, 24, 24, 5, 2, 2, 4512, 4);
    gemm_sk(wah, wal, nullptr, wb1, 64, 576, 4512, 8, 0, 4);
    k_relu<<<(4 * 64 * 576 + 255) / 256, 256, 0, stream>>>(wb1, 4 * 64 * 576);
    im2col_g(wb1, 64, 24, 24, 12, 12, 5, 2, 2, 1600, 4);
    gemm_sk(wbh, wbl, nullptr, wb2, 64, 144, 1600, 4, 0, 4);
    k_relu<<<(4 * 64 * 144 + 255) / 256, 256, 0, stream>>>(wb2, 4 * 64 * 144);
    im2col_g(wb2, 64, 12, 12, 6, 6, 3, 2, 1, 576, 4);
    gemm_sk(wch, wcl, nullptr, wb3, Mout, 36, 576, 2, 0, 4);
    k_mean<<<(4 * Mout + 255) / 256, 256, 0, stream>>>(wb3, fwout, 4 * Mout, 36);
  };

  k_correlation4<<<(4 * 49 * HW + 255) / 256, 256, 0, stream>>>(R0, T0, featw4);
  k_pack_enc4<<<(4 * 64 * HW + 255) / 256, 256, 0, stream>>>(enc4, featw4);
  branch(featw4, w0a_h, w0a_l, w0b_h, w0b_l, w0c_h, w0c_l, 177, fw1);
  k_w2b_fw_pad<<<(4 * 177 * 1632 + 255) / 256, 256, 0, stream>>>(
      wx_w, wx_b, fw1, wxad_h, wxad_l, 177, 1593, 1632, 4);
  mfma_dt(wxad_h, wxad_l, featw4, nullptr, featw24, 177, 177, 1632, 1, 2, 4);
  k_relu<<<(4 * 177 * HW + 255) / 256, 256, 0, stream>>>(featw24, 4 * 177 * HW);
  branch(featw24, w1a_h, w1a_l, w1b_h, w1b_l, w1c_h, w1c_l, 256, fw2);
  k_w2b_fw<<<(4 * 256 * 2304 + 255) / 256, 256, 0, stream>>>(
      wxf_w, wxf_b, fw2, wxf_h, wxf_l, 256, 2304, 4);
  mfma_dt(wxf_h, wxf_l, xy4, offsets4, deform4, 256, 256, 2304, 1, 2, 4);

  // ---- s_net (batch-4, implicit zero-offset) ----
  mfma_dt(s1w_h, s1w_l, deform4, nullptr, sn1, 128, 256, 2304, 0, 4, 4);
  k_relu<<<(4 * 128 * HW + 255) / 256, 256, 0, stream>>>(sn1, 4 * 128 * HW);
  mfma_dt(s2w_h, s2w_l, sn1, nullptr, sn2, 64, 128, 1152, 0, 4, 4);
  k_relu<<<(4 * 64 * HW + 255) / 256, 256, 0, stream>>>(sn2, 4 * 64 * HW);
  im2col_g(sn2, 64, 48, 48, 48, 48, 3, 1, 1, 576, 4);
  gemm_sk(s3w_h, s3w_l, nullptr, sw4, 1, 2304, 576, 1, 1, 4);

  // ---- blend ----
  k_blend<<<4608, 256, 0, stream>>>(deform4, deform4 + 2 * 256 * HW, sw4,
                                    sw4 + 2 * HW, (float*)d_out);
}

// Round 2
// 2492.745 us; speedup vs baseline: 1.1225x; 1.1225x over previous
//
#include <hip/hip_runtime.h>
#include <stdint.h>

// ---------------------------------------------------------------------------
// Round 15: revert to r13 structure (materialized im2col + k_mfma_nt; r14's
// in-GEMM implicit im2col was texture-pipe-bound: 32 scalar uncoalesced
// gathers per thread per K-step, 622 us vs 127 us). Upgrade k_mfma_nt from
// 128x64 to 128x128 tile: 48 MFMA per barrier pair per wave (was 24), B
// staging mirrors A path, grid.x halves (36->18) halving A-panel re-reads.
// Targets the barrier/staging-bound regime (MfmaUtil 21%, VALUBusy 11%,
// HBM 24% -- nothing saturated).
// ---------------------------------------------------------------------------

typedef unsigned short ushort_t;
typedef __attribute__((ext_vector_type(8))) short bf16x8;
typedef __attribute__((ext_vector_type(4))) float f32x4;

#define BN 2
#define HH 48
#define WWD 48
#define HW 2304

__device__ __forceinline__ float b2f(ushort_t h) {
  union { uint32_t u; float f; } v; v.u = ((uint32_t)h) << 16; return v.f;
}
__device__ __forceinline__ ushort_t f2b(float f) {
  union { float f; uint32_t u; } v; v.f = f;
  uint32_t u = v.u;
  uint32_t r = (u + 0x7fffu + ((u >> 16) & 1u)) >> 16;
  return (ushort_t)r;
}
__device__ __forceinline__ void split_bf(float v, ushort_t& hi, ushort_t& lo) {
  hi = f2b(v);
  lo = f2b(v - b2f(hi));
}

// ---------------- elementwise / packing kernels ----------------------------

__global__ void k_split_xy(const float* __restrict__ in, float* __restrict__ xf,
                           float* __restrict__ yf) {
  int idx = blockIdx.x * blockDim.x + threadIdx.x;
  const int tot = BN * 256 * HW;
  if (idx >= tot) return;
  int b = idx / (256 * HW);
  int r = idx - b * (256 * HW);
  xf[idx] = in[(size_t)(2 * b) * (256 * HW) + r];
  yf[idx] = in[(size_t)(2 * b + 1) * (256 * HW) + r];
}

__global__ void k_concat512(const float* __restrict__ a, const float* __restrict__ c2,
                            float* __restrict__ feat) {
  int idx = blockIdx.x * blockDim.x + threadIdx.x;
  const int tot = BN * 512 * HW;
  if (idx >= tot) return;
  int b = idx / (512 * HW);
  int r = idx - b * (512 * HW);
  int c = r / HW;
  int n = r - c * HW;
  feat[idx] = (c < 256) ? a[(b * 256 + c) * HW + n]
                        : c2[(b * 256 + (c - 256)) * HW + n];
}

// batch-4 concat: feat4[bb] = concat(xy4[bb], xy4[2+(bb&1)])
__global__ void k_concat512_4(const float* __restrict__ xy4,
                              float* __restrict__ feat) {
  int idx = blockIdx.x * blockDim.x + threadIdx.x;
  const int tot = 4 * 512 * HW;
  if (idx >= tot) return;
  int bb = idx / (512 * HW);
  int r = idx - bb * (512 * HW);
  int c = r / HW;
  int n = r - c * HW;
  feat[idx] = (c < 256)
                  ? xy4[((size_t)bb * 256 + c) * HW + n]
                  : xy4[((size_t)(2 + (bb & 1)) * 256 + (c - 256)) * HW + n];
}

__global__ void k_relu(float* __restrict__ p, int n) {
  int idx = blockIdx.x * blockDim.x + threadIdx.x;
  if (idx < n) p[idx] = fmaxf(p[idx], 0.f);
}

__global__ void k_mean(const float* __restrict__ src, float* __restrict__ dst,
                       int Mtot, int N) {
  int idx = blockIdx.x * blockDim.x + threadIdx.x;
  if (idx >= Mtot) return;
  const float* p = src + (size_t)idx * N;
  float s = 0.f;
  for (int i = 0; i < N; ++i) s += p[i];
  dst[idx] = s / (float)N;
}

__global__ void k_w2b(const float* __restrict__ w, ushort_t* __restrict__ ohi,
                      ushort_t* __restrict__ olo, int n) {
  int idx = blockIdx.x * blockDim.x + threadIdx.x;
  if (idx < n) split_bf(w[idx], ohi[idx], olo[idx]);
}

// z-merged conversions (same element count per z)
__global__ void k_w2bz3(const float* __restrict__ p0, const float* __restrict__ p1,
                        const float* __restrict__ p2, ushort_t* __restrict__ h0,
                        ushort_t* __restrict__ h1, ushort_t* __restrict__ h2,
                        ushort_t* __restrict__ l0, ushort_t* __restrict__ l1,
                        ushort_t* __restrict__ l2, int n) {
  int idx = blockIdx.x * blockDim.x + threadIdx.x;
  if (idx >= n) return;
  int z = blockIdx.z;
  const float* p = (z == 0) ? p0 : (z == 1) ? p1 : p2;
  ushort_t* h = (z == 0) ? h0 : (z == 1) ? h1 : h2;
  ushort_t* l = (z == 0) ? l0 : (z == 1) ? l1 : l2;
  split_bf(p[idx], h[idx], l[idx]);
}

__global__ void k_w2bz4(const float* __restrict__ p0, const float* __restrict__ p1,
                        const float* __restrict__ p2, const float* __restrict__ p3,
                        ushort_t* __restrict__ h0, ushort_t* __restrict__ h1,
                        ushort_t* __restrict__ h2, ushort_t* __restrict__ h3,
                        ushort_t* __restrict__ l0, ushort_t* __restrict__ l1,
                        ushort_t* __restrict__ l2, ushort_t* __restrict__ l3,
                        int n) {
  int idx = blockIdx.x * blockDim.x + threadIdx.x;
  if (idx >= n) return;
  int z = blockIdx.z;
  const float* p = (z == 0) ? p0 : (z == 1) ? p1 : (z == 2) ? p2 : p3;
  ushort_t* h = (z == 0) ? h0 : (z == 1) ? h1 : (z == 2) ? h2 : h3;
  ushort_t* l = (z == 0) ? l0 : (z == 1) ? l1 : (z == 2) ? l2 : l3;
  split_bf(p[idx], h[idx], l[idx]);
}

__global__ void k_w2b_pad(const float* __restrict__ w, ushort_t* __restrict__ ohi,
                          ushort_t* __restrict__ olo, int M, int K, int Kpad) {
  int idx = blockIdx.x * blockDim.x + threadIdx.x;
  if (idx >= M * Kpad) return;
  int m = idx / Kpad, k = idx - m * Kpad;
  float v = (k < K) ? w[(size_t)m * K + k] : 0.f;
  split_bf(v, ohi[idx], olo[idx]);
}

__global__ void k_w2b_padz2(const float* __restrict__ p0, const float* __restrict__ p1,
                            ushort_t* __restrict__ h0, ushort_t* __restrict__ h1,
                            ushort_t* __restrict__ l0, ushort_t* __restrict__ l1,
                            int M0, int M1, int K, int Kpad) {
  int idx = blockIdx.x * blockDim.x + threadIdx.x;
  int z = blockIdx.z;
  int M = z ? M1 : M0;
  if (idx >= M * Kpad) return;
  int m = idx / Kpad, k = idx - m * Kpad;
  const float* w = z ? p1 : p0;
  ushort_t* h = z ? h1 : h0;
  ushort_t* l = z ? l1 : l0;
  float v = (k < K) ? w[(size_t)m * K + k] : 0.f;
  split_bf(v, h[idx], l[idx]);
}

__global__ void k_w2b_fw(const float* __restrict__ w, const float* __restrict__ wb,
                         const float* __restrict__ fw, ushort_t* __restrict__ ohi,
                         ushort_t* __restrict__ olo, int M, int K, int NB) {
  int idx = blockIdx.x * blockDim.x + threadIdx.x;
  int tot = NB * M * K;
  if (idx >= tot) return;
  int b = idx / (M * K);
  int r = idx - b * (M * K);
  int m = r / K;
  split_bf(fw[b * M + m] * w[r] + wb[r], ohi[idx], olo[idx]);
}

__global__ void k_w2b_fw_pad(const float* __restrict__ w, const float* __restrict__ wb,
                             const float* __restrict__ fw, ushort_t* __restrict__ ohi,
                             ushort_t* __restrict__ olo, int M, int K, int Kpad,
                             int NB) {
  int idx = blockIdx.x * blockDim.x + threadIdx.x;
  int tot = NB * M * Kpad;
  if (idx >= tot) return;
  int b = idx / (M * Kpad);
  int r = idx - b * (M * Kpad);
  int m = r / Kpad;
  int k = r - m * Kpad;
  float v = 0.f;
  if (k < K) v = fw[b * M + m] * w[(size_t)m * K + k] + wb[(size_t)m * K + k];
  split_bf(v, ohi[idx], olo[idx]);
}

__global__ void k_correlation4(const float* __restrict__ R0,
                               const float* __restrict__ T0,
                               float* __restrict__ featw) {
  int idx = blockIdx.x * blockDim.x + threadIdx.x;
  const int tot = 4 * 49 * HW;
  if (idx >= tot) return;
  int n = idx % HW;
  int t = idx / HW;
  int d = t % 49;
  int bb = t / 49;
  int pass = bb >> 1, b = bb & 1;
  int dyi = d / 7, dxi = d - dyi * 7;
  int dy = 2 * (dyi - 3), dx = 2 * (dxi - 3);
  int h = n / WWD, w = n - h * WWD;
  int hb = h + dy, wb = w + dx;
  float s = 0.f;
  if (hb >= 0 && hb < HH && wb >= 0 && wb < WWD) {
    const float* ap = R0 + ((size_t)(b * 2 + pass) * 64) * HW + n;
    const float* bp = T0 + ((size_t)(b * 2 + 1) * 64) * HW + hb * WWD + wb;
#pragma unroll 8
    for (int c = 0; c < 64; ++c) s += ap[(size_t)c * HW] * bp[(size_t)c * HW];
  }
  featw[((size_t)bb * 177 + d) * HW + n] = s * (1.f / 64.f);
}

__global__ void k_pack_enc4(const float* __restrict__ enc4,
                            float* __restrict__ featw) {
  int idx = blockIdx.x * blockDim.x + threadIdx.x;
  const int tot = 4 * 64 * HW;
  if (idx >= tot) return;
  int bb = idx / (64 * HW);
  int r = idx - bb * (64 * HW);
  featw[((size_t)bb * 177 + 49) * HW + r] = enc4[(size_t)bb * 64 * HW + r];
  featw[((size_t)bb * 177 + 113) * HW + r] =
      enc4[(size_t)(2 + (bb & 1)) * 64 * HW + r];
}

// ---------------- im2col v2 (3x3 pad1 on 48x48, deform/zero) ---------------
template <int ZERO>
__global__ __launch_bounds__(256) void k_im2col2(
    const float* __restrict__ src, const float* __restrict__ off,
    ushort_t* __restrict__ dhi, ushort_t* __restrict__ dlo, int C) {
  __shared__ ushort_t LH[64][152];
  __shared__ ushort_t LL[64][152];
  const int b = blockIdx.z;
  const int t = threadIdx.x;
  const int nloc = t >> 2;
  const int csub = t & 3;
  const int n = blockIdx.x * 64 + nloc;
  const int c0 = blockIdx.y * 16 + csub * 4;
  const int K = C * 9;
  const int h = n / WWD, w = n - (n / WWD) * WWD;
  const float* sp = src + (size_t)b * C * HW;

  float wgt[9][4];
  int sid[9][4];
  if (ZERO) {
#pragma unroll
    for (int q = 0; q < 9; ++q) {
      int ki = q / 3, kj = q - (q / 3) * 3;
      int y = h - 1 + ki, x = w - 1 + kj;
      bool v = (y >= 0 && y < HH && x >= 0 && x < WWD);
      sid[q][0] = v ? y * WWD + x : 0;
      wgt[q][0] = v ? 1.f : 0.f;
    }
  } else {
#pragma unroll
    for (int q = 0; q < 9; ++q) {
      int ki = q / 3, kj = q - (q / 3) * 3;
      float dy = off[((size_t)(b * 9 + q) * 2 + 0) * HW + n];
      float dx = off[((size_t)(b * 9 + q) * 2 + 1) * HW + n];
      float py = (float)(h - 1 + ki) + dy;
      float px = (float)(w - 1 + kj) + dx;
      float fy = floorf(py), fx = floorf(px);
      float ay = py - fy, ax = px - fx;
      int y0 = (int)fy, x0 = (int)fx;
      int y1 = y0 + 1, x1 = x0 + 1;
      float w00 = (1.f - ay) * (1.f - ax), w01 = (1.f - ay) * ax;
      float w10 = ay * (1.f - ax), w11 = ay * ax;
      bool vy0 = (y0 >= 0 && y0 < HH), vy1 = (y1 >= 0 && y1 < HH);
      bool vx0 = (x0 >= 0 && x0 < WWD), vx1 = (x1 >= 0 && x1 < WWD);
      int cy0 = min(max(y0, 0), HH - 1), cy1 = min(max(y1, 0), HH - 1);
      int cx0 = min(max(x0, 0), WWD - 1), cx1 = min(max(x1, 0), WWD - 1);
      sid[q][0] = cy0 * WWD + cx0;
      sid[q][1] = cy0 * WWD + cx1;
      sid[q][2] = cy1 * WWD + cx0;
      sid[q][3] = cy1 * WWD + cx1;
      wgt[q][0] = (vy0 && vx0) ? w00 : 0.f;
      wgt[q][1] = (vy0 && vx1) ? w01 : 0.f;
      wgt[q][2] = (vy1 && vx0) ? w10 : 0.f;
      wgt[q][3] = (vy1 && vx1) ? w11 : 0.f;
    }
  }

#pragma unroll
  for (int cc = 0; cc < 4; ++cc) {
    int c = c0 + cc;
    const float* s = sp + (size_t)c * HW;
    int kb = (csub * 4 + cc) * 9;
#pragma unroll
    for (int q = 0; q < 9; ++q) {
      float v;
      if (ZERO)
        v = wgt[q][0] * s[sid[q][0]];
      else
        v = wgt[q][0] * s[sid[q][0]] + wgt[q][1] * s[sid[q][1]] +
            wgt[q][2] * s[sid[q][2]] + wgt[q][3] * s[sid[q][3]];
      ushort_t hi, lo;
      split_bf(v, hi, lo);
      LH[nloc][kb + q] = hi;
      LL[nloc][kb + q] = lo;
    }
  }
  __syncthreads();

  const size_t rowbase = (size_t)b * HW + blockIdx.x * 64;
  const int kt0 = blockIdx.y * 144;
  for (int idx = t; idx < 64 * 18; idx += 256) {
    int r = idx / 18, ch = idx - (idx / 18) * 18;
    uint4 vh = *(const uint4*)&LH[r][ch * 8];
    uint4 vl = *(const uint4*)&LL[r][ch * 8];
    size_t g = (rowbase + r) * K + kt0 + ch * 8;
    *(uint4*)(dhi + g) = vh;
    *(uint4*)(dlo + g) = vl;
  }
}

// ---------------- general im2col (any Ksz<=5/stride/pad, zero-offset) ------
__global__ __launch_bounds__(256) void k_im2col_g(
    const float* __restrict__ src, ushort_t* __restrict__ dhi,
    ushort_t* __restrict__ dlo, int C, int Hin, int Win, int Hout, int Wout,
    int Ksz, int stride, int pad, int KP) {
  __shared__ ushort_t LH[64][100];
  __shared__ ushort_t LL[64][100];
  const int b = blockIdx.z;
  const int t = threadIdx.x;
  const int nloc = t >> 2, csub = t & 3;
  const int n0 = blockIdx.x * 64;
  const int n = n0 + nloc;
  const int c = blockIdx.y * 4 + csub;
  const int N = Hout * Wout;
  const int K2 = Ksz * Ksz;
  const int h = n / Wout, w = n - (n / Wout) * Wout;
  const bool val = (c < C) && (n < N);
  const float* s = src + ((size_t)b * C + c) * Hin * Win;
  for (int q = 0; q < K2; ++q) {
    int ki = q / Ksz, kj = q - (q / Ksz) * Ksz;
    int y = h * stride + ki - pad, x = w * stride + kj - pad;
    float v = 0.f;
    if (val && y >= 0 && y < Hin && x >= 0 && x < Win) v = s[y * Win + x];
    ushort_t hi, lo;
    split_bf(v, hi, lo);
    LH[nloc][csub * K2 + q] = hi;
    LL[nloc][csub * K2 + q] = lo;
  }
  __syncthreads();
  const int Nc = gridDim.x * 64;
  const int rl = 4 * K2;
  const int kt0 = blockIdx.y * rl;
  const int nu2 = rl >> 2;
  for (int idx = t; idx < 64 * nu2; idx += 256) {
    int r = idx / nu2, ch = idx - (idx / nu2) * nu2;
    uint2 vh = *(const uint2*)&LH[r][ch * 4];
    uint2 vl = *(const uint2*)&LL[r][ch * 4];
    size_t g = ((size_t)b * Nc + n0 + r) * KP + kt0 + ch * 4;
    *(uint2*)(dhi + g) = vh;
    *(uint2*)(dlo + g) = vl;
  }
}

__global__ void k_blend(const float* __restrict__ d0, const float* __restrict__ d1,
                        const float* __restrict__ sw0, const float* __restrict__ sw1,
                        float* __restrict__ out) {
  int idx = blockIdx.x * blockDim.x + threadIdx.x;
  const int tot = BN * 256 * HW;
  if (idx >= tot) return;
  int b = idx / (256 * HW);
  int n = idx % HW;
  float s0 = sw0[b * HW + n], s1 = sw1[b * HW + n];
  const float eps = 1e-8f;
  float na = fmaxf(fabsf(s0), eps), nb = fmaxf(fabsf(s1), eps);
  float Wx = (s0 * s1) / (na * nb);
  float Wy = (s1 * s1) / (nb * nb);
  float mx = fmaxf(Wx, Wy);
  float e0 = expf(Wx - mx), e1 = expf(Wy - mx);
  float inv = 1.f / (e0 + e1);
  out[idx] = d0[idx] * (e0 * inv) + d1[idx] * (e1 * inv);
}

// ---------------- split-bf16 MFMA GEMM (128x128 tile) ----------------------
__global__ __launch_bounds__(256, 2) void k_mfma_nt(
    const ushort_t* __restrict__ Ahi, const ushort_t* __restrict__ Alo,
    const ushort_t* __restrict__ Bhi, const ushort_t* __restrict__ Blo,
    float* __restrict__ Cmat, int M, int N, int K, int abatch, int relu,
    int kslices) {
  __shared__ ushort_t AsH[128][40];
  __shared__ ushort_t AsL[128][40];
  __shared__ ushort_t BsH[128][40];
  __shared__ ushort_t BsL[128][40];
  const int zb = blockIdx.z;
  const int b = zb / kslices;
  const int slice = zb - b * kslices;
  const int nch = K >> 5;
  const int cper = (nch + kslices - 1) / kslices;
  const int kbeg = slice * cper * 32;
  const int kend = min(K, kbeg + cper * 32);
  const int n0 = blockIdx.x * 128;
  const int m0 = blockIdx.y * 128;
  const size_t aoff = abatch ? (size_t)b * M * K : (size_t)0;
  const ushort_t* AHp = Ahi + aoff;
  const ushort_t* ALp = Alo + aoff;
  const size_t boff = ((size_t)b * N + n0) * K;
  const ushort_t* BHp = Bhi + boff;
  const ushort_t* BLp = Blo + boff;
  const int t = threadIdx.x;
  const int lane = t & 63;
  const int wv = t >> 6;
  const int wm = wv >> 1, wn = wv & 1;
  const int l15 = lane & 15, quad = lane >> 4;

  const int arow = t >> 1;
  const int acnk = (t & 1) * 2;

  f32x4 acc[4][4];
  const f32x4 z4 = {0.f, 0.f, 0.f, 0.f};
#pragma unroll
  for (int i = 0; i < 4; ++i)
#pragma unroll
    for (int j = 0; j < 4; ++j) acc[i][j] = z4;

  const bool aval = (m0 + arow) < M;
  const uint4 zero16 = {0u, 0u, 0u, 0u};

  for (int k0 = kbeg; k0 < kend; k0 += 32) {
    const size_t arow_off = (size_t)(m0 + arow) * K + k0;
    uint4 ah0 = aval ? *(const uint4*)(AHp + arow_off + acnk * 8) : zero16;
    uint4 ah1 = aval ? *(const uint4*)(AHp + arow_off + (acnk + 1) * 8) : zero16;
    uint4 al0 = aval ? *(const uint4*)(ALp + arow_off + acnk * 8) : zero16;
    uint4 al1 = aval ? *(const uint4*)(ALp + arow_off + (acnk + 1) * 8) : zero16;
    const size_t brow_off = (size_t)arow * K + k0;
    uint4 bh0 = *(const uint4*)(BHp + brow_off + acnk * 8);
    uint4 bh1 = *(const uint4*)(BHp + brow_off + (acnk + 1) * 8);
    uint4 bl0 = *(const uint4*)(BLp + brow_off + acnk * 8);
    uint4 bl1 = *(const uint4*)(BLp + brow_off + (acnk + 1) * 8);
    *(uint4*)&AsH[arow][acnk * 8] = ah0;
    *(uint4*)&AsH[arow][(acnk + 1) * 8] = ah1;
    *(uint4*)&AsL[arow][acnk * 8] = al0;
    *(uint4*)&AsL[arow][(acnk + 1) * 8] = al1;
    *(uint4*)&BsH[arow][acnk * 8] = bh0;
    *(uint4*)&BsH[arow][(acnk + 1) * 8] = bh1;
    *(uint4*)&BsL[arow][acnk * 8] = bl0;
    *(uint4*)&BsL[arow][(acnk + 1) * 8] = bl1;
    __syncthreads();

    bf16x8 afh[4], afl[4], bfh[4], bfl[4];
#pragma unroll
    for (int mt = 0; mt < 4; ++mt) {
      afh[mt] = *(const bf16x8*)&AsH[wm * 64 + mt * 16 + l15][quad * 8];
      afl[mt] = *(const bf16x8*)&AsL[wm * 64 + mt * 16 + l15][quad * 8];
    }
#pragma unroll
    for (int nt = 0; nt < 4; ++nt) {
      bfh[nt] = *(const bf16x8*)&BsH[wn * 64 + nt * 16 + l15][quad * 8];
      bfl[nt] = *(const bf16x8*)&BsL[wn * 64 + nt * 16 + l15][quad * 8];
    }
#pragma unroll
    for (int mt = 0; mt < 4; ++mt)
#pragma unroll
      for (int nt = 0; nt < 4; ++nt) {
        acc[mt][nt] = __builtin_amdgcn_mfma_f32_16x16x32_bf16(
            afh[mt], bfh[nt], acc[mt][nt], 0, 0, 0);
        acc[mt][nt] = __builtin_amdgcn_mfma_f32_16x16x32_bf16(
            afh[mt], bfl[nt], acc[mt][nt], 0, 0, 0);
        acc[mt][nt] = __builtin_amdgcn_mfma_f32_16x16x32_bf16(
            afl[mt], bfh[nt], acc[mt][nt], 0, 0, 0);
      }
    __syncthreads();
  }

  float* Cp = Cmat + (size_t)b * M * N;
#pragma unroll
  for (int mt = 0; mt < 4; ++mt) {
#pragma unroll
    for (int nt = 0; nt < 4; ++nt) {
#pragma unroll
      for (int reg = 0; reg < 4; ++reg) {
        int m = m0 + wm * 64 + mt * 16 + quad * 4 + reg;
        if (m >= M) continue;
        int n = n0 + wn * 64 + nt * 16 + l15;
        if (kslices > 1) {
          atomicAdd(&Cp[(size_t)m * N + n], acc[mt][nt][reg]);
        } else {
          float v = acc[mt][nt][reg];
          if (relu) v = fmaxf(v, 0.f);
          Cp[(size_t)m * N + n] = v;
        }
      }
    }
  }
}

// ---------------- off-conv MFMA: implicit zero-offset im2col (3x3 p1) ------
__global__ __launch_bounds__(256) void k_off_mfma(
    const ushort_t* __restrict__ Ahi, const ushort_t* __restrict__ Alo,
    const float* __restrict__ src, float* __restrict__ Cmat,
    int M, int C, int kslices) {
  const int N = HW;
  const int K = C * 9;
  __shared__ ushort_t BsH[64][40];
  __shared__ ushort_t BsL[64][40];
  __shared__ int spix[64][10];
  const int zb = blockIdx.z;
  const int b = zb / kslices;
  const int slice = zb - b * kslices;
  const int Kc = K / kslices;
  const int kbeg = slice * Kc;
  const int n0 = blockIdx.x * 64;
  const int t = threadIdx.x;
  const int lane = t & 63;
  const int wv = t >> 6;
  const int l15 = lane & 15, quad = lane >> 4;
  const float* sp = src + (size_t)b * C * HW;

  for (int i = t; i < 64 * 9; i += 256) {
    int r = i / 9, q = i - (i / 9) * 9;
    int n = n0 + r;
    int h = n / WWD, w = n - (n / WWD) * WWD;
    int ki = q / 3, kj = q - (q / 3) * 3;
    int y = h - 1 + ki, x = w - 1 + kj;
    spix[r][q] = (y >= 0 && y < HH && x >= 0 && x < WWD) ? (y * WWD + x) : -1;
  }
  __syncthreads();

  const int srow = t >> 2;
  const int scnk = t & 3;

  f32x4 acc[2];
  const f32x4 z4 = {0.f, 0.f, 0.f, 0.f};
  acc[0] = z4;
  acc[1] = z4;
  const uint4 zero16 = {0u, 0u, 0u, 0u};

  for (int k0 = kbeg; k0 < kbeg + Kc; k0 += 32) {
    {
      int k = k0 + scnk * 8;
      int c = k / 9;
      int q = k - c * 9;
#pragma unroll
      for (int j = 0; j < 8; ++j) {
        int ix = spix[srow][q];
        float v = (ix >= 0) ? sp[(size_t)c * HW + ix] : 0.f;
        ushort_t hi, lo;
        split_bf(v, hi, lo);
        BsH[srow][scnk * 8 + j] = hi;
        BsL[srow][scnk * 8 + j] = lo;
        ++q;
        if (q == 9) { q = 0; ++c; }
      }
    }
    __syncthreads();

    bf16x8 afh[2], afl[2], bfh, bfl;
#pragma unroll
    for (int mt = 0; mt < 2; ++mt) {
      int m = mt * 16 + l15;
      bool v = m < M;
      uint4 ah = v ? *(const uint4*)(Ahi + (size_t)m * K + k0 + quad * 8) : zero16;
      uint4 al = v ? *(const uint4*)(Alo + (size_t)m * K + k0 + quad * 8) : zero16;
      afh[mt] = *(const bf16x8*)&ah;
      afl[mt] = *(const bf16x8*)&al;
    }
    bfh = *(const bf16x8*)&BsH[wv * 16 + l15][quad * 8];
    bfl = *(const bf16x8*)&BsL[wv * 16 + l15][quad * 8];
#pragma unroll
    for (int mt = 0; mt < 2; ++mt) {
      acc[mt] = __builtin_amdgcn_mfma_f32_16x16x32_bf16(afh[mt], bfh, acc[mt], 0, 0, 0);
      acc[mt] = __builtin_amdgcn_mfma_f32_16x16x32_bf16(afh[mt], bfl, acc[mt], 0, 0, 0);
      acc[mt] = __builtin_amdgcn_mfma_f32_16x16x32_bf16(afl[mt], bfh, acc[mt], 0, 0, 0);
    }
    __syncthreads();
  }

  float* Cp = Cmat + (size_t)b * M * N;
#pragma unroll
  for (int mt = 0; mt < 2; ++mt)
#pragma unroll
    for (int reg = 0; reg < 4; ++reg) {
      int m = mt * 16 + quad * 4 + reg;
      if (m >= M) continue;
      int n = n0 + wv * 16 + l15;
      atomicAdd(&Cp[(size_t)m * N + n], acc[mt][reg]);
    }
}

// ---------------- split-bf16 M32-tile GEMM over cols -----------------------
__global__ __launch_bounds__(256) void k_gemm_sk(
    const ushort_t* __restrict__ Ahi, const ushort_t* __restrict__ Alo,
    const ushort_t* __restrict__ Bhi, const ushort_t* __restrict__ Blo,
    const float* __restrict__ bias, float* __restrict__ Cmat,
    int M, int N, int Nc, int KP, int kslices, int relu) {
  __shared__ ushort_t BsH[64][40];
  __shared__ ushort_t BsL[64][40];
  const int zb = blockIdx.z;
  const int b = zb / kslices;
  const int slice = zb - b * kslices;
  const int nch = KP >> 5;
  const int cper = (nch + kslices - 1) / kslices;
  const int kbeg = slice * cper * 32;
  const int kend = min(KP, kbeg + cper * 32);
  const int n0 = blockIdx.x * 64;
  const int m0 = blockIdx.y * 32;
  const int t = threadIdx.x;
  const int lane = t & 63;
  const int wv = t >> 6;
  const int l15 = lane & 15, quad = lane >> 4;
  const ushort_t* BHp = Bhi + ((size_t)b * Nc + n0) * KP;
  const ushort_t* BLp = Blo + ((size_t)b * Nc + n0) * KP;
  const int srow = t >> 2, scnk = t & 3;

  f32x4 acc[2];
  const f32x4 z4 = {0.f, 0.f, 0.f, 0.f};
  acc[0] = z4;
  acc[1] = z4;
  const uint4 zero16 = {0u, 0u, 0u, 0u};

  for (int k0 = kbeg; k0 < kend; k0 += 32) {
    const size_t bo = (size_t)srow * KP + k0 + scnk * 8;
    uint4 bh = *(const uint4*)(BHp + bo);
    uint4 bl = *(const uint4*)(BLp + bo);
    *(uint4*)&BsH[srow][scnk * 8] = bh;
    *(uint4*)&BsL[srow][scnk * 8] = bl;
    __syncthreads();

    bf16x8 afh[2], afl[2], bfh, bfl;
#pragma unroll
    for (int mt = 0; mt < 2; ++mt) {
      int m = m0 + mt * 16 + l15;
      bool v = m < M;
      uint4 ah = v ? *(const uint4*)(Ahi + (size_t)m * KP + k0 + quad * 8) : zero16;
      uint4 al = v ? *(const uint4*)(Alo + (size_t)m * KP + k0 + quad * 8) : zero16;
      afh[mt] = *(const bf16x8*)&ah;
      afl[mt] = *(const bf16x8*)&al;
    }
    bfh = *(const bf16x8*)&BsH[wv * 16 + l15][quad * 8];
    bfl = *(const bf16x8*)&BsL[wv * 16 + l15][quad * 8];
#pragma unroll
    for (int mt = 0; mt < 2; ++mt) {
      acc[mt] = __builtin_amdgcn_mfma_f32_16x16x32_bf16(afh[mt], bfh, acc[mt], 0, 0, 0);
      acc[mt] = __builtin_amdgcn_mfma_f32_16x16x32_bf16(afh[mt], bfl, acc[mt], 0, 0, 0);
      acc[mt] = __builtin_amdgcn_mfma_f32_16x16x32_bf16(afl[mt], bfh, acc[mt], 0, 0, 0);
    }
    __syncthreads();
  }

  float* Cp = Cmat + (size_t)b * M * N;
  const int n = n0 + wv * 16 + l15;
  if (n < N) {
#pragma unroll
    for (int mt = 0; mt < 2; ++mt)
#pragma unroll
      for (int reg = 0; reg < 4; ++reg) {
        int m = m0 + mt * 16 + quad * 4 + reg;
        if (m >= M) continue;
        if (kslices > 1) {
          atomicAdd(&Cp[(size_t)m * N + n], acc[mt][reg]);
        } else {
          float v = acc[mt][reg];
          if (bias != nullptr) v += bias[m];
          if (relu) v = fmaxf(v, 0.f);
          Cp[(size_t)m * N + n] = v;
        }
      }
  }
}

// ---------------------------------------------------------------------------

extern "C" void kernel_launch(void* const* d_in, const int* in_sizes, int n_in,
                              void* d_out, int out_size, void* d_ws, size_t ws_size,
                              hipStream_t stream) {
  (void)in_sizes; (void)n_in; (void)out_size;

  const float* R0     = (const float*)d_in[0];
  const float* T0     = (const float*)d_in[1];
  const float* inp    = (const float*)d_in[2];
  const float* enc0_w = (const float*)d_in[3];
  const float* enc0_b = (const float*)d_in[4];
  const float* enc1_w = (const float*)d_in[5];
  const float* enc1_b = (const float*)d_in[6];
  const float* off_w[4] = {(const float*)d_in[7], (const float*)d_in[8],
                           (const float*)d_in[9], (const float*)d_in[10]};
  const float* def_w[3] = {(const float*)d_in[11], (const float*)d_in[12],
                           (const float*)d_in[13]};
  const float* w0a = (const float*)d_in[14];
  const float* w0b = (const float*)d_in[15];
  const float* w0c = (const float*)d_in[16];
  const float* w1a = (const float*)d_in[17];
  const float* w1b = (const float*)d_in[18];
  const float* w1c = (const float*)d_in[19];
  const float* wx_w  = (const float*)d_in[20];
  const float* wx_b  = (const float*)d_in[21];
  const float* wxf_w = (const float*)d_in[22];
  const float* wxf_b = (const float*)d_in[23];
  const float* s1w = (const float*)d_in[24];
  const float* s2w = (const float*)d_in[25];
  const float* s3w = (const float*)d_in[26];

  float* ws = (float*)d_ws;
  size_t used = 0;
  auto alloc = [&](size_t n) { float* p = ws + used; used += n; return p; };

  // fixed buffers (FIXED = 23,096,832 floats); variable: batch-4 stsn needs
  // 52,070,400 more floats (~301 MB total) -> runtime-gated.
  const size_t FIXED = 23096832, VAR4 = 52070400;
  const bool big = (FIXED + VAR4) * sizeof(float) <= ws_size;

  float* xy4     = alloc(2359296);
  float* xf      = xy4;
  float* yf      = xy4 + 1179648;
  float* enc4    = alloc(589824);
  float* xenc    = enc4;
  float* yenc    = enc4 + 294912;
  float* offsets4= alloc(165888);
  float* featw4  = alloc(1631232);
  float* featw24 = alloc(1631232);
  float* wb1     = alloc(147456);
  float* wb2     = alloc(36864);
  float* wb3     = alloc(36864);
  float* fw1     = alloc(1024);
  float* fw2     = alloc(1024);
  float* deform4 = alloc(2359296);
  float* sn1     = alloc(1179648);
  float* sn2     = alloc(589824);
  float* sw4     = alloc(9216);
  ushort_t *defw_h[3], *defw_l[3];
  for (int i = 0; i < 3; ++i) {
    defw_h[i] = (ushort_t*)alloc(1179648);
    defw_l[i] = (ushort_t*)alloc(1179648);
  }
  ushort_t *offw_h[4], *offw_l[4];
  for (int i = 0; i < 4; ++i) {
    offw_h[i] = (ushort_t*)alloc(41472);
    offw_l[i] = (ushort_t*)alloc(41472);
  }
  ushort_t* wxf_h = (ushort_t*)alloc(1179648);
  ushort_t* wxf_l = (ushort_t*)alloc(1179648);
  ushort_t* s1w_h = (ushort_t*)alloc(147456);
  ushort_t* s1w_l = (ushort_t*)alloc(147456);
  ushort_t* s2w_h = (ushort_t*)alloc(36864);
  ushort_t* s2w_l = (ushort_t*)alloc(36864);
  ushort_t* w0a_h = (ushort_t*)alloc(144384);
  ushort_t* w0a_l = (ushort_t*)alloc(144384);
  ushort_t* w1a_h = (ushort_t*)alloc(144384);
  ushort_t* w1a_l = (ushort_t*)alloc(144384);
  ushort_t* w0b_h = (ushort_t*)alloc(51200);
  ushort_t* w0b_l = (ushort_t*)alloc(51200);
  ushort_t* w1b_h = (ushort_t*)alloc(51200);
  ushort_t* w1b_l = (ushort_t*)alloc(51200);
  ushort_t* w0c_h = (ushort_t*)alloc(50976);
  ushort_t* w0c_l = (ushort_t*)alloc(50976);
  ushort_t* w1c_h = (ushort_t*)alloc(73728);
  ushort_t* w1c_l = (ushort_t*)alloc(73728);
  ushort_t* e0w_h = (ushort_t*)alloc(8192);
  ushort_t* e0w_l = (ushort_t*)alloc(8192);
  ushort_t* e1w_h = (ushort_t*)alloc(8192);
  ushort_t* e1w_l = (ushort_t*)alloc(8192);
  ushort_t* s3w_h = (ushort_t*)alloc(288);
  ushort_t* s3w_l = (ushort_t*)alloc(288);
  ushort_t* wxad_h = (ushort_t*)alloc(577728);
  ushort_t* wxad_l = (ushort_t*)alloc(577728);
  // variable-size stsn buffers
  float* featA = alloc(big ? 4718592 : 2359296);
  float* featB = alloc(big ? 4718592 : 2359296);
  float* offbN = alloc(big ? 165888 : 82944);
  ushort_t* cols_h = (ushort_t*)alloc(big ? 21233664 : 10616832);
  ushort_t* cols_l = (ushort_t*)alloc(big ? 21233664 : 10616832);
  if (used * sizeof(float) > ws_size) return;

  auto mfma = [&](const ushort_t* Ah, const ushort_t* Al, float* Cmat, int M,
                  int K, int abatch, int relu, int ks, int nb) {
    if (ks > 1)
      hipMemsetAsync(Cmat, 0, (size_t)nb * M * 2304 * sizeof(float), stream);
    dim3 grid(2304 / 128, (M + 127) / 128, nb * ks);
    k_mfma_nt<<<grid, 256, 0, stream>>>(Ah, Al, cols_h, cols_l, Cmat, M, 2304, K,
                                        abatch, relu, ks);
  };
  auto off_conv = [&](const ushort_t* Ah, const ushort_t* Al, const float* src,
                      float* Cmat, int C, int nb) {
    hipMemsetAsync(Cmat, 0, (size_t)nb * 18 * HW * sizeof(float), stream);
    dim3 grid(36, 1, nb * 8);
    k_off_mfma<<<grid, 256, 0, stream>>>(Ah, Al, src, Cmat, 18, C, 8);
  };
  auto im2col = [&](const float* src, const float* off, int C, int nb) {
    dim3 grid(36, C * 9 / 144, nb);
    if (off == nullptr)
      k_im2col2<1><<<grid, 256, 0, stream>>>(src, nullptr, cols_h, cols_l, C);
    else
      k_im2col2<0><<<grid, 256, 0, stream>>>(src, off, cols_h, cols_l, C);
  };
  auto im2col_g = [&](const float* src, int C, int Hin, int Win, int Hout,
                      int Wout, int Ksz, int stridec, int pad, int KP, int nb) {
    dim3 grid((Hout * Wout + 63) / 64, (C + 3) / 4, nb);
    k_im2col_g<<<grid, 256, 0, stream>>>(src, cols_h, cols_l, C, Hin, Win, Hout,
                                         Wout, Ksz, stridec, pad, KP);
  };
  auto gemm_sk = [&](const ushort_t* Ah, const ushort_t* Al, const float* bias,
                     float* Cmat, int M, int N, int KP, int kslices, int relu,
                     int nb) {
    int Nc = ((N + 63) / 64) * 64;
    if (kslices > 1)
      hipMemsetAsync(Cmat, 0, (size_t)nb * M * N * sizeof(float), stream);
    dim3 grid(Nc / 64, (M + 31) / 32, nb * kslices);
    k_gemm_sk<<<grid, 256, 0, stream>>>(Ah, Al, cols_h, cols_l, bias, Cmat, M,
                                        N, Nc, KP, kslices, relu);
  };

  // ---- weight conversions (merged) ----
  k_w2bz3<<<dim3((2359296 + 255) / 256, 1, 3), 256, 0, stream>>>(
      def_w[0], def_w[1], def_w[2], defw_h[0], defw_h[1], defw_h[2],
      defw_l[0], defw_l[1], defw_l[2], 2359296);
  k_w2bz4<<<dim3((82944 + 255) / 256, 1, 4), 256, 0, stream>>>(
      off_w[0], off_w[1], off_w[2], off_w[3], offw_h[0], offw_h[1], offw_h[2],
      offw_h[3], offw_l[0], offw_l[1], offw_l[2], offw_l[3], 82944);
  k_w2b<<<(294912 + 255) / 256, 256, 0, stream>>>(s1w, s1w_h, s1w_l, 294912);
  k_w2b<<<(73728 + 255) / 256, 256, 0, stream>>>(s2w, s2w_h, s2w_l, 73728);
  k_w2b_padz2<<<dim3((64 * 4512 + 255) / 256, 1, 2), 256, 0, stream>>>(
      w0a, w1a, w0a_h, w1a_h, w0a_l, w1a_l, 64, 64, 4425, 4512);
  k_w2b_padz2<<<dim3((64 * 1600 + 255) / 256, 1, 2), 256, 0, stream>>>(
      w0b, w1b, w0b_h, w1b_h, w0b_l, w1b_l, 64, 64, 1600, 1600);
  k_w2b_padz2<<<dim3((256 * 576 + 255) / 256, 1, 2), 256, 0, stream>>>(
      w0c, w1c, w0c_h, w1c_h, w0c_l, w1c_l, 177, 256, 576, 576);
  k_w2b_padz2<<<dim3((64 * 256 + 255) / 256, 1, 2), 256, 0, stream>>>(
      enc0_w, enc1_w, e0w_h, e1w_h, e0w_l, e1w_l, 64, 64, 256, 256);
  k_w2b_pad<<<(576 + 255) / 256, 256, 0, stream>>>(s3w, s3w_h, s3w_l, 1, 576, 576);

  // ---- split + encoders ----
  k_split_xy<<<4608, 256, 0, stream>>>(inp, xf, yf);
  im2col_g(xf, 256, 48, 48, 48, 48, 1, 1, 0, 256, BN);
  gemm_sk(e0w_h, e0w_l, enc0_b, xenc, 64, 2304, 256, 1, 0, BN);
  im2col_g(yf, 256, 48, 48, 48, 48, 1, 1, 0, 256, BN);
  gemm_sk(e1w_h, e1w_l, enc1_b, yenc, 64, 2304, 256, 1, 0, BN);

  // ---- stsn_offset: batch-4 merged chain if scratch allows, else batch-2 ---
  if (big) {
    k_concat512_4<<<(4 * 512 * HW) / 256, 256, 0, stream>>>(xy4, featA);
    float* cur = featA;
    float* nxt = featB;
    for (int i = 0; i < 3; ++i) {
      off_conv(offw_h[i], offw_l[i], cur, offbN, 512, 4);
      im2col(cur, offbN, 512, 4);
      mfma(defw_h[i], defw_l[i], nxt, 512, 4608, 0, 0, 4, 4);
      float* tmp = cur; cur = nxt; nxt = tmp;
    }
    off_conv(offw_h[3], offw_l[3], cur, offsets4, 512, 4);
  } else {
    auto stsn = [&](const float* srcA, const float* srcB, float* offset_out) {
      k_concat512<<<(BN * 512 * HW) / 256, 256, 0, stream>>>(srcA, srcB, featA);
      float* cur = featA;
      float* nxt = featB;
      for (int i = 0; i < 3; ++i) {
        off_conv(offw_h[i], offw_l[i], cur, offbN, 512, BN);
        im2col(cur, offbN, 512, BN);
        mfma(defw_h[i], defw_l[i], nxt, 512, 4608, 0, 0, 4, BN);
        float* tmp = cur; cur = nxt; nxt = tmp;
      }
      off_conv(offw_h[3], offw_l[3], cur, offset_out, 512, BN);
    };
    stsn(xf, yf, offsets4);
    stsn(yf, yf, offsets4 + 2 * 18 * HW);
  }

  // ---- astsn_weight + adaptive deform conv (batch-4) ----
  auto branch = [&](const float* fin, const ushort_t* wah, const ushort_t* wal,
                    const ushort_t* wbh, const ushort_t* wbl,
                    const ushort_t* wch, const ushort_t* wcl, int Mout,
                    float* fwout) {
    im2col_g(fin, 177, 48, 48, 24, 24, 5, 2, 2, 4512, 4);
    gemm_sk(wah, wal, nullptr, wb1, 64, 576, 4512, 8, 0, 4);
    k_relu<<<(4 * 64 * 576 + 255) / 256, 256, 0, stream>>>(wb1, 4 * 64 * 576);
    im2col_g(wb1, 64, 24, 24, 12, 12, 5, 2, 2, 1600, 4);
    gemm_sk(wbh, wbl, nullptr, wb2, 64, 144, 1600, 4, 0, 4);
    k_relu<<<(4 * 64 * 144 + 255) / 256, 256, 0, stream>>>(wb2, 4 * 64 * 144);
    im2col_g(wb2, 64, 12, 12, 6, 6, 3, 2, 1, 576, 4);
    gemm_sk(wch, wcl, nullptr, wb3, Mout, 36, 576, 2, 0, 4);
    k_mean<<<(4 * Mout + 255) / 256, 256, 0, stream>>>(wb3, fwout, 4 * Mout, 36);
  };

  k_correlation4<<<(4 * 49 * HW + 255) / 256, 256, 0, stream>>>(R0, T0, featw4);
  k_pack_enc4<<<(4 * 64 * HW + 255) / 256, 256, 0, stream>>>(enc4, featw4);
  branch(featw4, w0a_h, w0a_l, w0b_h, w0b_l, w0c_h, w0c_l, 177, fw1);
  k_w2b_fw_pad<<<(4 * 177 * 1632 + 255) / 256, 256, 0, stream>>>(
      wx_w, wx_b, fw1, wxad_h, wxad_l, 177, 1593, 1632, 4);
  im2col_g(featw4, 177, 48, 48, 48, 48, 3, 1, 1, 1632, 4);
  mfma(wxad_h, wxad_l, featw24, 177, 1632, 1, 0, 2, 4);
  k_relu<<<(4 * 177 * HW + 255) / 256, 256, 0, stream>>>(featw24, 4 * 177 * HW);
  branch(featw24, w1a_h, w1a_l, w1b_h, w1b_l, w1c_h, w1c_l, 256, fw2);
  k_w2b_fw<<<(4 * 256 * 2304 + 255) / 256, 256, 0, stream>>>(
      wxf_w, wxf_b, fw2, wxf_h, wxf_l, 256, 2304, 4);
  im2col(xy4, offsets4, 256, 4);
  mfma(wxf_h, wxf_l, deform4, 256, 2304, 1, 0, 2, 4);

  // ---- s_net (batch-4) ----
  im2col(deform4, nullptr, 256, 4);
  mfma(s1w_h, s1w_l, sn1, 128, 2304, 0, 0, 4, 4);
  k_relu<<<(4 * 128 * HW + 255) / 256, 256, 0, stream>>>(sn1, 4 * 128 * HW);
  im2col(sn1, nullptr, 128, 4);
  mfma(s2w_h, s2w_l, sn2, 64, 1152, 0, 0, 4, 4);
  k_relu<<<(4 * 64 * HW + 255) / 256, 256, 0, stream>>>(sn2, 4 * 64 * HW);
  im2col_g(sn2, 64, 48, 48, 48, 48, 3, 1, 1, 576, 4);
  gemm_sk(s3w_h, s3w_l, nullptr, sw4, 1, 2304, 576, 1, 1, 4);

  // ---- blend ----
  k_blend<<<4608, 256, 0, stream>>>(deform4, deform4 + 2 * 256 * HW, sw4,
                                    sw4 + 2 * HW, (float*)d_out);
}

// Round 3
// 2209.980 us; speedup vs baseline: 1.2661x; 1.1279x over previous
//
#include <hip/hip_runtime.h>
#include <stdint.h>

// ---------------------------------------------------------------------------
// Round 16: r13 structure restored (128x64 k_mfma_nt proven 127us; r15's
// 128x128 tile lost occupancy 35->18% and regressed). New: k_off_mfma
// B-staging remapped to lane=pixel (p=t&63, k-chunk=wave id) so every gather
// is one coalesced 64-lane stream for a single (c,q); spix table moved from
// LDS to 9 per-thread registers. Same arithmetic -> bit-identical output.
// ---------------------------------------------------------------------------

typedef unsigned short ushort_t;
typedef __attribute__((ext_vector_type(8))) short bf16x8;
typedef __attribute__((ext_vector_type(4))) float f32x4;

#define BN 2
#define HH 48
#define WWD 48
#define HW 2304

__device__ __forceinline__ float b2f(ushort_t h) {
  union { uint32_t u; float f; } v; v.u = ((uint32_t)h) << 16; return v.f;
}
__device__ __forceinline__ ushort_t f2b(float f) {
  union { float f; uint32_t u; } v; v.f = f;
  uint32_t u = v.u;
  uint32_t r = (u + 0x7fffu + ((u >> 16) & 1u)) >> 16;
  return (ushort_t)r;
}
__device__ __forceinline__ void split_bf(float v, ushort_t& hi, ushort_t& lo) {
  hi = f2b(v);
  lo = f2b(v - b2f(hi));
}

// ---------------- elementwise / packing kernels ----------------------------

__global__ void k_split_xy(const float* __restrict__ in, float* __restrict__ xf,
                           float* __restrict__ yf) {
  int idx = blockIdx.x * blockDim.x + threadIdx.x;
  const int tot = BN * 256 * HW;
  if (idx >= tot) return;
  int b = idx / (256 * HW);
  int r = idx - b * (256 * HW);
  xf[idx] = in[(size_t)(2 * b) * (256 * HW) + r];
  yf[idx] = in[(size_t)(2 * b + 1) * (256 * HW) + r];
}

__global__ void k_concat512(const float* __restrict__ a, const float* __restrict__ c2,
                            float* __restrict__ feat) {
  int idx = blockIdx.x * blockDim.x + threadIdx.x;
  const int tot = BN * 512 * HW;
  if (idx >= tot) return;
  int b = idx / (512 * HW);
  int r = idx - b * (512 * HW);
  int c = r / HW;
  int n = r - c * HW;
  feat[idx] = (c < 256) ? a[(b * 256 + c) * HW + n]
                        : c2[(b * 256 + (c - 256)) * HW + n];
}

// batch-4 concat: feat4[bb] = concat(xy4[bb], xy4[2+(bb&1)])
__global__ void k_concat512_4(const float* __restrict__ xy4,
                              float* __restrict__ feat) {
  int idx = blockIdx.x * blockDim.x + threadIdx.x;
  const int tot = 4 * 512 * HW;
  if (idx >= tot) return;
  int bb = idx / (512 * HW);
  int r = idx - bb * (512 * HW);
  int c = r / HW;
  int n = r - c * HW;
  feat[idx] = (c < 256)
                  ? xy4[((size_t)bb * 256 + c) * HW + n]
                  : xy4[((size_t)(2 + (bb & 1)) * 256 + (c - 256)) * HW + n];
}

__global__ void k_relu(float* __restrict__ p, int n) {
  int idx = blockIdx.x * blockDim.x + threadIdx.x;
  if (idx < n) p[idx] = fmaxf(p[idx], 0.f);
}

__global__ void k_mean(const float* __restrict__ src, float* __restrict__ dst,
                       int Mtot, int N) {
  int idx = blockIdx.x * blockDim.x + threadIdx.x;
  if (idx >= Mtot) return;
  const float* p = src + (size_t)idx * N;
  float s = 0.f;
  for (int i = 0; i < N; ++i) s += p[i];
  dst[idx] = s / (float)N;
}

__global__ void k_w2b(const float* __restrict__ w, ushort_t* __restrict__ ohi,
                      ushort_t* __restrict__ olo, int n) {
  int idx = blockIdx.x * blockDim.x + threadIdx.x;
  if (idx < n) split_bf(w[idx], ohi[idx], olo[idx]);
}

// z-merged conversions (same element count per z)
__global__ void k_w2bz3(const float* __restrict__ p0, const float* __restrict__ p1,
                        const float* __restrict__ p2, ushort_t* __restrict__ h0,
                        ushort_t* __restrict__ h1, ushort_t* __restrict__ h2,
                        ushort_t* __restrict__ l0, ushort_t* __restrict__ l1,
                        ushort_t* __restrict__ l2, int n) {
  int idx = blockIdx.x * blockDim.x + threadIdx.x;
  if (idx >= n) return;
  int z = blockIdx.z;
  const float* p = (z == 0) ? p0 : (z == 1) ? p1 : p2;
  ushort_t* h = (z == 0) ? h0 : (z == 1) ? h1 : h2;
  ushort_t* l = (z == 0) ? l0 : (z == 1) ? l1 : l2;
  split_bf(p[idx], h[idx], l[idx]);
}

__global__ void k_w2bz4(const float* __restrict__ p0, const float* __restrict__ p1,
                        const float* __restrict__ p2, const float* __restrict__ p3,
                        ushort_t* __restrict__ h0, ushort_t* __restrict__ h1,
                        ushort_t* __restrict__ h2, ushort_t* __restrict__ h3,
                        ushort_t* __restrict__ l0, ushort_t* __restrict__ l1,
                        ushort_t* __restrict__ l2, ushort_t* __restrict__ l3,
                        int n) {
  int idx = blockIdx.x * blockDim.x + threadIdx.x;
  if (idx >= n) return;
  int z = blockIdx.z;
  const float* p = (z == 0) ? p0 : (z == 1) ? p1 : (z == 2) ? p2 : p3;
  ushort_t* h = (z == 0) ? h0 : (z == 1) ? h1 : (z == 2) ? h2 : h3;
  ushort_t* l = (z == 0) ? l0 : (z == 1) ? l1 : (z == 2) ? l2 : l3;
  split_bf(p[idx], h[idx], l[idx]);
}

__global__ void k_w2b_pad(const float* __restrict__ w, ushort_t* __restrict__ ohi,
                          ushort_t* __restrict__ olo, int M, int K, int Kpad) {
  int idx = blockIdx.x * blockDim.x + threadIdx.x;
  if (idx >= M * Kpad) return;
  int m = idx / Kpad, k = idx - m * Kpad;
  float v = (k < K) ? w[(size_t)m * K + k] : 0.f;
  split_bf(v, ohi[idx], olo[idx]);
}

__global__ void k_w2b_padz2(const float* __restrict__ p0, const float* __restrict__ p1,
                            ushort_t* __restrict__ h0, ushort_t* __restrict__ h1,
                            ushort_t* __restrict__ l0, ushort_t* __restrict__ l1,
                            int M0, int M1, int K, int Kpad) {
  int idx = blockIdx.x * blockDim.x + threadIdx.x;
  int z = blockIdx.z;
  int M = z ? M1 : M0;
  if (idx >= M * Kpad) return;
  int m = idx / Kpad, k = idx - m * Kpad;
  const float* w = z ? p1 : p0;
  ushort_t* h = z ? h1 : h0;
  ushort_t* l = z ? l1 : l0;
  float v = (k < K) ? w[(size_t)m * K + k] : 0.f;
  split_bf(v, h[idx], l[idx]);
}

__global__ void k_w2b_fw(const float* __restrict__ w, const float* __restrict__ wb,
                         const float* __restrict__ fw, ushort_t* __restrict__ ohi,
                         ushort_t* __restrict__ olo, int M, int K, int NB) {
  int idx = blockIdx.x * blockDim.x + threadIdx.x;
  int tot = NB * M * K;
  if (idx >= tot) return;
  int b = idx / (M * K);
  int r = idx - b * (M * K);
  int m = r / K;
  split_bf(fw[b * M + m] * w[r] + wb[r], ohi[idx], olo[idx]);
}

__global__ void k_w2b_fw_pad(const float* __restrict__ w, const float* __restrict__ wb,
                             const float* __restrict__ fw, ushort_t* __restrict__ ohi,
                             ushort_t* __restrict__ olo, int M, int K, int Kpad,
                             int NB) {
  int idx = blockIdx.x * blockDim.x + threadIdx.x;
  int tot = NB * M * Kpad;
  if (idx >= tot) return;
  int b = idx / (M * Kpad);
  int r = idx - b * (M * Kpad);
  int m = r / Kpad;
  int k = r - m * Kpad;
  float v = 0.f;
  if (k < K) v = fw[b * M + m] * w[(size_t)m * K + k] + wb[(size_t)m * K + k];
  split_bf(v, ohi[idx], olo[idx]);
}

__global__ void k_correlation4(const float* __restrict__ R0,
                               const float* __restrict__ T0,
                               float* __restrict__ featw) {
  int idx = blockIdx.x * blockDim.x + threadIdx.x;
  const int tot = 4 * 49 * HW;
  if (idx >= tot) return;
  int n = idx % HW;
  int t = idx / HW;
  int d = t % 49;
  int bb = t / 49;
  int pass = bb >> 1, b = bb & 1;
  int dyi = d / 7, dxi = d - dyi * 7;
  int dy = 2 * (dyi - 3), dx = 2 * (dxi - 3);
  int h = n / WWD, w = n - h * WWD;
  int hb = h + dy, wb = w + dx;
  float s = 0.f;
  if (hb >= 0 && hb < HH && wb >= 0 && wb < WWD) {
    const float* ap = R0 + ((size_t)(b * 2 + pass) * 64) * HW + n;
    const float* bp = T0 + ((size_t)(b * 2 + 1) * 64) * HW + hb * WWD + wb;
#pragma unroll 8
    for (int c = 0; c < 64; ++c) s += ap[(size_t)c * HW] * bp[(size_t)c * HW];
  }
  featw[((size_t)bb * 177 + d) * HW + n] = s * (1.f / 64.f);
}

__global__ void k_pack_enc4(const float* __restrict__ enc4,
                            float* __restrict__ featw) {
  int idx = blockIdx.x * blockDim.x + threadIdx.x;
  const int tot = 4 * 64 * HW;
  if (idx >= tot) return;
  int bb = idx / (64 * HW);
  int r = idx - bb * (64 * HW);
  featw[((size_t)bb * 177 + 49) * HW + r] = enc4[(size_t)bb * 64 * HW + r];
  featw[((size_t)bb * 177 + 113) * HW + r] =
      enc4[(size_t)(2 + (bb & 1)) * 64 * HW + r];
}

// ---------------- im2col v2 (3x3 pad1 on 48x48, deform/zero) ---------------
template <int ZERO>
__global__ __launch_bounds__(256) void k_im2col2(
    const float* __restrict__ src, const float* __restrict__ off,
    ushort_t* __restrict__ dhi, ushort_t* __restrict__ dlo, int C) {
  __shared__ ushort_t LH[64][152];
  __shared__ ushort_t LL[64][152];
  const int b = blockIdx.z;
  const int t = threadIdx.x;
  const int nloc = t >> 2;
  const int csub = t & 3;
  const int n = blockIdx.x * 64 + nloc;
  const int c0 = blockIdx.y * 16 + csub * 4;
  const int K = C * 9;
  const int h = n / WWD, w = n - (n / WWD) * WWD;
  const float* sp = src + (size_t)b * C * HW;

  float wgt[9][4];
  int sid[9][4];
  if (ZERO) {
#pragma unroll
    for (int q = 0; q < 9; ++q) {
      int ki = q / 3, kj = q - (q / 3) * 3;
      int y = h - 1 + ki, x = w - 1 + kj;
      bool v = (y >= 0 && y < HH && x >= 0 && x < WWD);
      sid[q][0] = v ? y * WWD + x : 0;
      wgt[q][0] = v ? 1.f : 0.f;
    }
  } else {
#pragma unroll
    for (int q = 0; q < 9; ++q) {
      int ki = q / 3, kj = q - (q / 3) * 3;
      float dy = off[((size_t)(b * 9 + q) * 2 + 0) * HW + n];
      float dx = off[((size_t)(b * 9 + q) * 2 + 1) * HW + n];
      float py = (float)(h - 1 + ki) + dy;
      float px = (float)(w - 1 + kj) + dx;
      float fy = floorf(py), fx = floorf(px);
      float ay = py - fy, ax = px - fx;
      int y0 = (int)fy, x0 = (int)fx;
      int y1 = y0 + 1, x1 = x0 + 1;
      float w00 = (1.f - ay) * (1.f - ax), w01 = (1.f - ay) * ax;
      float w10 = ay * (1.f - ax), w11 = ay * ax;
      bool vy0 = (y0 >= 0 && y0 < HH), vy1 = (y1 >= 0 && y1 < HH);
      bool vx0 = (x0 >= 0 && x0 < WWD), vx1 = (x1 >= 0 && x1 < WWD);
      int cy0 = min(max(y0, 0), HH - 1), cy1 = min(max(y1, 0), HH - 1);
      int cx0 = min(max(x0, 0), WWD - 1), cx1 = min(max(x1, 0), WWD - 1);
      sid[q][0] = cy0 * WWD + cx0;
      sid[q][1] = cy0 * WWD + cx1;
      sid[q][2] = cy1 * WWD + cx0;
      sid[q][3] = cy1 * WWD + cx1;
      wgt[q][0] = (vy0 && vx0) ? w00 : 0.f;
      wgt[q][1] = (vy0 && vx1) ? w01 : 0.f;
      wgt[q][2] = (vy1 && vx0) ? w10 : 0.f;
      wgt[q][3] = (vy1 && vx1) ? w11 : 0.f;
    }
  }

#pragma unroll
  for (int cc = 0; cc < 4; ++cc) {
    int c = c0 + cc;
    const float* s = sp + (size_t)c * HW;
    int kb = (csub * 4 + cc) * 9;
#pragma unroll
    for (int q = 0; q < 9; ++q) {
      float v;
      if (ZERO)
        v = wgt[q][0] * s[sid[q][0]];
      else
        v = wgt[q][0] * s[sid[q][0]] + wgt[q][1] * s[sid[q][1]] +
            wgt[q][2] * s[sid[q][2]] + wgt[q][3] * s[sid[q][3]];
      ushort_t hi, lo;
      split_bf(v, hi, lo);
      LH[nloc][kb + q] = hi;
      LL[nloc][kb + q] = lo;
    }
  }
  __syncthreads();

  const size_t rowbase = (size_t)b * HW + blockIdx.x * 64;
  const int kt0 = blockIdx.y * 144;
  for (int idx = t; idx < 64 * 18; idx += 256) {
    int r = idx / 18, ch = idx - (idx / 18) * 18;
    uint4 vh = *(const uint4*)&LH[r][ch * 8];
    uint4 vl = *(const uint4*)&LL[r][ch * 8];
    size_t g = (rowbase + r) * K + kt0 + ch * 8;
    *(uint4*)(dhi + g) = vh;
    *(uint4*)(dlo + g) = vl;
  }
}

// ---------------- general im2col (any Ksz<=5/stride/pad, zero-offset) ------
__global__ __launch_bounds__(256) void k_im2col_g(
    const float* __restrict__ src, ushort_t* __restrict__ dhi,
    ushort_t* __restrict__ dlo, int C, int Hin, int Win, int Hout, int Wout,
    int Ksz, int stride, int pad, int KP) {
  __shared__ ushort_t LH[64][100];
  __shared__ ushort_t LL[64][100];
  const int b = blockIdx.z;
  const int t = threadIdx.x;
  const int nloc = t >> 2, csub = t & 3;
  const int n0 = blockIdx.x * 64;
  const int n = n0 + nloc;
  const int c = blockIdx.y * 4 + csub;
  const int N = Hout * Wout;
  const int K2 = Ksz * Ksz;
  const int h = n / Wout, w = n - (n / Wout) * Wout;
  const bool val = (c < C) && (n < N);
  const float* s = src + ((size_t)b * C + c) * Hin * Win;
  for (int q = 0; q < K2; ++q) {
    int ki = q / Ksz, kj = q - (q / Ksz) * Ksz;
    int y = h * stride + ki - pad, x = w * stride + kj - pad;
    float v = 0.f;
    if (val && y >= 0 && y < Hin && x >= 0 && x < Win) v = s[y * Win + x];
    ushort_t hi, lo;
    split_bf(v, hi, lo);
    LH[nloc][csub * K2 + q] = hi;
    LL[nloc][csub * K2 + q] = lo;
  }
  __syncthreads();
  const int Nc = gridDim.x * 64;
  const int rl = 4 * K2;
  const int kt0 = blockIdx.y * rl;
  const int nu2 = rl >> 2;
  for (int idx = t; idx < 64 * nu2; idx += 256) {
    int r = idx / nu2, ch = idx - (idx / nu2) * nu2;
    uint2 vh = *(const uint2*)&LH[r][ch * 4];
    uint2 vl = *(const uint2*)&LL[r][ch * 4];
    size_t g = ((size_t)b * Nc + n0 + r) * KP + kt0 + ch * 4;
    *(uint2*)(dhi + g) = vh;
    *(uint2*)(dlo + g) = vl;
  }
}

__global__ void k_blend(const float* __restrict__ d0, const float* __restrict__ d1,
                        const float* __restrict__ sw0, const float* __restrict__ sw1,
                        float* __restrict__ out) {
  int idx = blockIdx.x * blockDim.x + threadIdx.x;
  const int tot = BN * 256 * HW;
  if (idx >= tot) return;
  int b = idx / (256 * HW);
  int n = idx % HW;
  float s0 = sw0[b * HW + n], s1 = sw1[b * HW + n];
  const float eps = 1e-8f;
  float na = fmaxf(fabsf(s0), eps), nb = fmaxf(fabsf(s1), eps);
  float Wx = (s0 * s1) / (na * nb);
  float Wy = (s1 * s1) / (nb * nb);
  float mx = fmaxf(Wx, Wy);
  float e0 = expf(Wx - mx), e1 = expf(Wy - mx);
  float inv = 1.f / (e0 + e1);
  out[idx] = d0[idx] * (e0 * inv) + d1[idx] * (e1 * inv);
}

// ---------------- split-bf16 MFMA GEMM (128x64 tile, r13-proven) -----------
__global__ __launch_bounds__(256) void k_mfma_nt(
    const ushort_t* __restrict__ Ahi, const ushort_t* __restrict__ Alo,
    const ushort_t* __restrict__ Bhi, const ushort_t* __restrict__ Blo,
    float* __restrict__ Cmat, int M, int N, int K, int abatch, int relu,
    int kslices) {
  __shared__ ushort_t AsH[128][40];
  __shared__ ushort_t AsL[128][40];
  __shared__ ushort_t BsH[64][40];
  __shared__ ushort_t BsL[64][40];
  const int zb = blockIdx.z;
  const int b = zb / kslices;
  const int slice = zb - b * kslices;
  const int nch = K >> 5;
  const int cper = (nch + kslices - 1) / kslices;
  const int kbeg = slice * cper * 32;
  const int kend = min(K, kbeg + cper * 32);
  const int n0 = blockIdx.x * 64;
  const int m0 = blockIdx.y * 128;
  const size_t aoff = abatch ? (size_t)b * M * K : (size_t)0;
  const ushort_t* AHp = Ahi + aoff;
  const ushort_t* ALp = Alo + aoff;
  const size_t boff = ((size_t)b * N + n0) * K;
  const ushort_t* BHp = Bhi + boff;
  const ushort_t* BLp = Blo + boff;
  const int t = threadIdx.x;
  const int lane = t & 63;
  const int wv = t >> 6;
  const int wm = wv >> 1, wn = wv & 1;
  const int l15 = lane & 15, quad = lane >> 4;

  const int arow = t >> 1;
  const int acnk = (t & 1) * 2;
  const int brow = t >> 2;
  const int bcnk = t & 3;

  f32x4 acc[4][2];
  const f32x4 z4 = {0.f, 0.f, 0.f, 0.f};
#pragma unroll
  for (int i = 0; i < 4; ++i)
#pragma unroll
    for (int j = 0; j < 2; ++j) acc[i][j] = z4;

  const bool aval = (m0 + arow) < M;
  const uint4 zero16 = {0u, 0u, 0u, 0u};

  for (int k0 = kbeg; k0 < kend; k0 += 32) {
    const size_t arow_off = (size_t)(m0 + arow) * K + k0;
    uint4 ah0 = aval ? *(const uint4*)(AHp + arow_off + acnk * 8) : zero16;
    uint4 ah1 = aval ? *(const uint4*)(AHp + arow_off + (acnk + 1) * 8) : zero16;
    uint4 al0 = aval ? *(const uint4*)(ALp + arow_off + acnk * 8) : zero16;
    uint4 al1 = aval ? *(const uint4*)(ALp + arow_off + (acnk + 1) * 8) : zero16;
    const size_t brow_off = (size_t)brow * K + k0 + bcnk * 8;
    uint4 bh0 = *(const uint4*)(BHp + brow_off);
    uint4 bl0 = *(const uint4*)(BLp + brow_off);
    *(uint4*)&AsH[arow][acnk * 8] = ah0;
    *(uint4*)&AsH[arow][(acnk + 1) * 8] = ah1;
    *(uint4*)&AsL[arow][acnk * 8] = al0;
    *(uint4*)&AsL[arow][(acnk + 1) * 8] = al1;
    *(uint4*)&BsH[brow][bcnk * 8] = bh0;
    *(uint4*)&BsL[brow][bcnk * 8] = bl0;
    __syncthreads();

    bf16x8 afh[4], afl[4], bfh[2], bfl[2];
#pragma unroll
    for (int mt = 0; mt < 4; ++mt) {
      afh[mt] = *(const bf16x8*)&AsH[wm * 64 + mt * 16 + l15][quad * 8];
      afl[mt] = *(const bf16x8*)&AsL[wm * 64 + mt * 16 + l15][quad * 8];
    }
#pragma unroll
    for (int nt = 0; nt < 2; ++nt) {
      bfh[nt] = *(const bf16x8*)&BsH[wn * 32 + nt * 16 + l15][quad * 8];
      bfl[nt] = *(const bf16x8*)&BsL[wn * 32 + nt * 16 + l15][quad * 8];
    }
#pragma unroll
    for (int mt = 0; mt < 4; ++mt)
#pragma unroll
      for (int nt = 0; nt < 2; ++nt) {
        acc[mt][nt] = __builtin_amdgcn_mfma_f32_16x16x32_bf16(
            afh[mt], bfh[nt], acc[mt][nt], 0, 0, 0);
        acc[mt][nt] = __builtin_amdgcn_mfma_f32_16x16x32_bf16(
            afh[mt], bfl[nt], acc[mt][nt], 0, 0, 0);
        acc[mt][nt] = __builtin_amdgcn_mfma_f32_16x16x32_bf16(
            afl[mt], bfh[nt], acc[mt][nt], 0, 0, 0);
      }
    __syncthreads();
  }

  float* Cp = Cmat + (size_t)b * M * N;
#pragma unroll
  for (int mt = 0; mt < 4; ++mt) {
#pragma unroll
    for (int nt = 0; nt < 2; ++nt) {
#pragma unroll
      for (int reg = 0; reg < 4; ++reg) {
        int m = m0 + wm * 64 + mt * 16 + quad * 4 + reg;
        if (m >= M) continue;
        int n = n0 + wn * 32 + nt * 16 + l15;
        if (kslices > 1) {
          atomicAdd(&Cp[(size_t)m * N + n], acc[mt][nt][reg]);
        } else {
          float v = acc[mt][nt][reg];
          if (relu) v = fmaxf(v, 0.f);
          Cp[(size_t)m * N + n] = v;
        }
      }
    }
  }
}

// ---------------- off-conv MFMA: implicit zero-offset im2col (3x3 p1) ------
// B-staging: lane = pixel (p = t&63), k-chunk = wave id (t>>6). Every gather
// instruction is one coalesced 64-lane stream for a single (c,q); the 9
// 3x3-tap pixel ids live in per-thread registers (no LDS table).
__global__ __launch_bounds__(256) void k_off_mfma(
    const ushort_t* __restrict__ Ahi, const ushort_t* __restrict__ Alo,
    const float* __restrict__ src, float* __restrict__ Cmat,
    int M, int C, int kslices) {
  const int N = HW;
  const int K = C * 9;
  __shared__ ushort_t BsH[64][40];
  __shared__ ushort_t BsL[64][40];
  const int zb = blockIdx.z;
  const int b = zb / kslices;
  const int slice = zb - b * kslices;
  const int Kc = K / kslices;
  const int kbeg = slice * Kc;
  const int n0 = blockIdx.x * 64;
  const int t = threadIdx.x;
  const int lane = t & 63;
  const int wv = t >> 6;
  const int l15 = lane & 15, quad = lane >> 4;
  const float* sp = src + (size_t)b * C * HW;

  // per-thread tap table (p = lane pixel)
  const int p = t & 63;
  const int wch = t >> 6;  // k-chunk = wave id (wave-uniform)
  {
  }
  int pix[9];
  float msk[9];
  {
    int n = n0 + p;
    int h = n / WWD, w = n - (n / WWD) * WWD;
#pragma unroll
    for (int q = 0; q < 9; ++q) {
      int ki = q / 3, kj = q - (q / 3) * 3;
      int y = h - 1 + ki, x = w - 1 + kj;
      bool v = (y >= 0 && y < HH && x >= 0 && x < WWD);
      pix[q] = v ? (y * WWD + x) : 0;
      msk[q] = v ? 1.f : 0.f;
    }
  }

  f32x4 acc[2];
  const f32x4 z4 = {0.f, 0.f, 0.f, 0.f};
  acc[0] = z4;
  acc[1] = z4;
  const uint4 zero16 = {0u, 0u, 0u, 0u};

  for (int k0 = kbeg; k0 < kbeg + Kc; k0 += 32) {
    {
      int k = k0 + wch * 8;
      int c = k / 9;
      int q = k - c * 9;
      union { ushort_t u[8]; uint4 v; } ph, pl;
#pragma unroll
      for (int j = 0; j < 8; ++j) {
        float v = msk[q] * sp[(size_t)c * HW + pix[q]];
        split_bf(v, ph.u[j], pl.u[j]);
        ++q;
        if (q == 9) { q = 0; ++c; }
      }
      *(uint4*)&BsH[p][wch * 8] = ph.v;
      *(uint4*)&BsL[p][wch * 8] = pl.v;
    }
    __syncthreads();

    bf16x8 afh[2], afl[2], bfh, bfl;
#pragma unroll
    for (int mt = 0; mt < 2; ++mt) {
      int m = mt * 16 + l15;
      bool v = m < M;
      uint4 ah = v ? *(const uint4*)(Ahi + (size_t)m * K + k0 + quad * 8) : zero16;
      uint4 al = v ? *(const uint4*)(Alo + (size_t)m * K + k0 + quad * 8) : zero16;
      afh[mt] = *(const bf16x8*)&ah;
      afl[mt] = *(const bf16x8*)&al;
    }
    bfh = *(const bf16x8*)&BsH[wv * 16 + l15][quad * 8];
    bfl = *(const bf16x8*)&BsL[wv * 16 + l15][quad * 8];
#pragma unroll
    for (int mt = 0; mt < 2; ++mt) {
      acc[mt] = __builtin_amdgcn_mfma_f32_16x16x32_bf16(afh[mt], bfh, acc[mt], 0, 0, 0);
      acc[mt] = __builtin_amdgcn_mfma_f32_16x16x32_bf16(afh[mt], bfl, acc[mt], 0, 0, 0);
      acc[mt] = __builtin_amdgcn_mfma_f32_16x16x32_bf16(afl[mt], bfh, acc[mt], 0, 0, 0);
    }
    __syncthreads();
  }

  float* Cp = Cmat + (size_t)b * M * N;
#pragma unroll
  for (int mt = 0; mt < 2; ++mt)
#pragma unroll
    for (int reg = 0; reg < 4; ++reg) {
      int m = mt * 16 + quad * 4 + reg;
      if (m >= M) continue;
      int n = n0 + wv * 16 + l15;
      atomicAdd(&Cp[(size_t)m * N + n], acc[mt][reg]);
    }
}

// ---------------- split-bf16 M32-tile GEMM over cols -----------------------
__global__ __launch_bounds__(256) void k_gemm_sk(
    const ushort_t* __restrict__ Ahi, const ushort_t* __restrict__ Alo,
    const ushort_t* __restrict__ Bhi, const ushort_t* __restrict__ Blo,
    const float* __restrict__ bias, float* __restrict__ Cmat,
    int M, int N, int Nc, int KP, int kslices, int relu) {
  __shared__ ushort_t BsH[64][40];
  __shared__ ushort_t BsL[64][40];
  const int zb = blockIdx.z;
  const int b = zb / kslices;
  const int slice = zb - b * kslices;
  const int nch = KP >> 5;
  const int cper = (nch + kslices - 1) / kslices;
  const int kbeg = slice * cper * 32;
  const int kend = min(KP, kbeg + cper * 32);
  const int n0 = blockIdx.x * 64;
  const int m0 = blockIdx.y * 32;
  const int t = threadIdx.x;
  const int lane = t & 63;
  const int wv = t >> 6;
  const int l15 = lane & 15, quad = lane >> 4;
  const ushort_t* BHp = Bhi + ((size_t)b * Nc + n0) * KP;
  const ushort_t* BLp = Blo + ((size_t)b * Nc + n0) * KP;
  const int srow = t >> 2, scnk = t & 3;

  f32x4 acc[2];
  const f32x4 z4 = {0.f, 0.f, 0.f, 0.f};
  acc[0] = z4;
  acc[1] = z4;
  const uint4 zero16 = {0u, 0u, 0u, 0u};

  for (int k0 = kbeg; k0 < kend; k0 += 32) {
    const size_t bo = (size_t)srow * KP + k0 + scnk * 8;
    uint4 bh = *(const uint4*)(BHp + bo);
    uint4 bl = *(const uint4*)(BLp + bo);
    *(uint4*)&BsH[srow][scnk * 8] = bh;
    *(uint4*)&BsL[srow][scnk * 8] = bl;
    __syncthreads();

    bf16x8 afh[2], afl[2], bfh, bfl;
#pragma unroll
    for (int mt = 0; mt < 2; ++mt) {
      int m = m0 + mt * 16 + l15;
      bool v = m < M;
      uint4 ah = v ? *(const uint4*)(Ahi + (size_t)m * KP + k0 + quad * 8) : zero16;
      uint4 al = v ? *(const uint4*)(Alo + (size_t)m * KP + k0 + quad * 8) : zero16;
      afh[mt] = *(const bf16x8*)&ah;
      afl[mt] = *(const bf16x8*)&al;
    }
    bfh = *(const bf16x8*)&BsH[wv * 16 + l15][quad * 8];
    bfl = *(const bf16x8*)&BsL[wv * 16 + l15][quad * 8];
#pragma unroll
    for (int mt = 0; mt < 2; ++mt) {
      acc[mt] = __builtin_amdgcn_mfma_f32_16x16x32_bf16(afh[mt], bfh, acc[mt], 0, 0, 0);
      acc[mt] = __builtin_amdgcn_mfma_f32_16x16x32_bf16(afh[mt], bfl, acc[mt], 0, 0, 0);
      acc[mt] = __builtin_amdgcn_mfma_f32_16x16x32_bf16(afl[mt], bfh, acc[mt], 0, 0, 0);
    }
    __syncthreads();
  }

  float* Cp = Cmat + (size_t)b * M * N;
  const int n = n0 + wv * 16 + l15;
  if (n < N) {
#pragma unroll
    for (int mt = 0; mt < 2; ++mt)
#pragma unroll
      for (int reg = 0; reg < 4; ++reg) {
        int m = m0 + mt * 16 + quad * 4 + reg;
        if (m >= M) continue;
        if (kslices > 1) {
          atomicAdd(&Cp[(size_t)m * N + n], acc[mt][reg]);
        } else {
          float v = acc[mt][reg];
          if (bias != nullptr) v += bias[m];
          if (relu) v = fmaxf(v, 0.f);
          Cp[(size_t)m * N + n] = v;
        }
      }
  }
}

// ---------------------------------------------------------------------------

extern "C" void kernel_launch(void* const* d_in, const int* in_sizes, int n_in,
                              void* d_out, int out_size, void* d_ws, size_t ws_size,
                              hipStream_t stream) {
  (void)in_sizes; (void)n_in; (void)out_size;

  const float* R0     = (const float*)d_in[0];
  const float* T0     = (const float*)d_in[1];
  const float* inp    = (const float*)d_in[2];
  const float* enc0_w = (const float*)d_in[3];
  const float* enc0_b = (const float*)d_in[4];
  const float* enc1_w = (const float*)d_in[5];
  const float* enc1_b = (const float*)d_in[6];
  const float* off_w[4] = {(const float*)d_in[7], (const float*)d_in[8],
                           (const float*)d_in[9], (const float*)d_in[10]};
  const float* def_w[3] = {(const float*)d_in[11], (const float*)d_in[12],
                           (const float*)d_in[13]};
  const float* w0a = (const float*)d_in[14];
  const float* w0b = (const float*)d_in[15];
  const float* w0c = (const float*)d_in[16];
  const float* w1a = (const float*)d_in[17];
  const float* w1b = (const float*)d_in[18];
  const float* w1c = (const float*)d_in[19];
  const float* wx_w  = (const float*)d_in[20];
  const float* wx_b  = (const float*)d_in[21];
  const float* wxf_w = (const float*)d_in[22];
  const float* wxf_b = (const float*)d_in[23];
  const float* s1w = (const float*)d_in[24];
  const float* s2w = (const float*)d_in[25];
  const float* s3w = (const float*)d_in[26];

  float* ws = (float*)d_ws;
  size_t used = 0;
  auto alloc = [&](size_t n) { float* p = ws + used; used += n; return p; };

  // fixed buffers (FIXED = 23,096,832 floats); variable: batch-4 stsn needs
  // 52,070,400 more floats (~301 MB total) -> runtime-gated.
  const size_t FIXED = 23096832, VAR4 = 52070400;
  const bool big = (FIXED + VAR4) * sizeof(float) <= ws_size;

  float* xy4     = alloc(2359296);
  float* xf      = xy4;
  float* yf      = xy4 + 1179648;
  float* enc4    = alloc(589824);
  float* xenc    = enc4;
  float* yenc    = enc4 + 294912;
  float* offsets4= alloc(165888);
  float* featw4  = alloc(1631232);
  float* featw24 = alloc(1631232);
  float* wb1     = alloc(147456);
  float* wb2     = alloc(36864);
  float* wb3     = alloc(36864);
  float* fw1     = alloc(1024);
  float* fw2     = alloc(1024);
  float* deform4 = alloc(2359296);
  float* sn1     = alloc(1179648);
  float* sn2     = alloc(589824);
  float* sw4     = alloc(9216);
  ushort_t *defw_h[3], *defw_l[3];
  for (int i = 0; i < 3; ++i) {
    defw_h[i] = (ushort_t*)alloc(1179648);
    defw_l[i] = (ushort_t*)alloc(1179648);
  }
  ushort_t *offw_h[4], *offw_l[4];
  for (int i = 0; i < 4; ++i) {
    offw_h[i] = (ushort_t*)alloc(41472);
    offw_l[i] = (ushort_t*)alloc(41472);
  }
  ushort_t* wxf_h = (ushort_t*)alloc(1179648);
  ushort_t* wxf_l = (ushort_t*)alloc(1179648);
  ushort_t* s1w_h = (ushort_t*)alloc(147456);
  ushort_t* s1w_l = (ushort_t*)alloc(147456);
  ushort_t* s2w_h = (ushort_t*)alloc(36864);
  ushort_t* s2w_l = (ushort_t*)alloc(36864);
  ushort_t* w0a_h = (ushort_t*)alloc(144384);
  ushort_t* w0a_l = (ushort_t*)alloc(144384);
  ushort_t* w1a_h = (ushort_t*)alloc(144384);
  ushort_t* w1a_l = (ushort_t*)alloc(144384);
  ushort_t* w0b_h = (ushort_t*)alloc(51200);
  ushort_t* w0b_l = (ushort_t*)alloc(51200);
  ushort_t* w1b_h = (ushort_t*)alloc(51200);
  ushort_t* w1b_l = (ushort_t*)alloc(51200);
  ushort_t* w0c_h = (ushort_t*)alloc(50976);
  ushort_t* w0c_l = (ushort_t*)alloc(50976);
  ushort_t* w1c_h = (ushort_t*)alloc(73728);
  ushort_t* w1c_l = (ushort_t*)alloc(73728);
  ushort_t* e0w_h = (ushort_t*)alloc(8192);
  ushort_t* e0w_l = (ushort_t*)alloc(8192);
  ushort_t* e1w_h = (ushort_t*)alloc(8192);
  ushort_t* e1w_l = (ushort_t*)alloc(8192);
  ushort_t* s3w_h = (ushort_t*)alloc(288);
  ushort_t* s3w_l = (ushort_t*)alloc(288);
  ushort_t* wxad_h = (ushort_t*)alloc(577728);
  ushort_t* wxad_l = (ushort_t*)alloc(577728);
  // variable-size stsn buffers
  float* featA = alloc(big ? 4718592 : 2359296);
  float* featB = alloc(big ? 4718592 : 2359296);
  float* offbN = alloc(big ? 165888 : 82944);
  ushort_t* cols_h = (ushort_t*)alloc(big ? 21233664 : 10616832);
  ushort_t* cols_l = (ushort_t*)alloc(big ? 21233664 : 10616832);
  if (used * sizeof(float) > ws_size) return;

  auto mfma = [&](const ushort_t* Ah, const ushort_t* Al, float* Cmat, int M,
                  int K, int abatch, int relu, int ks, int nb) {
    if (ks > 1)
      hipMemsetAsync(Cmat, 0, (size_t)nb * M * 2304 * sizeof(float), stream);
    dim3 grid(2304 / 64, (M + 127) / 128, nb * ks);
    k_mfma_nt<<<grid, 256, 0, stream>>>(Ah, Al, cols_h, cols_l, Cmat, M, 2304, K,
                                        abatch, relu, ks);
  };
  auto off_conv = [&](const ushort_t* Ah, const ushort_t* Al, const float* src,
                      float* Cmat, int C, int nb) {
    hipMemsetAsync(Cmat, 0, (size_t)nb * 18 * HW * sizeof(float), stream);
    dim3 grid(36, 1, nb * 8);
    k_off_mfma<<<grid, 256, 0, stream>>>(Ah, Al, src, Cmat, 18, C, 8);
  };
  auto im2col = [&](const float* src, const float* off, int C, int nb) {
    dim3 grid(36, C * 9 / 144, nb);
    if (off == nullptr)
      k_im2col2<1><<<grid, 256, 0, stream>>>(src, nullptr, cols_h, cols_l, C);
    else
      k_im2col2<0><<<grid, 256, 0, stream>>>(src, off, cols_h, cols_l, C);
  };
  auto im2col_g = [&](const float* src, int C, int Hin, int Win, int Hout,
                      int Wout, int Ksz, int stridec, int pad, int KP, int nb) {
    dim3 grid((Hout * Wout + 63) / 64, (C + 3) / 4, nb);
    k_im2col_g<<<grid, 256, 0, stream>>>(src, cols_h, cols_l, C, Hin, Win, Hout,
                                         Wout, Ksz, stridec, pad, KP);
  };
  auto gemm_sk = [&](const ushort_t* Ah, const ushort_t* Al, const float* bias,
                     float* Cmat, int M, int N, int KP, int kslices, int relu,
                     int nb) {
    int Nc = ((N + 63) / 64) * 64;
    if (kslices > 1)
      hipMemsetAsync(Cmat, 0, (size_t)nb * M * N * sizeof(float), stream);
    dim3 grid(Nc / 64, (M + 31) / 32, nb * kslices);
    k_gemm_sk<<<grid, 256, 0, stream>>>(Ah, Al, cols_h, cols_l, bias, Cmat, M,
                                        N, Nc, KP, kslices, relu);
  };

  // ---- weight conversions (merged) ----
  k_w2bz3<<<dim3((2359296 + 255) / 256, 1, 3), 256, 0, stream>>>(
      def_w[0], def_w[1], def_w[2], defw_h[0], defw_h[1], defw_h[2],
      defw_l[0], defw_l[1], defw_l[2], 2359296);
  k_w2bz4<<<dim3((82944 + 255) / 256, 1, 4), 256, 0, stream>>>(
      off_w[0], off_w[1], off_w[2], off_w[3], offw_h[0], offw_h[1], offw_h[2],
      offw_h[3], offw_l[0], offw_l[1], offw_l[2], offw_l[3], 82944);
  k_w2b<<<(294912 + 255) / 256, 256, 0, stream>>>(s1w, s1w_h, s1w_l, 294912);
  k_w2b<<<(73728 + 255) / 256, 256, 0, stream>>>(s2w, s2w_h, s2w_l, 73728);
  k_w2b_padz2<<<dim3((64 * 4512 + 255) / 256, 1, 2), 256, 0, stream>>>(
      w0a, w1a, w0a_h, w1a_h, w0a_l, w1a_l, 64, 64, 4425, 4512);
  k_w2b_padz2<<<dim3((64 * 1600 + 255) / 256, 1, 2), 256, 0, stream>>>(
      w0b, w1b, w0b_h, w1b_h, w0b_l, w1b_l, 64, 64, 1600, 1600);
  k_w2b_padz2<<<dim3((256 * 576 + 255) / 256, 1, 2), 256, 0, stream>>>(
      w0c, w1c, w0c_h, w1c_h, w0c_l, w1c_l, 177, 256, 576, 576);
  k_w2b_padz2<<<dim3((64 * 256 + 255) / 256, 1, 2), 256, 0, stream>>>(
      enc0_w, enc1_w, e0w_h, e1w_h, e0w_l, e1w_l, 64, 64, 256, 256);
  k_w2b_pad<<<(576 + 255) / 256, 256, 0, stream>>>(s3w, s3w_h, s3w_l, 1, 576, 576);

  // ---- split + encoders ----
  k_split_xy<<<4608, 256, 0, stream>>>(inp, xf, yf);
  im2col_g(xf, 256, 48, 48, 48, 48, 1, 1, 0, 256, BN);
  gemm_sk(e0w_h, e0w_l, enc0_b, xenc, 64, 2304, 256, 1, 0, BN);
  im2col_g(yf, 256, 48, 48, 48, 48, 1, 1, 0, 256, BN);
  gemm_sk(e1w_h, e1w_l, enc1_b, yenc, 64, 2304, 256, 1, 0, BN);

  // ---- stsn_offset: batch-4 merged chain if scratch allows, else batch-2 ---
  if (big) {
    k_concat512_4<<<(4 * 512 * HW) / 256, 256, 0, stream>>>(xy4, featA);
    float* cur = featA;
    float* nxt = featB;
    for (int i = 0; i < 3; ++i) {
      off_conv(offw_h[i], offw_l[i], cur, offbN, 512, 4);
      im2col(cur, offbN, 512, 4);
      mfma(defw_h[i], defw_l[i], nxt, 512, 4608, 0, 0, 4, 4);
      float* tmp = cur; cur = nxt; nxt = tmp;
    }
    off_conv(offw_h[3], offw_l[3], cur, offsets4, 512, 4);
  } else {
    auto stsn = [&](const float* srcA, const float* srcB, float* offset_out) {
      k_concat512<<<(BN * 512 * HW) / 256, 256, 0, stream>>>(srcA, srcB, featA);
      float* cur = featA;
      float* nxt = featB;
      for (int i = 0; i < 3; ++i) {
        off_conv(offw_h[i], offw_l[i], cur, offbN, 512, BN);
        im2col(cur, offbN, 512, BN);
        mfma(defw_h[i], defw_l[i], nxt, 512, 4608, 0, 0, 4, BN);
        float* tmp = cur; cur = nxt; nxt = tmp;
      }
      off_conv(offw_h[3], offw_l[3], cur, offset_out, 512, BN);
    };
    stsn(xf, yf, offsets4);
    stsn(yf, yf, offsets4 + 2 * 18 * HW);
  }

  // ---- astsn_weight + adaptive deform conv (batch-4) ----
  auto branch = [&](const float* fin, const ushort_t* wah, const ushort_t* wal,
                    const ushort_t* wbh, const ushort_t* wbl,
                    const ushort_t* wch, const ushort_t* wcl, int Mout,
                    float* fwout) {
    im2col_g(fin, 177, 48, 48, 24, 24, 5, 2, 2, 4512, 4);
    gemm_sk(wah, wal, nullptr, wb1, 64, 576, 4512, 8, 0, 4);
    k_relu<<<(4 * 64 * 576 + 255) / 256, 256, 0, stream>>>(wb1, 4 * 64 * 576);
    im2col_g(wb1, 64, 24, 24, 12, 12, 5, 2, 2, 1600, 4);
    gemm_sk(wbh, wbl, nullptr, wb2, 64, 144, 1600, 4, 0, 4);
    k_relu<<<(4 * 64 * 144 + 255) / 256, 256, 0, stream>>>(wb2, 4 * 64 * 144);
    im2col_g(wb2, 64, 12, 12, 6, 6, 3, 2, 1, 576, 4);
    gemm_sk(wch, wcl, nullptr, wb3, Mout, 36, 576, 2, 0, 4);
    k_mean<<<(4 * Mout + 255) / 256, 256, 0, stream>>>(wb3, fwout, 4 * Mout, 36);
  };

  k_correlation4<<<(4 * 49 * HW + 255) / 256, 256, 0, stream>>>(R0, T0, featw4);
  k_pack_enc4<<<(4 * 64 * HW + 255) / 256, 256, 0, stream>>>(enc4, featw4);
  branch(featw4, w0a_h, w0a_l, w0b_h, w0b_l, w0c_h, w0c_l, 177, fw1);
  k_w2b_fw_pad<<<(4 * 177 * 1632 + 255) / 256, 256, 0, stream>>>(
      wx_w, wx_b, fw1, wxad_h, wxad_l, 177, 1593, 1632, 4);
  im2col_g(featw4, 177, 48, 48, 48, 48, 3, 1, 1, 1632, 4);
  mfma(wxad_h, wxad_l, featw24, 177, 1632, 1, 0, 2, 4);
  k_relu<<<(4 * 177 * HW + 255) / 256, 256, 0, stream>>>(featw24, 4 * 177 * HW);
  branch(featw24, w1a_h, w1a_l, w1b_h, w1b_l, w1c_h, w1c_l, 256, fw2);
  k_w2b_fw<<<(4 * 256 * 2304 + 255) / 256, 256, 0, stream>>>(
      wxf_w, wxf_b, fw2, wxf_h, wxf_l, 256, 2304, 4);
  im2col(xy4, offsets4, 256, 4);
  mfma(wxf_h, wxf_l, deform4, 256, 2304, 1, 0, 2, 4);

  // ---- s_net (batch-4) ----
  im2col(deform4, nullptr, 256, 4);
  mfma(s1w_h, s1w_l, sn1, 128, 2304, 0, 0, 4, 4);
  k_relu<<<(4 * 128 * HW + 255) / 256, 256, 0, stream>>>(sn1, 4 * 128 * HW);
  im2col(sn1, nullptr, 128, 4);
  mfma(s2w_h, s2w_l, sn2, 64, 1152, 0, 0, 4, 4);
  k_relu<<<(4 * 64 * HW + 255) / 256, 256, 0, stream>>>(sn2, 4 * 64 * HW);
  im2col_g(sn2, 64, 48, 48, 48, 48, 3, 1, 1, 576, 4);
  gemm_sk(s3w_h, s3w_l, nullptr, sw4, 1, 2304, 576, 1, 1, 4);

  // ---- blend ----
  k_blend<<<4608, 256, 0, stream>>>(deform4, deform4 + 2 * 256 * HW, sw4,
                                    sw4 + 2 * HW, (float*)d_out);
}

// Round 4
// 2185.707 us; speedup vs baseline: 1.2802x; 1.0111x over previous
//
#include <hip/hip_runtime.h>
#include <stdint.h>

// ---------------------------------------------------------------------------
// Round 17: T14 issue-early prefetch in all three MFMA kernels (next K-step's
// global loads / gathers hoisted into the MFMA phase via register staging;
// same barrier structure, LDS unchanged) -- attacks the measured 2-phase
// latency stall (MfmaUtil 20%, VALU 11%, HBM 23%, ~2.8 waves/SIMD: nothing
// saturated => serialized load latency). Plus ReLU fused into im2col readers
// (per-tap fmaxf before bilinear weighting == relu-then-sample, bit-identical)
// removing 7 k_relu dispatches and their memory round-trips.
// ---------------------------------------------------------------------------

typedef unsigned short ushort_t;
typedef __attribute__((ext_vector_type(8))) short bf16x8;
typedef __attribute__((ext_vector_type(4))) float f32x4;

#define BN 2
#define HH 48
#define WWD 48
#define HW 2304

__device__ __forceinline__ float b2f(ushort_t h) {
  union { uint32_t u; float f; } v; v.u = ((uint32_t)h) << 16; return v.f;
}
__device__ __forceinline__ ushort_t f2b(float f) {
  union { float f; uint32_t u; } v; v.f = f;
  uint32_t u = v.u;
  uint32_t r = (u + 0x7fffu + ((u >> 16) & 1u)) >> 16;
  return (ushort_t)r;
}
__device__ __forceinline__ void split_bf(float v, ushort_t& hi, ushort_t& lo) {
  hi = f2b(v);
  lo = f2b(v - b2f(hi));
}

// ---------------- elementwise / packing kernels ----------------------------

__global__ void k_split_xy(const float* __restrict__ in, float* __restrict__ xf,
                           float* __restrict__ yf) {
  int idx = blockIdx.x * blockDim.x + threadIdx.x;
  const int tot = BN * 256 * HW;
  if (idx >= tot) return;
  int b = idx / (256 * HW);
  int r = idx - b * (256 * HW);
  xf[idx] = in[(size_t)(2 * b) * (256 * HW) + r];
  yf[idx] = in[(size_t)(2 * b + 1) * (256 * HW) + r];
}

__global__ void k_concat512(const float* __restrict__ a, const float* __restrict__ c2,
                            float* __restrict__ feat) {
  int idx = blockIdx.x * blockDim.x + threadIdx.x;
  const int tot = BN * 512 * HW;
  if (idx >= tot) return;
  int b = idx / (512 * HW);
  int r = idx - b * (512 * HW);
  int c = r / HW;
  int n = r - c * HW;
  feat[idx] = (c < 256) ? a[(b * 256 + c) * HW + n]
                        : c2[(b * 256 + (c - 256)) * HW + n];
}

// batch-4 concat: feat4[bb] = concat(xy4[bb], xy4[2+(bb&1)])
__global__ void k_concat512_4(const float* __restrict__ xy4,
                              float* __restrict__ feat) {
  int idx = blockIdx.x * blockDim.x + threadIdx.x;
  const int tot = 4 * 512 * HW;
  if (idx >= tot) return;
  int bb = idx / (512 * HW);
  int r = idx - bb * (512 * HW);
  int c = r / HW;
  int n = r - c * HW;
  feat[idx] = (c < 256)
                  ? xy4[((size_t)bb * 256 + c) * HW + n]
                  : xy4[((size_t)(2 + (bb & 1)) * 256 + (c - 256)) * HW + n];
}

__global__ void k_mean(const float* __restrict__ src, float* __restrict__ dst,
                       int Mtot, int N) {
  int idx = blockIdx.x * blockDim.x + threadIdx.x;
  if (idx >= Mtot) return;
  const float* p = src + (size_t)idx * N;
  float s = 0.f;
  for (int i = 0; i < N; ++i) s += p[i];
  dst[idx] = s / (float)N;
}

__global__ void k_w2b(const float* __restrict__ w, ushort_t* __restrict__ ohi,
                      ushort_t* __restrict__ olo, int n) {
  int idx = blockIdx.x * blockDim.x + threadIdx.x;
  if (idx < n) split_bf(w[idx], ohi[idx], olo[idx]);
}

// z-merged conversions (same element count per z)
__global__ void k_w2bz3(const float* __restrict__ p0, const float* __restrict__ p1,
                        const float* __restrict__ p2, ushort_t* __restrict__ h0,
                        ushort_t* __restrict__ h1, ushort_t* __restrict__ h2,
                        ushort_t* __restrict__ l0, ushort_t* __restrict__ l1,
                        ushort_t* __restrict__ l2, int n) {
  int idx = blockIdx.x * blockDim.x + threadIdx.x;
  if (idx >= n) return;
  int z = blockIdx.z;
  const float* p = (z == 0) ? p0 : (z == 1) ? p1 : p2;
  ushort_t* h = (z == 0) ? h0 : (z == 1) ? h1 : h2;
  ushort_t* l = (z == 0) ? l0 : (z == 1) ? l1 : l2;
  split_bf(p[idx], h[idx], l[idx]);
}

__global__ void k_w2bz4(const float* __restrict__ p0, const float* __restrict__ p1,
                        const float* __restrict__ p2, const float* __restrict__ p3,
                        ushort_t* __restrict__ h0, ushort_t* __restrict__ h1,
                        ushort_t* __restrict__ h2, ushort_t* __restrict__ h3,
                        ushort_t* __restrict__ l0, ushort_t* __restrict__ l1,
                        ushort_t* __restrict__ l2, ushort_t* __restrict__ l3,
                        int n) {
  int idx = blockIdx.x * blockDim.x + threadIdx.x;
  if (idx >= n) return;
  int z = blockIdx.z;
  const float* p = (z == 0) ? p0 : (z == 1) ? p1 : (z == 2) ? p2 : p3;
  ushort_t* h = (z == 0) ? h0 : (z == 1) ? h1 : (z == 2) ? h2 : h3;
  ushort_t* l = (z == 0) ? l0 : (z == 1) ? l1 : (z == 2) ? l2 : l3;
  split_bf(p[idx], h[idx], l[idx]);
}

__global__ void k_w2b_pad(const float* __restrict__ w, ushort_t* __restrict__ ohi,
                          ushort_t* __restrict__ olo, int M, int K, int Kpad) {
  int idx = blockIdx.x * blockDim.x + threadIdx.x;
  if (idx >= M * Kpad) return;
  int m = idx / Kpad, k = idx - m * Kpad;
  float v = (k < K) ? w[(size_t)m * K + k] : 0.f;
  split_bf(v, ohi[idx], olo[idx]);
}

__global__ void k_w2b_padz2(const float* __restrict__ p0, const float* __restrict__ p1,
                            ushort_t* __restrict__ h0, ushort_t* __restrict__ h1,
                            ushort_t* __restrict__ l0, ushort_t* __restrict__ l1,
                            int M0, int M1, int K, int Kpad) {
  int idx = blockIdx.x * blockDim.x + threadIdx.x;
  int z = blockIdx.z;
  int M = z ? M1 : M0;
  if (idx >= M * Kpad) return;
  int m = idx / Kpad, k = idx - m * Kpad;
  const float* w = z ? p1 : p0;
  ushort_t* h = z ? h1 : h0;
  ushort_t* l = z ? l1 : l0;
  float v = (k < K) ? w[(size_t)m * K + k] : 0.f;
  split_bf(v, h[idx], l[idx]);
}

__global__ void k_w2b_fw(const float* __restrict__ w, const float* __restrict__ wb,
                         const float* __restrict__ fw, ushort_t* __restrict__ ohi,
                         ushort_t* __restrict__ olo, int M, int K, int NB) {
  int idx = blockIdx.x * blockDim.x + threadIdx.x;
  int tot = NB * M * K;
  if (idx >= tot) return;
  int b = idx / (M * K);
  int r = idx - b * (M * K);
  int m = r / K;
  split_bf(fw[b * M + m] * w[r] + wb[r], ohi[idx], olo[idx]);
}

__global__ void k_w2b_fw_pad(const float* __restrict__ w, const float* __restrict__ wb,
                             const float* __restrict__ fw, ushort_t* __restrict__ ohi,
                             ushort_t* __restrict__ olo, int M, int K, int Kpad,
                             int NB) {
  int idx = blockIdx.x * blockDim.x + threadIdx.x;
  int tot = NB * M * Kpad;
  if (idx >= tot) return;
  int b = idx / (M * Kpad);
  int r = idx - b * (M * Kpad);
  int m = r / Kpad;
  int k = r - m * Kpad;
  float v = 0.f;
  if (k < K) v = fw[b * M + m] * w[(size_t)m * K + k] + wb[(size_t)m * K + k];
  split_bf(v, ohi[idx], olo[idx]);
}

__global__ void k_correlation4(const float* __restrict__ R0,
                               const float* __restrict__ T0,
                               float* __restrict__ featw) {
  int idx = blockIdx.x * blockDim.x + threadIdx.x;
  const int tot = 4 * 49 * HW;
  if (idx >= tot) return;
  int n = idx % HW;
  int t = idx / HW;
  int d = t % 49;
  int bb = t / 49;
  int pass = bb >> 1, b = bb & 1;
  int dyi = d / 7, dxi = d - dyi * 7;
  int dy = 2 * (dyi - 3), dx = 2 * (dxi - 3);
  int h = n / WWD, w = n - h * WWD;
  int hb = h + dy, wb = w + dx;
  float s = 0.f;
  if (hb >= 0 && hb < HH && wb >= 0 && wb < WWD) {
    const float* ap = R0 + ((size_t)(b * 2 + pass) * 64) * HW + n;
    const float* bp = T0 + ((size_t)(b * 2 + 1) * 64) * HW + hb * WWD + wb;
#pragma unroll 8
    for (int c = 0; c < 64; ++c) s += ap[(size_t)c * HW] * bp[(size_t)c * HW];
  }
  featw[((size_t)bb * 177 + d) * HW + n] = s * (1.f / 64.f);
}

__global__ void k_pack_enc4(const float* __restrict__ enc4,
                            float* __restrict__ featw) {
  int idx = blockIdx.x * blockDim.x + threadIdx.x;
  const int tot = 4 * 64 * HW;
  if (idx >= tot) return;
  int bb = idx / (64 * HW);
  int r = idx - bb * (64 * HW);
  featw[((size_t)bb * 177 + 49) * HW + r] = enc4[(size_t)bb * 64 * HW + r];
  featw[((size_t)bb * 177 + 113) * HW + r] =
      enc4[(size_t)(2 + (bb & 1)) * 64 * HW + r];
}

// ---------------- im2col v2 (3x3 pad1 on 48x48, deform/zero) ---------------
// relu: apply fmaxf(.,0) to each tap load (== im2col of relu'd map).
template <int ZERO>
__global__ __launch_bounds__(256) void k_im2col2(
    const float* __restrict__ src, const float* __restrict__ off,
    ushort_t* __restrict__ dhi, ushort_t* __restrict__ dlo, int C, int relu) {
  __shared__ ushort_t LH[64][152];
  __shared__ ushort_t LL[64][152];
  const int b = blockIdx.z;
  const int t = threadIdx.x;
  const int nloc = t >> 2;
  const int csub = t & 3;
  const int n = blockIdx.x * 64 + nloc;
  const int c0 = blockIdx.y * 16 + csub * 4;
  const int K = C * 9;
  const int h = n / WWD, w = n - (n / WWD) * WWD;
  const float* sp = src + (size_t)b * C * HW;

  float wgt[9][4];
  int sid[9][4];
  if (ZERO) {
#pragma unroll
    for (int q = 0; q < 9; ++q) {
      int ki = q / 3, kj = q - (q / 3) * 3;
      int y = h - 1 + ki, x = w - 1 + kj;
      bool v = (y >= 0 && y < HH && x >= 0 && x < WWD);
      sid[q][0] = v ? y * WWD + x : 0;
      wgt[q][0] = v ? 1.f : 0.f;
    }
  } else {
#pragma unroll
    for (int q = 0; q < 9; ++q) {
      int ki = q / 3, kj = q - (q / 3) * 3;
      float dy = off[((size_t)(b * 9 + q) * 2 + 0) * HW + n];
      float dx = off[((size_t)(b * 9 + q) * 2 + 1) * HW + n];
      float py = (float)(h - 1 + ki) + dy;
      float px = (float)(w - 1 + kj) + dx;
      float fy = floorf(py), fx = floorf(px);
      float ay = py - fy, ax = px - fx;
      int y0 = (int)fy, x0 = (int)fx;
      int y1 = y0 + 1, x1 = x0 + 1;
      float w00 = (1.f - ay) * (1.f - ax), w01 = (1.f - ay) * ax;
      float w10 = ay * (1.f - ax), w11 = ay * ax;
      bool vy0 = (y0 >= 0 && y0 < HH), vy1 = (y1 >= 0 && y1 < HH);
      bool vx0 = (x0 >= 0 && x0 < WWD), vx1 = (x1 >= 0 && x1 < WWD);
      int cy0 = min(max(y0, 0), HH - 1), cy1 = min(max(y1, 0), HH - 1);
      int cx0 = min(max(x0, 0), WWD - 1), cx1 = min(max(x1, 0), WWD - 1);
      sid[q][0] = cy0 * WWD + cx0;
      sid[q][1] = cy0 * WWD + cx1;
      sid[q][2] = cy1 * WWD + cx0;
      sid[q][3] = cy1 * WWD + cx1;
      wgt[q][0] = (vy0 && vx0) ? w00 : 0.f;
      wgt[q][1] = (vy0 && vx1) ? w01 : 0.f;
      wgt[q][2] = (vy1 && vx0) ? w10 : 0.f;
      wgt[q][3] = (vy1 && vx1) ? w11 : 0.f;
    }
  }

#pragma unroll
  for (int cc = 0; cc < 4; ++cc) {
    int c = c0 + cc;
    const float* s = sp + (size_t)c * HW;
    int kb = (csub * 4 + cc) * 9;
#pragma unroll
    for (int q = 0; q < 9; ++q) {
      float v;
      if (ZERO) {
        float t0 = s[sid[q][0]];
        if (relu) t0 = fmaxf(t0, 0.f);
        v = wgt[q][0] * t0;
      } else {
        float t0 = s[sid[q][0]], t1 = s[sid[q][1]];
        float t2 = s[sid[q][2]], t3 = s[sid[q][3]];
        if (relu) {
          t0 = fmaxf(t0, 0.f); t1 = fmaxf(t1, 0.f);
          t2 = fmaxf(t2, 0.f); t3 = fmaxf(t3, 0.f);
        }
        v = wgt[q][0] * t0 + wgt[q][1] * t1 + wgt[q][2] * t2 + wgt[q][3] * t3;
      }
      ushort_t hi, lo;
      split_bf(v, hi, lo);
      LH[nloc][kb + q] = hi;
      LL[nloc][kb + q] = lo;
    }
  }
  __syncthreads();

  const size_t rowbase = (size_t)b * HW + blockIdx.x * 64;
  const int kt0 = blockIdx.y * 144;
  for (int idx = t; idx < 64 * 18; idx += 256) {
    int r = idx / 18, ch = idx - (idx / 18) * 18;
    uint4 vh = *(const uint4*)&LH[r][ch * 8];
    uint4 vl = *(const uint4*)&LL[r][ch * 8];
    size_t g = (rowbase + r) * K + kt0 + ch * 8;
    *(uint4*)(dhi + g) = vh;
    *(uint4*)(dlo + g) = vl;
  }
}

// ---------------- general im2col (any Ksz<=5/stride/pad, zero-offset) ------
__global__ __launch_bounds__(256) void k_im2col_g(
    const float* __restrict__ src, ushort_t* __restrict__ dhi,
    ushort_t* __restrict__ dlo, int C, int Hin, int Win, int Hout, int Wout,
    int Ksz, int stride, int pad, int KP, int relu) {
  __shared__ ushort_t LH[64][100];
  __shared__ ushort_t LL[64][100];
  const int b = blockIdx.z;
  const int t = threadIdx.x;
  const int nloc = t >> 2, csub = t & 3;
  const int n0 = blockIdx.x * 64;
  const int n = n0 + nloc;
  const int c = blockIdx.y * 4 + csub;
  const int N = Hout * Wout;
  const int K2 = Ksz * Ksz;
  const int h = n / Wout, w = n - (n / Wout) * Wout;
  const bool val = (c < C) && (n < N);
  const float* s = src + ((size_t)b * C + c) * Hin * Win;
  for (int q = 0; q < K2; ++q) {
    int ki = q / Ksz, kj = q - (q / Ksz) * Ksz;
    int y = h * stride + ki - pad, x = w * stride + kj - pad;
    float v = 0.f;
    if (val && y >= 0 && y < Hin && x >= 0 && x < Win) v = s[y * Win + x];
    if (relu) v = fmaxf(v, 0.f);
    ushort_t hi, lo;
    split_bf(v, hi, lo);
    LH[nloc][csub * K2 + q] = hi;
    LL[nloc][csub * K2 + q] = lo;
  }
  __syncthreads();
  const int Nc = gridDim.x * 64;
  const int rl = 4 * K2;
  const int kt0 = blockIdx.y * rl;
  const int nu2 = rl >> 2;
  for (int idx = t; idx < 64 * nu2; idx += 256) {
    int r = idx / nu2, ch = idx - (idx / nu2) * nu2;
    uint2 vh = *(const uint2*)&LH[r][ch * 4];
    uint2 vl = *(const uint2*)&LL[r][ch * 4];
    size_t g = ((size_t)b * Nc + n0 + r) * KP + kt0 + ch * 4;
    *(uint2*)(dhi + g) = vh;
    *(uint2*)(dlo + g) = vl;
  }
}

__global__ void k_blend(const float* __restrict__ d0, const float* __restrict__ d1,
                        const float* __restrict__ sw0, const float* __restrict__ sw1,
                        float* __restrict__ out) {
  int idx = blockIdx.x * blockDim.x + threadIdx.x;
  const int tot = BN * 256 * HW;
  if (idx >= tot) return;
  int b = idx / (256 * HW);
  int n = idx % HW;
  float s0 = sw0[b * HW + n], s1 = sw1[b * HW + n];
  const float eps = 1e-8f;
  float na = fmaxf(fabsf(s0), eps), nb = fmaxf(fabsf(s1), eps);
  float Wx = (s0 * s1) / (na * nb);
  float Wy = (s1 * s1) / (nb * nb);
  float mx = fmaxf(Wx, Wy);
  float e0 = expf(Wx - mx), e1 = expf(Wy - mx);
  float inv = 1.f / (e0 + e1);
  out[idx] = d0[idx] * (e0 * inv) + d1[idx] * (e1 * inv);
}

// ---------------- split-bf16 MFMA GEMM (128x64 tile, T14 prefetch) ---------
__global__ __launch_bounds__(256) void k_mfma_nt(
    const ushort_t* __restrict__ Ahi, const ushort_t* __restrict__ Alo,
    const ushort_t* __restrict__ Bhi, const ushort_t* __restrict__ Blo,
    float* __restrict__ Cmat, int M, int N, int K, int abatch, int relu,
    int kslices) {
  __shared__ ushort_t AsH[128][40];
  __shared__ ushort_t AsL[128][40];
  __shared__ ushort_t BsH[64][40];
  __shared__ ushort_t BsL[64][40];
  const int zb = blockIdx.z;
  const int b = zb / kslices;
  const int slice = zb - b * kslices;
  const int nch = K >> 5;
  const int cper = (nch + kslices - 1) / kslices;
  const int kbeg = slice * cper * 32;
  const int kend = min(K, kbeg + cper * 32);
  const int n0 = blockIdx.x * 64;
  const int m0 = blockIdx.y * 128;
  const size_t aoff = abatch ? (size_t)b * M * K : (size_t)0;
  const ushort_t* AHp = Ahi + aoff;
  const ushort_t* ALp = Alo + aoff;
  const size_t boff = ((size_t)b * N + n0) * K;
  const ushort_t* BHp = Bhi + boff;
  const ushort_t* BLp = Blo + boff;
  const int t = threadIdx.x;
  const int lane = t & 63;
  const int wv = t >> 6;
  const int wm = wv >> 1, wn = wv & 1;
  const int l15 = lane & 15, quad = lane >> 4;

  const int arow = t >> 1;
  const int acnk = (t & 1) * 2;
  const int brow = t >> 2;
  const int bcnk = t & 3;

  f32x4 acc[4][2];
  const f32x4 z4 = {0.f, 0.f, 0.f, 0.f};
#pragma unroll
  for (int i = 0; i < 4; ++i)
#pragma unroll
    for (int j = 0; j < 2; ++j) acc[i][j] = z4;

  const bool aval = (m0 + arow) < M;
  const uint4 zero16 = {0u, 0u, 0u, 0u};

  // T14: register staging; loads for step k+1 issued during MFMA of step k.
  uint4 ah0, ah1, al0, al1, bh0, bl0;
  auto loadk = [&](int k0) {
    const size_t arow_off = (size_t)(m0 + arow) * K + k0;
    ah0 = aval ? *(const uint4*)(AHp + arow_off + acnk * 8) : zero16;
    ah1 = aval ? *(const uint4*)(AHp + arow_off + (acnk + 1) * 8) : zero16;
    al0 = aval ? *(const uint4*)(ALp + arow_off + acnk * 8) : zero16;
    al1 = aval ? *(const uint4*)(ALp + arow_off + (acnk + 1) * 8) : zero16;
    const size_t brow_off = (size_t)brow * K + k0 + bcnk * 8;
    bh0 = *(const uint4*)(BHp + brow_off);
    bl0 = *(const uint4*)(BLp + brow_off);
  };
  loadk(kbeg);

  for (int k0 = kbeg; k0 < kend; k0 += 32) {
    *(uint4*)&AsH[arow][acnk * 8] = ah0;
    *(uint4*)&AsH[arow][(acnk + 1) * 8] = ah1;
    *(uint4*)&AsL[arow][acnk * 8] = al0;
    *(uint4*)&AsL[arow][(acnk + 1) * 8] = al1;
    *(uint4*)&BsH[brow][bcnk * 8] = bh0;
    *(uint4*)&BsL[brow][bcnk * 8] = bl0;
    __syncthreads();

    if (k0 + 32 < kend) loadk(k0 + 32);

    bf16x8 afh[4], afl[4], bfh[2], bfl[2];
#pragma unroll
    for (int mt = 0; mt < 4; ++mt) {
      afh[mt] = *(const bf16x8*)&AsH[wm * 64 + mt * 16 + l15][quad * 8];
      afl[mt] = *(const bf16x8*)&AsL[wm * 64 + mt * 16 + l15][quad * 8];
    }
#pragma unroll
    for (int nt = 0; nt < 2; ++nt) {
      bfh[nt] = *(const bf16x8*)&BsH[wn * 32 + nt * 16 + l15][quad * 8];
      bfl[nt] = *(const bf16x8*)&BsL[wn * 32 + nt * 16 + l15][quad * 8];
    }
#pragma unroll
    for (int mt = 0; mt < 4; ++mt)
#pragma unroll
      for (int nt = 0; nt < 2; ++nt) {
        acc[mt][nt] = __builtin_amdgcn_mfma_f32_16x16x32_bf16(
            afh[mt], bfh[nt], acc[mt][nt], 0, 0, 0);
        acc[mt][nt] = __builtin_amdgcn_mfma_f32_16x16x32_bf16(
            afh[mt], bfl[nt], acc[mt][nt], 0, 0, 0);
        acc[mt][nt] = __builtin_amdgcn_mfma_f32_16x16x32_bf16(
            afl[mt], bfh[nt], acc[mt][nt], 0, 0, 0);
      }
    __syncthreads();
  }

  float* Cp = Cmat + (size_t)b * M * N;
#pragma unroll
  for (int mt = 0; mt < 4; ++mt) {
#pragma unroll
    for (int nt = 0; nt < 2; ++nt) {
#pragma unroll
      for (int reg = 0; reg < 4; ++reg) {
        int m = m0 + wm * 64 + mt * 16 + quad * 4 + reg;
        if (m >= M) continue;
        int n = n0 + wn * 32 + nt * 16 + l15;
        if (kslices > 1) {
          atomicAdd(&Cp[(size_t)m * N + n], acc[mt][nt][reg]);
        } else {
          float v = acc[mt][nt][reg];
          if (relu) v = fmaxf(v, 0.f);
          Cp[(size_t)m * N + n] = v;
        }
      }
    }
  }
}

// ---------------- off-conv MFMA: implicit zero-offset im2col (3x3 p1) ------
// lane = pixel staging (coalesced per-(c,q) gathers) + T14 prefetch of the
// next step's 8 raw samples into registers during the MFMA phase.
__global__ __launch_bounds__(256) void k_off_mfma(
    const ushort_t* __restrict__ Ahi, const ushort_t* __restrict__ Alo,
    const float* __restrict__ src, float* __restrict__ Cmat,
    int M, int C, int kslices) {
  const int N = HW;
  const int K = C * 9;
  __shared__ ushort_t BsH[64][40];
  __shared__ ushort_t BsL[64][40];
  const int zb = blockIdx.z;
  const int b = zb / kslices;
  const int slice = zb - b * kslices;
  const int Kc = K / kslices;
  const int kbeg = slice * Kc;
  const int n0 = blockIdx.x * 64;
  const int t = threadIdx.x;
  const int lane = t & 63;
  const int wv = t >> 6;
  const int l15 = lane & 15, quad = lane >> 4;
  const float* sp = src + (size_t)b * C * HW;

  const int p = t & 63;
  const int wch = t >> 6;  // k-chunk = wave id (wave-uniform)
  int pix[9];
  float msk[9];
  {
    int n = n0 + p;
    int h = n / WWD, w = n - (n / WWD) * WWD;
#pragma unroll
    for (int q = 0; q < 9; ++q) {
      int ki = q / 3, kj = q - (q / 3) * 3;
      int y = h - 1 + ki, x = w - 1 + kj;
      bool v = (y >= 0 && y < HH && x >= 0 && x < WWD);
      pix[q] = v ? (y * WWD + x) : 0;
      msk[q] = v ? 1.f : 0.f;
    }
  }

  f32x4 acc[2];
  const f32x4 z4 = {0.f, 0.f, 0.f, 0.f};
  acc[0] = z4;
  acc[1] = z4;
  const uint4 zero16 = {0u, 0u, 0u, 0u};

  float pv[8];
  auto gath = [&](int k0) {
    int k = k0 + wch * 8;
    int c = k / 9;
    int q = k - c * 9;
#pragma unroll
    for (int j = 0; j < 8; ++j) {
      pv[j] = msk[q] * sp[(size_t)c * HW + pix[q]];
      ++q;
      if (q == 9) { q = 0; ++c; }
    }
  };
  gath(kbeg);

  for (int k0 = kbeg; k0 < kbeg + Kc; k0 += 32) {
    {
      union { ushort_t u[8]; uint4 v; } ph, pl;
#pragma unroll
      for (int j = 0; j < 8; ++j) split_bf(pv[j], ph.u[j], pl.u[j]);
      *(uint4*)&BsH[p][wch * 8] = ph.v;
      *(uint4*)&BsL[p][wch * 8] = pl.v;
    }
    __syncthreads();

    if (k0 + 32 < kbeg + Kc) gath(k0 + 32);

    bf16x8 afh[2], afl[2], bfh, bfl;
#pragma unroll
    for (int mt = 0; mt < 2; ++mt) {
      int m = mt * 16 + l15;
      bool v = m < M;
      uint4 ah = v ? *(const uint4*)(Ahi + (size_t)m * K + k0 + quad * 8) : zero16;
      uint4 al = v ? *(const uint4*)(Alo + (size_t)m * K + k0 + quad * 8) : zero16;
      afh[mt] = *(const bf16x8*)&ah;
      afl[mt] = *(const bf16x8*)&al;
    }
    bfh = *(const bf16x8*)&BsH[wv * 16 + l15][quad * 8];
    bfl = *(const bf16x8*)&BsL[wv * 16 + l15][quad * 8];
#pragma unroll
    for (int mt = 0; mt < 2; ++mt) {
      acc[mt] = __builtin_amdgcn_mfma_f32_16x16x32_bf16(afh[mt], bfh, acc[mt], 0, 0, 0);
      acc[mt] = __builtin_amdgcn_mfma_f32_16x16x32_bf16(afh[mt], bfl, acc[mt], 0, 0, 0);
      acc[mt] = __builtin_amdgcn_mfma_f32_16x16x32_bf16(afl[mt], bfh, acc[mt], 0, 0, 0);
    }
    __syncthreads();
  }

  float* Cp = Cmat + (size_t)b * M * N;
#pragma unroll
  for (int mt = 0; mt < 2; ++mt)
#pragma unroll
    for (int reg = 0; reg < 4; ++reg) {
      int m = mt * 16 + quad * 4 + reg;
      if (m >= M) continue;
      int n = n0 + wv * 16 + l15;
      atomicAdd(&Cp[(size_t)m * N + n], acc[mt][reg]);
    }
}

// ---------------- split-bf16 M32-tile GEMM over cols (T14 prefetch) --------
__global__ __launch_bounds__(256) void k_gemm_sk(
    const ushort_t* __restrict__ Ahi, const ushort_t* __restrict__ Alo,
    const ushort_t* __restrict__ Bhi, const ushort_t* __restrict__ Blo,
    const float* __restrict__ bias, float* __restrict__ Cmat,
    int M, int N, int Nc, int KP, int kslices, int relu) {
  __shared__ ushort_t BsH[64][40];
  __shared__ ushort_t BsL[64][40];
  const int zb = blockIdx.z;
  const int b = zb / kslices;
  const int slice = zb - b * kslices;
  const int nch = KP >> 5;
  const int cper = (nch + kslices - 1) / kslices;
  const int kbeg = slice * cper * 32;
  const int kend = min(KP, kbeg + cper * 32);
  const int n0 = blockIdx.x * 64;
  const int m0 = blockIdx.y * 32;
  const int t = threadIdx.x;
  const int lane = t & 63;
  const int wv = t >> 6;
  const int l15 = lane & 15, quad = lane >> 4;
  const ushort_t* BHp = Bhi + ((size_t)b * Nc + n0) * KP;
  const ushort_t* BLp = Blo + ((size_t)b * Nc + n0) * KP;
  const int srow = t >> 2, scnk = t & 3;

  f32x4 acc[2];
  const f32x4 z4 = {0.f, 0.f, 0.f, 0.f};
  acc[0] = z4;
  acc[1] = z4;
  const uint4 zero16 = {0u, 0u, 0u, 0u};

  uint4 bh, bl;
  auto loadb = [&](int k0) {
    const size_t bo = (size_t)srow * KP + k0 + scnk * 8;
    bh = *(const uint4*)(BHp + bo);
    bl = *(const uint4*)(BLp + bo);
  };
  loadb(kbeg);

  for (int k0 = kbeg; k0 < kend; k0 += 32) {
    *(uint4*)&BsH[srow][scnk * 8] = bh;
    *(uint4*)&BsL[srow][scnk * 8] = bl;
    __syncthreads();

    if (k0 + 32 < kend) loadb(k0 + 32);

    bf16x8 afh[2], afl[2], bfh, bfl;
#pragma unroll
    for (int mt = 0; mt < 2; ++mt) {
      int m = m0 + mt * 16 + l15;
      bool v = m < M;
      uint4 ah = v ? *(const uint4*)(Ahi + (size_t)m * KP + k0 + quad * 8) : zero16;
      uint4 al = v ? *(const uint4*)(Alo + (size_t)m * KP + k0 + quad * 8) : zero16;
      afh[mt] = *(const bf16x8*)&ah;
      afl[mt] = *(const bf16x8*)&al;
    }
    bfh = *(const bf16x8*)&BsH[wv * 16 + l15][quad * 8];
    bfl = *(const bf16x8*)&BsL[wv * 16 + l15][quad * 8];
#pragma unroll
    for (int mt = 0; mt < 2; ++mt) {
      acc[mt] = __builtin_amdgcn_mfma_f32_16x16x32_bf16(afh[mt], bfh, acc[mt], 0, 0, 0);
      acc[mt] = __builtin_amdgcn_mfma_f32_16x16x32_bf16(afh[mt], bfl, acc[mt], 0, 0, 0);
      acc[mt] = __builtin_amdgcn_mfma_f32_16x16x32_bf16(afl[mt], bfh, acc[mt], 0, 0, 0);
    }
    __syncthreads();
  }

  float* Cp = Cmat + (size_t)b * M * N;
  const int n = n0 + wv * 16 + l15;
  if (n < N) {
#pragma unroll
    for (int mt = 0; mt < 2; ++mt)
#pragma unroll
      for (int reg = 0; reg < 4; ++reg) {
        int m = m0 + mt * 16 + quad * 4 + reg;
        if (m >= M) continue;
        if (kslices > 1) {
          atomicAdd(&Cp[(size_t)m * N + n], acc[mt][reg]);
        } else {
          float v = acc[mt][reg];
          if (bias != nullptr) v += bias[m];
          if (relu) v = fmaxf(v, 0.f);
          Cp[(size_t)m * N + n] = v;
        }
      }
  }
}

// ---------------------------------------------------------------------------

extern "C" void kernel_launch(void* const* d_in, const int* in_sizes, int n_in,
                              void* d_out, int out_size, void* d_ws, size_t ws_size,
                              hipStream_t stream) {
  (void)in_sizes; (void)n_in; (void)out_size;

  const float* R0     = (const float*)d_in[0];
  const float* T0     = (const float*)d_in[1];
  const float* inp    = (const float*)d_in[2];
  const float* enc0_w = (const float*)d_in[3];
  const float* enc0_b = (const float*)d_in[4];
  const float* enc1_w = (const float*)d_in[5];
  const float* enc1_b = (const float*)d_in[6];
  const float* off_w[4] = {(const float*)d_in[7], (const float*)d_in[8],
                           (const float*)d_in[9], (const float*)d_in[10]};
  const float* def_w[3] = {(const float*)d_in[11], (const float*)d_in[12],
                           (const float*)d_in[13]};
  const float* w0a = (const float*)d_in[14];
  const float* w0b = (const float*)d_in[15];
  const float* w0c = (const float*)d_in[16];
  const float* w1a = (const float*)d_in[17];
  const float* w1b = (const float*)d_in[18];
  const float* w1c = (const float*)d_in[19];
  const float* wx_w  = (const float*)d_in[20];
  const float* wx_b  = (const float*)d_in[21];
  const float* wxf_w = (const float*)d_in[22];
  const float* wxf_b = (const float*)d_in[23];
  const float* s1w = (const float*)d_in[24];
  const float* s2w = (const float*)d_in[25];
  const float* s3w = (const float*)d_in[26];

  float* ws = (float*)d_ws;
  size_t used = 0;
  auto alloc = [&](size_t n) { float* p = ws + used; used += n; return p; };

  // fixed buffers (FIXED = 23,096,832 floats); variable: batch-4 stsn needs
  // 52,070,400 more floats (~301 MB total) -> runtime-gated.
  const size_t FIXED = 23096832, VAR4 = 52070400;
  const bool big = (FIXED + VAR4) * sizeof(float) <= ws_size;

  float* xy4     = alloc(2359296);
  float* xf      = xy4;
  float* yf      = xy4 + 1179648;
  float* enc4    = alloc(589824);
  float* xenc    = enc4;
  float* yenc    = enc4 + 294912;
  float* offsets4= alloc(165888);
  float* featw4  = alloc(1631232);
  float* featw24 = alloc(1631232);
  float* wb1     = alloc(147456);
  float* wb2     = alloc(36864);
  float* wb3     = alloc(36864);
  float* fw1     = alloc(1024);
  float* fw2     = alloc(1024);
  float* deform4 = alloc(2359296);
  float* sn1     = alloc(1179648);
  float* sn2     = alloc(589824);
  float* sw4     = alloc(9216);
  ushort_t *defw_h[3], *defw_l[3];
  for (int i = 0; i < 3; ++i) {
    defw_h[i] = (ushort_t*)alloc(1179648);
    defw_l[i] = (ushort_t*)alloc(1179648);
  }
  ushort_t *offw_h[4], *offw_l[4];
  for (int i = 0; i < 4; ++i) {
    offw_h[i] = (ushort_t*)alloc(41472);
    offw_l[i] = (ushort_t*)alloc(41472);
  }
  ushort_t* wxf_h = (ushort_t*)alloc(1179648);
  ushort_t* wxf_l = (ushort_t*)alloc(1179648);
  ushort_t* s1w_h = (ushort_t*)alloc(147456);
  ushort_t* s1w_l = (ushort_t*)alloc(147456);
  ushort_t* s2w_h = (ushort_t*)alloc(36864);
  ushort_t* s2w_l = (ushort_t*)alloc(36864);
  ushort_t* w0a_h = (ushort_t*)alloc(144384);
  ushort_t* w0a_l = (ushort_t*)alloc(144384);
  ushort_t* w1a_h = (ushort_t*)alloc(144384);
  ushort_t* w1a_l = (ushort_t*)alloc(144384);
  ushort_t* w0b_h = (ushort_t*)alloc(51200);
  ushort_t* w0b_l = (ushort_t*)alloc(51200);
  ushort_t* w1b_h = (ushort_t*)alloc(51200);
  ushort_t* w1b_l = (ushort_t*)alloc(51200);
  ushort_t* w0c_h = (ushort_t*)alloc(50976);
  ushort_t* w0c_l = (ushort_t*)alloc(50976);
  ushort_t* w1c_h = (ushort_t*)alloc(73728);
  ushort_t* w1c_l = (ushort_t*)alloc(73728);
  ushort_t* e0w_h = (ushort_t*)alloc(8192);
  ushort_t* e0w_l = (ushort_t*)alloc(8192);
  ushort_t* e1w_h = (ushort_t*)alloc(8192);
  ushort_t* e1w_l = (ushort_t*)alloc(8192);
  ushort_t* s3w_h = (ushort_t*)alloc(288);
  ushort_t* s3w_l = (ushort_t*)alloc(288);
  ushort_t* wxad_h = (ushort_t*)alloc(577728);
  ushort_t* wxad_l = (ushort_t*)alloc(577728);
  // variable-size stsn buffers
  float* featA = alloc(big ? 4718592 : 2359296);
  float* featB = alloc(big ? 4718592 : 2359296);
  float* offbN = alloc(big ? 165888 : 82944);
  ushort_t* cols_h = (ushort_t*)alloc(big ? 21233664 : 10616832);
  ushort_t* cols_l = (ushort_t*)alloc(big ? 21233664 : 10616832);
  if (used * sizeof(float) > ws_size) return;

  auto mfma = [&](const ushort_t* Ah, const ushort_t* Al, float* Cmat, int M,
                  int K, int abatch, int relu, int ks, int nb) {
    if (ks > 1)
      hipMemsetAsync(Cmat, 0, (size_t)nb * M * 2304 * sizeof(float), stream);
    dim3 grid(2304 / 64, (M + 127) / 128, nb * ks);
    k_mfma_nt<<<grid, 256, 0, stream>>>(Ah, Al, cols_h, cols_l, Cmat, M, 2304, K,
                                        abatch, relu, ks);
  };
  auto off_conv = [&](const ushort_t* Ah, const ushort_t* Al, const float* src,
                      float* Cmat, int C, int nb) {
    hipMemsetAsync(Cmat, 0, (size_t)nb * 18 * HW * sizeof(float), stream);
    dim3 grid(36, 1, nb * 8);
    k_off_mfma<<<grid, 256, 0, stream>>>(Ah, Al, src, Cmat, 18, C, 8);
  };
  auto im2col = [&](const float* src, const float* off, int C, int nb, int relu) {
    dim3 grid(36, C * 9 / 144, nb);
    if (off == nullptr)
      k_im2col2<1><<<grid, 256, 0, stream>>>(src, nullptr, cols_h, cols_l, C, relu);
    else
      k_im2col2<0><<<grid, 256, 0, stream>>>(src, off, cols_h, cols_l, C, relu);
  };
  auto im2col_g = [&](const float* src, int C, int Hin, int Win, int Hout,
                      int Wout, int Ksz, int stridec, int pad, int KP, int nb,
                      int relu) {
    dim3 grid((Hout * Wout + 63) / 64, (C + 3) / 4, nb);
    k_im2col_g<<<grid, 256, 0, stream>>>(src, cols_h, cols_l, C, Hin, Win, Hout,
                                         Wout, Ksz, stridec, pad, KP, relu);
  };
  auto gemm_sk = [&](const ushort_t* Ah, const ushort_t* Al, const float* bias,
                     float* Cmat, int M, int N, int KP, int kslices, int relu,
                     int nb) {
    int Nc = ((N + 63) / 64) * 64;
    if (kslices > 1)
      hipMemsetAsync(Cmat, 0, (size_t)nb * M * N * sizeof(float), stream);
    dim3 grid(Nc / 64, (M + 31) / 32, nb * kslices);
    k_gemm_sk<<<grid, 256, 0, stream>>>(Ah, Al, cols_h, cols_l, bias, Cmat, M,
                                        N, Nc, KP, kslices, relu);
  };

  // ---- weight conversions (merged) ----
  k_w2bz3<<<dim3((2359296 + 255) / 256, 1, 3), 256, 0, stream>>>(
      def_w[0], def_w[1], def_w[2], defw_h[0], defw_h[1], defw_h[2],
      defw_l[0], defw_l[1], defw_l[2], 2359296);
  k_w2bz4<<<dim3((82944 + 255) / 256, 1, 4), 256, 0, stream>>>(
      off_w[0], off_w[1], off_w[2], off_w[3], offw_h[0], offw_h[1], offw_h[2],
      offw_h[3], offw_l[0], offw_l[1], offw_l[2], offw_l[3], 82944);
  k_w2b<<<(294912 + 255) / 256, 256, 0, stream>>>(s1w, s1w_h, s1w_l, 294912);
  k_w2b<<<(73728 + 255) / 256, 256, 0, stream>>>(s2w, s2w_h, s2w_l, 73728);
  k_w2b_padz2<<<dim3((64 * 4512 + 255) / 256, 1, 2), 256, 0, stream>>>(
      w0a, w1a, w0a_h, w1a_h, w0a_l, w1a_l, 64, 64, 4425, 4512);
  k_w2b_padz2<<<dim3((64 * 1600 + 255) / 256, 1, 2), 256, 0, stream>>>(
      w0b, w1b, w0b_h, w1b_h, w0b_l, w1b_l, 64, 64, 1600, 1600);
  k_w2b_padz2<<<dim3((256 * 576 + 255) / 256, 1, 2), 256, 0, stream>>>(
      w0c, w1c, w0c_h, w1c_h, w0c_l, w1c_l, 177, 256, 576, 576);
  k_w2b_padz2<<<dim3((64 * 256 + 255) / 256, 1, 2), 256, 0, stream>>>(
      enc0_w, enc1_w, e0w_h, e1w_h, e0w_l, e1w_l, 64, 64, 256, 256);
  k_w2b_pad<<<(576 + 255) / 256, 256, 0, stream>>>(s3w, s3w_h, s3w_l, 1, 576, 576);

  // ---- split + encoders ----
  k_split_xy<<<4608, 256, 0, stream>>>(inp, xf, yf);
  im2col_g(xf, 256, 48, 48, 48, 48, 1, 1, 0, 256, BN, 0);
  gemm_sk(e0w_h, e0w_l, enc0_b, xenc, 64, 2304, 256, 1, 0, BN);
  im2col_g(yf, 256, 48, 48, 48, 48, 1, 1, 0, 256, BN, 0);
  gemm_sk(e1w_h, e1w_l, enc1_b, yenc, 64, 2304, 256, 1, 0, BN);

  // ---- stsn_offset: batch-4 merged chain if scratch allows, else batch-2 ---
  if (big) {
    k_concat512_4<<<(4 * 512 * HW) / 256, 256, 0, stream>>>(xy4, featA);
    float* cur = featA;
    float* nxt = featB;
    for (int i = 0; i < 3; ++i) {
      off_conv(offw_h[i], offw_l[i], cur, offbN, 512, 4);
      im2col(cur, offbN, 512, 4, 0);
      mfma(defw_h[i], defw_l[i], nxt, 512, 4608, 0, 0, 4, 4);
      float* tmp = cur; cur = nxt; nxt = tmp;
    }
    off_conv(offw_h[3], offw_l[3], cur, offsets4, 512, 4);
  } else {
    auto stsn = [&](const float* srcA, const float* srcB, float* offset_out) {
      k_concat512<<<(BN * 512 * HW) / 256, 256, 0, stream>>>(srcA, srcB, featA);
      float* cur = featA;
      float* nxt = featB;
      for (int i = 0; i < 3; ++i) {
        off_conv(offw_h[i], offw_l[i], cur, offbN, 512, BN);
        im2col(cur, offbN, 512, BN, 0);
        mfma(defw_h[i], defw_l[i], nxt, 512, 4608, 0, 0, 4, BN);
        float* tmp = cur; cur = nxt; nxt = tmp;
      }
      off_conv(offw_h[3], offw_l[3], cur, offset_out, 512, BN);
    };
    stsn(xf, yf, offsets4);
    stsn(yf, yf, offsets4 + 2 * 18 * HW);
  }

  // ---- astsn_weight + adaptive deform conv (batch-4) ----
  // relu_in: apply relu while reading fin (fused; fin stored raw).
  auto branch = [&](const float* fin, int relu_in, const ushort_t* wah,
                    const ushort_t* wal, const ushort_t* wbh, const ushort_t* wbl,
                    const ushort_t* wch, const ushort_t* wcl, int Mout,
                    float* fwout) {
    im2col_g(fin, 177, 48, 48, 24, 24, 5, 2, 2, 4512, 4, relu_in);
    gemm_sk(wah, wal, nullptr, wb1, 64, 576, 4512, 8, 0, 4);
    im2col_g(wb1, 64, 24, 24, 12, 12, 5, 2, 2, 1600, 4, 1);
    gemm_sk(wbh, wbl, nullptr, wb2, 64, 144, 1600, 4, 0, 4);
    im2col_g(wb2, 64, 12, 12, 6, 6, 3, 2, 1, 576, 4, 1);
    gemm_sk(wch, wcl, nullptr, wb3, Mout, 36, 576, 2, 0, 4);
    k_mean<<<(4 * Mout + 255) / 256, 256, 0, stream>>>(wb3, fwout, 4 * Mout, 36);
  };

  k_correlation4<<<(4 * 49 * HW + 255) / 256, 256, 0, stream>>>(R0, T0, featw4);
  k_pack_enc4<<<(4 * 64 * HW + 255) / 256, 256, 0, stream>>>(enc4, featw4);
  branch(featw4, 0, w0a_h, w0a_l, w0b_h, w0b_l, w0c_h, w0c_l, 177, fw1);
  k_w2b_fw_pad<<<(4 * 177 * 1632 + 255) / 256, 256, 0, stream>>>(
      wx_w, wx_b, fw1, wxad_h, wxad_l, 177, 1593, 1632, 4);
  im2col_g(featw4, 177, 48, 48, 48, 48, 3, 1, 1, 1632, 4, 0);
  mfma(wxad_h, wxad_l, featw24, 177, 1632, 1, 0, 2, 4);
  // featw24 stored raw; relu fused into branch's first im2col (relu_in=1)
  branch(featw24, 1, w1a_h, w1a_l, w1b_h, w1b_l, w1c_h, w1c_l, 256, fw2);
  k_w2b_fw<<<(4 * 256 * 2304 + 255) / 256, 256, 0, stream>>>(
      wxf_w, wxf_b, fw2, wxf_h, wxf_l, 256, 2304, 4);
  im2col(xy4, offsets4, 256, 4, 0);
  mfma(wxf_h, wxf_l, deform4, 256, 2304, 1, 0, 2, 4);

  // ---- s_net (batch-4); relu fused into the following im2col ----
  im2col(deform4, nullptr, 256, 4, 0);
  mfma(s1w_h, s1w_l, sn1, 128, 2304, 0, 0, 4, 4);
  im2col(sn1, nullptr, 128, 4, 1);
  mfma(s2w_h, s2w_l, sn2, 64, 1152, 0, 0, 4, 4);
  im2col_g(sn2, 64, 48, 48, 48, 48, 3, 1, 1, 576, 4, 1);
  gemm_sk(s3w_h, s3w_l, nullptr, sw4, 1, 2304, 576, 1, 1, 4);

  // ---- blend ----
  k_blend<<<4608, 256, 0, stream>>>(deform4, deform4 + 2 * 256 * HW, sw4,
                                    sw4 + 2 * HW, (float*)d_out);
}

// Round 5
// 2182.037 us; speedup vs baseline: 1.2824x; 1.0017x over previous
//
#include <hip/hip_runtime.h>
#include <stdint.h>

// ---------------------------------------------------------------------------
// Round 18: LDS chunk-plane transpose in all MFMA kernels. Old [row][40ush]
// layout: bank-start (row*20dw)%32, gcd(20,32)=4 => rows r,r+8 collide =>
// 4-way conflict on every fragment b128 read (SQ_LDS_BANK_CONFLICT 1.59e7
// ~= 20% of dispatch cycles). Padding can't fix it (b128 16B-align vs
// stride%4dw!=0 contradiction). New layout As[chunk][row][8]: fragment reads
// at row*16B => bank-start row*4%32, all 32 banks hit exactly 2x per 16-lane
// group = inherent minimum (2-way free, m136). Same data mapping ->
// bit-identical. LDS 30.7->24.6KB. T14 prefetch + fused ReLU kept from r17.
// ---------------------------------------------------------------------------

typedef unsigned short ushort_t;
typedef __attribute__((ext_vector_type(8))) short bf16x8;
typedef __attribute__((ext_vector_type(4))) float f32x4;

#define BN 2
#define HH 48
#define WWD 48
#define HW 2304

__device__ __forceinline__ float b2f(ushort_t h) {
  union { uint32_t u; float f; } v; v.u = ((uint32_t)h) << 16; return v.f;
}
__device__ __forceinline__ ushort_t f2b(float f) {
  union { float f; uint32_t u; } v; v.f = f;
  uint32_t u = v.u;
  uint32_t r = (u + 0x7fffu + ((u >> 16) & 1u)) >> 16;
  return (ushort_t)r;
}
__device__ __forceinline__ void split_bf(float v, ushort_t& hi, ushort_t& lo) {
  hi = f2b(v);
  lo = f2b(v - b2f(hi));
}

// ---------------- elementwise / packing kernels ----------------------------

__global__ void k_split_xy(const float* __restrict__ in, float* __restrict__ xf,
                           float* __restrict__ yf) {
  int idx = blockIdx.x * blockDim.x + threadIdx.x;
  const int tot = BN * 256 * HW;
  if (idx >= tot) return;
  int b = idx / (256 * HW);
  int r = idx - b * (256 * HW);
  xf[idx] = in[(size_t)(2 * b) * (256 * HW) + r];
  yf[idx] = in[(size_t)(2 * b + 1) * (256 * HW) + r];
}

__global__ void k_concat512(const float* __restrict__ a, const float* __restrict__ c2,
                            float* __restrict__ feat) {
  int idx = blockIdx.x * blockDim.x + threadIdx.x;
  const int tot = BN * 512 * HW;
  if (idx >= tot) return;
  int b = idx / (512 * HW);
  int r = idx - b * (512 * HW);
  int c = r / HW;
  int n = r - c * HW;
  feat[idx] = (c < 256) ? a[(b * 256 + c) * HW + n]
                        : c2[(b * 256 + (c - 256)) * HW + n];
}

// batch-4 concat: feat4[bb] = concat(xy4[bb], xy4[2+(bb&1)])
__global__ void k_concat512_4(const float* __restrict__ xy4,
                              float* __restrict__ feat) {
  int idx = blockIdx.x * blockDim.x + threadIdx.x;
  const int tot = 4 * 512 * HW;
  if (idx >= tot) return;
  int bb = idx / (512 * HW);
  int r = idx - bb * (512 * HW);
  int c = r / HW;
  int n = r - c * HW;
  feat[idx] = (c < 256)
                  ? xy4[((size_t)bb * 256 + c) * HW + n]
                  : xy4[((size_t)(2 + (bb & 1)) * 256 + (c - 256)) * HW + n];
}

__global__ void k_mean(const float* __restrict__ src, float* __restrict__ dst,
                       int Mtot, int N) {
  int idx = blockIdx.x * blockDim.x + threadIdx.x;
  if (idx >= Mtot) return;
  const float* p = src + (size_t)idx * N;
  float s = 0.f;
  for (int i = 0; i < N; ++i) s += p[i];
  dst[idx] = s / (float)N;
}

__global__ void k_w2b(const float* __restrict__ w, ushort_t* __restrict__ ohi,
                      ushort_t* __restrict__ olo, int n) {
  int idx = blockIdx.x * blockDim.x + threadIdx.x;
  if (idx < n) split_bf(w[idx], ohi[idx], olo[idx]);
}

// z-merged conversions (same element count per z)
__global__ void k_w2bz3(const float* __restrict__ p0, const float* __restrict__ p1,
                        const float* __restrict__ p2, ushort_t* __restrict__ h0,
                        ushort_t* __restrict__ h1, ushort_t* __restrict__ h2,
                        ushort_t* __restrict__ l0, ushort_t* __restrict__ l1,
                        ushort_t* __restrict__ l2, int n) {
  int idx = blockIdx.x * blockDim.x + threadIdx.x;
  if (idx >= n) return;
  int z = blockIdx.z;
  const float* p = (z == 0) ? p0 : (z == 1) ? p1 : p2;
  ushort_t* h = (z == 0) ? h0 : (z == 1) ? h1 : h2;
  ushort_t* l = (z == 0) ? l0 : (z == 1) ? l1 : l2;
  split_bf(p[idx], h[idx], l[idx]);
}

__global__ void k_w2bz4(const float* __restrict__ p0, const float* __restrict__ p1,
                        const float* __restrict__ p2, const float* __restrict__ p3,
                        ushort_t* __restrict__ h0, ushort_t* __restrict__ h1,
                        ushort_t* __restrict__ h2, ushort_t* __restrict__ h3,
                        ushort_t* __restrict__ l0, ushort_t* __restrict__ l1,
                        ushort_t* __restrict__ l2, ushort_t* __restrict__ l3,
                        int n) {
  int idx = blockIdx.x * blockDim.x + threadIdx.x;
  if (idx >= n) return;
  int z = blockIdx.z;
  const float* p = (z == 0) ? p0 : (z == 1) ? p1 : (z == 2) ? p2 : p3;
  ushort_t* h = (z == 0) ? h0 : (z == 1) ? h1 : (z == 2) ? h2 : h3;
  ushort_t* l = (z == 0) ? l0 : (z == 1) ? l1 : (z == 2) ? l2 : l3;
  split_bf(p[idx], h[idx], l[idx]);
}

__global__ void k_w2b_pad(const float* __restrict__ w, ushort_t* __restrict__ ohi,
                          ushort_t* __restrict__ olo, int M, int K, int Kpad) {
  int idx = blockIdx.x * blockDim.x + threadIdx.x;
  if (idx >= M * Kpad) return;
  int m = idx / Kpad, k = idx - m * Kpad;
  float v = (k < K) ? w[(size_t)m * K + k] : 0.f;
  split_bf(v, ohi[idx], olo[idx]);
}

__global__ void k_w2b_padz2(const float* __restrict__ p0, const float* __restrict__ p1,
                            ushort_t* __restrict__ h0, ushort_t* __restrict__ h1,
                            ushort_t* __restrict__ l0, ushort_t* __restrict__ l1,
                            int M0, int M1, int K, int Kpad) {
  int idx = blockIdx.x * blockDim.x + threadIdx.x;
  int z = blockIdx.z;
  int M = z ? M1 : M0;
  if (idx >= M * Kpad) return;
  int m = idx / Kpad, k = idx - m * Kpad;
  const float* w = z ? p1 : p0;
  ushort_t* h = z ? h1 : h0;
  ushort_t* l = z ? l1 : l0;
  float v = (k < K) ? w[(size_t)m * K + k] : 0.f;
  split_bf(v, h[idx], l[idx]);
}

__global__ void k_w2b_fw(const float* __restrict__ w, const float* __restrict__ wb,
                         const float* __restrict__ fw, ushort_t* __restrict__ ohi,
                         ushort_t* __restrict__ olo, int M, int K, int NB) {
  int idx = blockIdx.x * blockDim.x + threadIdx.x;
  int tot = NB * M * K;
  if (idx >= tot) return;
  int b = idx / (M * K);
  int r = idx - b * (M * K);
  int m = r / K;
  split_bf(fw[b * M + m] * w[r] + wb[r], ohi[idx], olo[idx]);
}

__global__ void k_w2b_fw_pad(const float* __restrict__ w, const float* __restrict__ wb,
                             const float* __restrict__ fw, ushort_t* __restrict__ ohi,
                             ushort_t* __restrict__ olo, int M, int K, int Kpad,
                             int NB) {
  int idx = blockIdx.x * blockDim.x + threadIdx.x;
  int tot = NB * M * Kpad;
  if (idx >= tot) return;
  int b = idx / (M * Kpad);
  int r = idx - b * (M * Kpad);
  int m = r / Kpad;
  int k = r - m * Kpad;
  float v = 0.f;
  if (k < K) v = fw[b * M + m] * w[(size_t)m * K + k] + wb[(size_t)m * K + k];
  split_bf(v, ohi[idx], olo[idx]);
}

__global__ void k_correlation4(const float* __restrict__ R0,
                               const float* __restrict__ T0,
                               float* __restrict__ featw) {
  int idx = blockIdx.x * blockDim.x + threadIdx.x;
  const int tot = 4 * 49 * HW;
  if (idx >= tot) return;
  int n = idx % HW;
  int t = idx / HW;
  int d = t % 49;
  int bb = t / 49;
  int pass = bb >> 1, b = bb & 1;
  int dyi = d / 7, dxi = d - dyi * 7;
  int dy = 2 * (dyi - 3), dx = 2 * (dxi - 3);
  int h = n / WWD, w = n - h * WWD;
  int hb = h + dy, wb = w + dx;
  float s = 0.f;
  if (hb >= 0 && hb < HH && wb >= 0 && wb < WWD) {
    const float* ap = R0 + ((size_t)(b * 2 + pass) * 64) * HW + n;
    const float* bp = T0 + ((size_t)(b * 2 + 1) * 64) * HW + hb * WWD + wb;
#pragma unroll 8
    for (int c = 0; c < 64; ++c) s += ap[(size_t)c * HW] * bp[(size_t)c * HW];
  }
  featw[((size_t)bb * 177 + d) * HW + n] = s * (1.f / 64.f);
}

__global__ void k_pack_enc4(const float* __restrict__ enc4,
                            float* __restrict__ featw) {
  int idx = blockIdx.x * blockDim.x + threadIdx.x;
  const int tot = 4 * 64 * HW;
  if (idx >= tot) return;
  int bb = idx / (64 * HW);
  int r = idx - bb * (64 * HW);
  featw[((size_t)bb * 177 + 49) * HW + r] = enc4[(size_t)bb * 64 * HW + r];
  featw[((size_t)bb * 177 + 113) * HW + r] =
      enc4[(size_t)(2 + (bb & 1)) * 64 * HW + r];
}

// ---------------- im2col v2 (3x3 pad1 on 48x48, deform/zero) ---------------
// relu: apply fmaxf(.,0) to each tap load (== im2col of relu'd map).
template <int ZERO>
__global__ __launch_bounds__(256) void k_im2col2(
    const float* __restrict__ src, const float* __restrict__ off,
    ushort_t* __restrict__ dhi, ushort_t* __restrict__ dlo, int C, int relu) {
  __shared__ ushort_t LH[64][152];
  __shared__ ushort_t LL[64][152];
  const int b = blockIdx.z;
  const int t = threadIdx.x;
  const int nloc = t >> 2;
  const int csub = t & 3;
  const int n = blockIdx.x * 64 + nloc;
  const int c0 = blockIdx.y * 16 + csub * 4;
  const int K = C * 9;
  const int h = n / WWD, w = n - (n / WWD) * WWD;
  const float* sp = src + (size_t)b * C * HW;

  float wgt[9][4];
  int sid[9][4];
  if (ZERO) {
#pragma unroll
    for (int q = 0; q < 9; ++q) {
      int ki = q / 3, kj = q - (q / 3) * 3;
      int y = h - 1 + ki, x = w - 1 + kj;
      bool v = (y >= 0 && y < HH && x >= 0 && x < WWD);
      sid[q][0] = v ? y * WWD + x : 0;
      wgt[q][0] = v ? 1.f : 0.f;
    }
  } else {
#pragma unroll
    for (int q = 0; q < 9; ++q) {
      int ki = q / 3, kj = q - (q / 3) * 3;
      float dy = off[((size_t)(b * 9 + q) * 2 + 0) * HW + n];
      float dx = off[((size_t)(b * 9 + q) * 2 + 1) * HW + n];
      float py = (float)(h - 1 + ki) + dy;
      float px = (float)(w - 1 + kj) + dx;
      float fy = floorf(py), fx = floorf(px);
      float ay = py - fy, ax = px - fx;
      int y0 = (int)fy, x0 = (int)fx;
      int y1 = y0 + 1, x1 = x0 + 1;
      float w00 = (1.f - ay) * (1.f - ax), w01 = (1.f - ay) * ax;
      float w10 = ay * (1.f - ax), w11 = ay * ax;
      bool vy0 = (y0 >= 0 && y0 < HH), vy1 = (y1 >= 0 && y1 < HH);
      bool vx0 = (x0 >= 0 && x0 < WWD), vx1 = (x1 >= 0 && x1 < WWD);
      int cy0 = min(max(y0, 0), HH - 1), cy1 = min(max(y1, 0), HH - 1);
      int cx0 = min(max(x0, 0), WWD - 1), cx1 = min(max(x1, 0), WWD - 1);
      sid[q][0] = cy0 * WWD + cx0;
      sid[q][1] = cy0 * WWD + cx1;
      sid[q][2] = cy1 * WWD + cx0;
      sid[q][3] = cy1 * WWD + cx1;
      wgt[q][0] = (vy0 && vx0) ? w00 : 0.f;
      wgt[q][1] = (vy0 && vx1) ? w01 : 0.f;
      wgt[q][2] = (vy1 && vx0) ? w10 : 0.f;
      wgt[q][3] = (vy1 && vx1) ? w11 : 0.f;
    }
  }

#pragma unroll
  for (int cc = 0; cc < 4; ++cc) {
    int c = c0 + cc;
    const float* s = sp + (size_t)c * HW;
    int kb = (csub * 4 + cc) * 9;
#pragma unroll
    for (int q = 0; q < 9; ++q) {
      float v;
      if (ZERO) {
        float t0 = s[sid[q][0]];
        if (relu) t0 = fmaxf(t0, 0.f);
        v = wgt[q][0] * t0;
      } else {
        float t0 = s[sid[q][0]], t1 = s[sid[q][1]];
        float t2 = s[sid[q][2]], t3 = s[sid[q][3]];
        if (relu) {
          t0 = fmaxf(t0, 0.f); t1 = fmaxf(t1, 0.f);
          t2 = fmaxf(t2, 0.f); t3 = fmaxf(t3, 0.f);
        }
        v = wgt[q][0] * t0 + wgt[q][1] * t1 + wgt[q][2] * t2 + wgt[q][3] * t3;
      }
      ushort_t hi, lo;
      split_bf(v, hi, lo);
      LH[nloc][kb + q] = hi;
      LL[nloc][kb + q] = lo;
    }
  }
  __syncthreads();

  const size_t rowbase = (size_t)b * HW + blockIdx.x * 64;
  const int kt0 = blockIdx.y * 144;
  for (int idx = t; idx < 64 * 18; idx += 256) {
    int r = idx / 18, ch = idx - (idx / 18) * 18;
    uint4 vh = *(const uint4*)&LH[r][ch * 8];
    uint4 vl = *(const uint4*)&LL[r][ch * 8];
    size_t g = (rowbase + r) * K + kt0 + ch * 8;
    *(uint4*)(dhi + g) = vh;
    *(uint4*)(dlo + g) = vl;
  }
}

// ---------------- general im2col (any Ksz<=5/stride/pad, zero-offset) ------
__global__ __launch_bounds__(256) void k_im2col_g(
    const float* __restrict__ src, ushort_t* __restrict__ dhi,
    ushort_t* __restrict__ dlo, int C, int Hin, int Win, int Hout, int Wout,
    int Ksz, int stride, int pad, int KP, int relu) {
  __shared__ ushort_t LH[64][100];
  __shared__ ushort_t LL[64][100];
  const int b = blockIdx.z;
  const int t = threadIdx.x;
  const int nloc = t >> 2, csub = t & 3;
  const int n0 = blockIdx.x * 64;
  const int n = n0 + nloc;
  const int c = blockIdx.y * 4 + csub;
  const int N = Hout * Wout;
  const int K2 = Ksz * Ksz;
  const int h = n / Wout, w = n - (n / Wout) * Wout;
  const bool val = (c < C) && (n < N);
  const float* s = src + ((size_t)b * C + c) * Hin * Win;
  for (int q = 0; q < K2; ++q) {
    int ki = q / Ksz, kj = q - (q / Ksz) * Ksz;
    int y = h * stride + ki - pad, x = w * stride + kj - pad;
    float v = 0.f;
    if (val && y >= 0 && y < Hin && x >= 0 && x < Win) v = s[y * Win + x];
    if (relu) v = fmaxf(v, 0.f);
    ushort_t hi, lo;
    split_bf(v, hi, lo);
    LH[nloc][csub * K2 + q] = hi;
    LL[nloc][csub * K2 + q] = lo;
  }
  __syncthreads();
  const int Nc = gridDim.x * 64;
  const int rl = 4 * K2;
  const int kt0 = blockIdx.y * rl;
  const int nu2 = rl >> 2;
  for (int idx = t; idx < 64 * nu2; idx += 256) {
    int r = idx / nu2, ch = idx - (idx / nu2) * nu2;
    uint2 vh = *(const uint2*)&LH[r][ch * 4];
    uint2 vl = *(const uint2*)&LL[r][ch * 4];
    size_t g = ((size_t)b * Nc + n0 + r) * KP + kt0 + ch * 4;
    *(uint2*)(dhi + g) = vh;
    *(uint2*)(dlo + g) = vl;
  }
}

__global__ void k_blend(const float* __restrict__ d0, const float* __restrict__ d1,
                        const float* __restrict__ sw0, const float* __restrict__ sw1,
                        float* __restrict__ out) {
  int idx = blockIdx.x * blockDim.x + threadIdx.x;
  const int tot = BN * 256 * HW;
  if (idx >= tot) return;
  int b = idx / (256 * HW);
  int n = idx % HW;
  float s0 = sw0[b * HW + n], s1 = sw1[b * HW + n];
  const float eps = 1e-8f;
  float na = fmaxf(fabsf(s0), eps), nb = fmaxf(fabsf(s1), eps);
  float Wx = (s0 * s1) / (na * nb);
  float Wy = (s1 * s1) / (nb * nb);
  float mx = fmaxf(Wx, Wy);
  float e0 = expf(Wx - mx), e1 = expf(Wy - mx);
  float inv = 1.f / (e0 + e1);
  out[idx] = d0[idx] * (e0 * inv) + d1[idx] * (e1 * inv);
}

// ---------------- split-bf16 MFMA GEMM (128x64, chunk-plane LDS) -----------
__global__ __launch_bounds__(256) void k_mfma_nt(
    const ushort_t* __restrict__ Ahi, const ushort_t* __restrict__ Alo,
    const ushort_t* __restrict__ Bhi, const ushort_t* __restrict__ Blo,
    float* __restrict__ Cmat, int M, int N, int K, int abatch, int relu,
    int kslices) {
  // chunk-plane layout: [k-chunk][row][8 ushorts] -> fragment reads at
  // row*16B, bank-start row*4%32, conflict-free (inherent 2-way only).
  __shared__ ushort_t AsH[4][128][8];
  __shared__ ushort_t AsL[4][128][8];
  __shared__ ushort_t BsH[4][64][8];
  __shared__ ushort_t BsL[4][64][8];
  const int zb = blockIdx.z;
  const int b = zb / kslices;
  const int slice = zb - b * kslices;
  const int nch = K >> 5;
  const int cper = (nch + kslices - 1) / kslices;
  const int kbeg = slice * cper * 32;
  const int kend = min(K, kbeg + cper * 32);
  const int n0 = blockIdx.x * 64;
  const int m0 = blockIdx.y * 128;
  const size_t aoff = abatch ? (size_t)b * M * K : (size_t)0;
  const ushort_t* AHp = Ahi + aoff;
  const ushort_t* ALp = Alo + aoff;
  const size_t boff = ((size_t)b * N + n0) * K;
  const ushort_t* BHp = Bhi + boff;
  const ushort_t* BLp = Blo + boff;
  const int t = threadIdx.x;
  const int lane = t & 63;
  const int wv = t >> 6;
  const int wm = wv >> 1, wn = wv & 1;
  const int l15 = lane & 15, quad = lane >> 4;

  const int arow = t >> 1;
  const int acnk = (t & 1) * 2;
  const int brow = t >> 2;
  const int bcnk = t & 3;

  f32x4 acc[4][2];
  const f32x4 z4 = {0.f, 0.f, 0.f, 0.f};
#pragma unroll
  for (int i = 0; i < 4; ++i)
#pragma unroll
    for (int j = 0; j < 2; ++j) acc[i][j] = z4;

  const bool aval = (m0 + arow) < M;
  const uint4 zero16 = {0u, 0u, 0u, 0u};

  // T14: register staging; loads for step k+1 issued during MFMA of step k.
  uint4 ah0, ah1, al0, al1, bh0, bl0;
  auto loadk = [&](int k0) {
    const size_t arow_off = (size_t)(m0 + arow) * K + k0;
    ah0 = aval ? *(const uint4*)(AHp + arow_off + acnk * 8) : zero16;
    ah1 = aval ? *(const uint4*)(AHp + arow_off + (acnk + 1) * 8) : zero16;
    al0 = aval ? *(const uint4*)(ALp + arow_off + acnk * 8) : zero16;
    al1 = aval ? *(const uint4*)(ALp + arow_off + (acnk + 1) * 8) : zero16;
    const size_t brow_off = (size_t)brow * K + k0 + bcnk * 8;
    bh0 = *(const uint4*)(BHp + brow_off);
    bl0 = *(const uint4*)(BLp + brow_off);
  };
  loadk(kbeg);

  for (int k0 = kbeg; k0 < kend; k0 += 32) {
    *(uint4*)&AsH[acnk][arow][0] = ah0;
    *(uint4*)&AsH[acnk + 1][arow][0] = ah1;
    *(uint4*)&AsL[acnk][arow][0] = al0;
    *(uint4*)&AsL[acnk + 1][arow][0] = al1;
    *(uint4*)&BsH[bcnk][brow][0] = bh0;
    *(uint4*)&BsL[bcnk][brow][0] = bl0;
    __syncthreads();

    if (k0 + 32 < kend) loadk(k0 + 32);

    bf16x8 afh[4], afl[4], bfh[2], bfl[2];
#pragma unroll
    for (int mt = 0; mt < 4; ++mt) {
      afh[mt] = *(const bf16x8*)&AsH[quad][wm * 64 + mt * 16 + l15][0];
      afl[mt] = *(const bf16x8*)&AsL[quad][wm * 64 + mt * 16 + l15][0];
    }
#pragma unroll
    for (int nt = 0; nt < 2; ++nt) {
      bfh[nt] = *(const bf16x8*)&BsH[quad][wn * 32 + nt * 16 + l15][0];
      bfl[nt] = *(const bf16x8*)&BsL[quad][wn * 32 + nt * 16 + l15][0];
    }
#pragma unroll
    for (int mt = 0; mt < 4; ++mt)
#pragma unroll
      for (int nt = 0; nt < 2; ++nt) {
        acc[mt][nt] = __builtin_amdgcn_mfma_f32_16x16x32_bf16(
            afh[mt], bfh[nt], acc[mt][nt], 0, 0, 0);
        acc[mt][nt] = __builtin_amdgcn_mfma_f32_16x16x32_bf16(
            afh[mt], bfl[nt], acc[mt][nt], 0, 0, 0);
        acc[mt][nt] = __builtin_amdgcn_mfma_f32_16x16x32_bf16(
            afl[mt], bfh[nt], acc[mt][nt], 0, 0, 0);
      }
    __syncthreads();
  }

  float* Cp = Cmat + (size_t)b * M * N;
#pragma unroll
  for (int mt = 0; mt < 4; ++mt) {
#pragma unroll
    for (int nt = 0; nt < 2; ++nt) {
#pragma unroll
      for (int reg = 0; reg < 4; ++reg) {
        int m = m0 + wm * 64 + mt * 16 + quad * 4 + reg;
        if (m >= M) continue;
        int n = n0 + wn * 32 + nt * 16 + l15;
        if (kslices > 1) {
          atomicAdd(&Cp[(size_t)m * N + n], acc[mt][nt][reg]);
        } else {
          float v = acc[mt][nt][reg];
          if (relu) v = fmaxf(v, 0.f);
          Cp[(size_t)m * N + n] = v;
        }
      }
    }
  }
}

// ---------------- off-conv MFMA: implicit zero-offset im2col (3x3 p1) ------
// lane = pixel staging (coalesced per-(c,q) gathers) + T14 prefetch; LDS in
// chunk-plane layout (conflict-free fragment reads).
__global__ __launch_bounds__(256) void k_off_mfma(
    const ushort_t* __restrict__ Ahi, const ushort_t* __restrict__ Alo,
    const float* __restrict__ src, float* __restrict__ Cmat,
    int M, int C, int kslices) {
  const int N = HW;
  const int K = C * 9;
  __shared__ ushort_t BsH[4][64][8];
  __shared__ ushort_t BsL[4][64][8];
  const int zb = blockIdx.z;
  const int b = zb / kslices;
  const int slice = zb - b * kslices;
  const int Kc = K / kslices;
  const int kbeg = slice * Kc;
  const int n0 = blockIdx.x * 64;
  const int t = threadIdx.x;
  const int lane = t & 63;
  const int wv = t >> 6;
  const int l15 = lane & 15, quad = lane >> 4;
  const float* sp = src + (size_t)b * C * HW;

  const int p = t & 63;
  const int wch = t >> 6;  // k-chunk = wave id (wave-uniform)
  int pix[9];
  float msk[9];
  {
    int n = n0 + p;
    int h = n / WWD, w = n - (n / WWD) * WWD;
#pragma unroll
    for (int q = 0; q < 9; ++q) {
      int ki = q / 3, kj = q - (q / 3) * 3;
      int y = h - 1 + ki, x = w - 1 + kj;
      bool v = (y >= 0 && y < HH && x >= 0 && x < WWD);
      pix[q] = v ? (y * WWD + x) : 0;
      msk[q] = v ? 1.f : 0.f;
    }
  }

  f32x4 acc[2];
  const f32x4 z4 = {0.f, 0.f, 0.f, 0.f};
  acc[0] = z4;
  acc[1] = z4;
  const uint4 zero16 = {0u, 0u, 0u, 0u};

  float pv[8];
  auto gath = [&](int k0) {
    int k = k0 + wch * 8;
    int c = k / 9;
    int q = k - c * 9;
#pragma unroll
    for (int j = 0; j < 8; ++j) {
      pv[j] = msk[q] * sp[(size_t)c * HW + pix[q]];
      ++q;
      if (q == 9) { q = 0; ++c; }
    }
  };
  gath(kbeg);

  for (int k0 = kbeg; k0 < kbeg + Kc; k0 += 32) {
    {
      union { ushort_t u[8]; uint4 v; } ph, pl;
#pragma unroll
      for (int j = 0; j < 8; ++j) split_bf(pv[j], ph.u[j], pl.u[j]);
      *(uint4*)&BsH[wch][p][0] = ph.v;
      *(uint4*)&BsL[wch][p][0] = pl.v;
    }
    __syncthreads();

    if (k0 + 32 < kbeg + Kc) gath(k0 + 32);

    bf16x8 afh[2], afl[2], bfh, bfl;
#pragma unroll
    for (int mt = 0; mt < 2; ++mt) {
      int m = mt * 16 + l15;
      bool v = m < M;
      uint4 ah = v ? *(const uint4*)(Ahi + (size_t)m * K + k0 + quad * 8) : zero16;
      uint4 al = v ? *(const uint4*)(Alo + (size_t)m * K + k0 + quad * 8) : zero16;
      afh[mt] = *(const bf16x8*)&ah;
      afl[mt] = *(const bf16x8*)&al;
    }
    bfh = *(const bf16x8*)&BsH[quad][wv * 16 + l15][0];
    bfl = *(const bf16x8*)&BsL[quad][wv * 16 + l15][0];
#pragma unroll
    for (int mt = 0; mt < 2; ++mt) {
      acc[mt] = __builtin_amdgcn_mfma_f32_16x16x32_bf16(afh[mt], bfh, acc[mt], 0, 0, 0);
      acc[mt] = __builtin_amdgcn_mfma_f32_16x16x32_bf16(afh[mt], bfl, acc[mt], 0, 0, 0);
      acc[mt] = __builtin_amdgcn_mfma_f32_16x16x32_bf16(afl[mt], bfh, acc[mt], 0, 0, 0);
    }
    __syncthreads();
  }

  float* Cp = Cmat + (size_t)b * M * N;
#pragma unroll
  for (int mt = 0; mt < 2; ++mt)
#pragma unroll
    for (int reg = 0; reg < 4; ++reg) {
      int m = mt * 16 + quad * 4 + reg;
      if (m >= M) continue;
      int n = n0 + wv * 16 + l15;
      atomicAdd(&Cp[(size_t)m * N + n], acc[mt][reg]);
    }
}

// ---------------- split-bf16 M32-tile GEMM over cols (chunk-plane LDS) -----
__global__ __launch_bounds__(256) void k_gemm_sk(
    const ushort_t* __restrict__ Ahi, const ushort_t* __restrict__ Alo,
    const ushort_t* __restrict__ Bhi, const ushort_t* __restrict__ Blo,
    const float* __restrict__ bias, float* __restrict__ Cmat,
    int M, int N, int Nc, int KP, int kslices, int relu) {
  __shared__ ushort_t BsH[4][64][8];
  __shared__ ushort_t BsL[4][64][8];
  const int zb = blockIdx.z;
  const int b = zb / kslices;
  const int slice = zb - b * kslices;
  const int nch = KP >> 5;
  const int cper = (nch + kslices - 1) / kslices;
  const int kbeg = slice * cper * 32;
  const int kend = min(KP, kbeg + cper * 32);
  const int n0 = blockIdx.x * 64;
  const int m0 = blockIdx.y * 32;
  const int t = threadIdx.x;
  const int lane = t & 63;
  const int wv = t >> 6;
  const int l15 = lane & 15, quad = lane >> 4;
  const ushort_t* BHp = Bhi + ((size_t)b * Nc + n0) * KP;
  const ushort_t* BLp = Blo + ((size_t)b * Nc + n0) * KP;
  const int srow = t >> 2, scnk = t & 3;

  f32x4 acc[2];
  const f32x4 z4 = {0.f, 0.f, 0.f, 0.f};
  acc[0] = z4;
  acc[1] = z4;
  const uint4 zero16 = {0u, 0u, 0u, 0u};

  uint4 bh, bl;
  auto loadb = [&](int k0) {
    const size_t bo = (size_t)srow * KP + k0 + scnk * 8;
    bh = *(const uint4*)(BHp + bo);
    bl = *(const uint4*)(BLp + bo);
  };
  loadb(kbeg);

  for (int k0 = kbeg; k0 < kend; k0 += 32) {
    *(uint4*)&BsH[scnk][srow][0] = bh;
    *(uint4*)&BsL[scnk][srow][0] = bl;
    __syncthreads();

    if (k0 + 32 < kend) loadb(k0 + 32);

    bf16x8 afh[2], afl[2], bfh, bfl;
#pragma unroll
    for (int mt = 0; mt < 2; ++mt) {
      int m = m0 + mt * 16 + l15;
      bool v = m < M;
      uint4 ah = v ? *(const uint4*)(Ahi + (size_t)m * KP + k0 + quad * 8) : zero16;
      uint4 al = v ? *(const uint4*)(Alo + (size_t)m * KP + k0 + quad * 8) : zero16;
      afh[mt] = *(const bf16x8*)&ah;
      afl[mt] = *(const bf16x8*)&al;
    }
    bfh = *(const bf16x8*)&BsH[quad][wv * 16 + l15][0];
    bfl = *(const bf16x8*)&BsL[quad][wv * 16 + l15][0];
#pragma unroll
    for (int mt = 0; mt < 2; ++mt) {
      acc[mt] = __builtin_amdgcn_mfma_f32_16x16x32_bf16(afh[mt], bfh, acc[mt], 0, 0, 0);
      acc[mt] = __builtin_amdgcn_mfma_f32_16x16x32_bf16(afh[mt], bfl, acc[mt], 0, 0, 0);
      acc[mt] = __builtin_amdgcn_mfma_f32_16x16x32_bf16(afl[mt], bfh, acc[mt], 0, 0, 0);
    }
    __syncthreads();
  }

  float* Cp = Cmat + (size_t)b * M * N;
  const int n = n0 + wv * 16 + l15;
  if (n < N) {
#pragma unroll
    for (int mt = 0; mt < 2; ++mt)
#pragma unroll
      for (int reg = 0; reg < 4; ++reg) {
        int m = m0 + mt * 16 + quad * 4 + reg;
        if (m >= M) continue;
        if (kslices > 1) {
          atomicAdd(&Cp[(size_t)m * N + n], acc[mt][reg]);
        } else {
          float v = acc[mt][reg];
          if (bias != nullptr) v += bias[m];
          if (relu) v = fmaxf(v, 0.f);
          Cp[(size_t)m * N + n] = v;
        }
      }
  }
}

// ---------------------------------------------------------------------------

extern "C" void kernel_launch(void* const* d_in, const int* in_sizes, int n_in,
                              void* d_out, int out_size, void* d_ws, size_t ws_size,
                              hipStream_t stream) {
  (void)in_sizes; (void)n_in; (void)out_size;

  const float* R0     = (const float*)d_in[0];
  const float* T0     = (const float*)d_in[1];
  const float* inp    = (const float*)d_in[2];
  const float* enc0_w = (const float*)d_in[3];
  const float* enc0_b = (const float*)d_in[4];
  const float* enc1_w = (const float*)d_in[5];
  const float* enc1_b = (const float*)d_in[6];
  const float* off_w[4] = {(const float*)d_in[7], (const float*)d_in[8],
                           (const float*)d_in[9], (const float*)d_in[10]};
  const float* def_w[3] = {(const float*)d_in[11], (const float*)d_in[12],
                           (const float*)d_in[13]};
  const float* w0a = (const float*)d_in[14];
  const float* w0b = (const float*)d_in[15];
  const float* w0c = (const float*)d_in[16];
  const float* w1a = (const float*)d_in[17];
  const float* w1b = (const float*)d_in[18];
  const float* w1c = (const float*)d_in[19];
  const float* wx_w  = (const float*)d_in[20];
  const float* wx_b  = (const float*)d_in[21];
  const float* wxf_w = (const float*)d_in[22];
  const float* wxf_b = (const float*)d_in[23];
  const float* s1w = (const float*)d_in[24];
  const float* s2w = (const float*)d_in[25];
  const float* s3w = (const float*)d_in[26];

  float* ws = (float*)d_ws;
  size_t used = 0;
  auto alloc = [&](size_t n) { float* p = ws + used; used += n; return p; };

  // fixed buffers (FIXED = 23,096,832 floats); variable: batch-4 stsn needs
  // 52,070,400 more floats (~301 MB total) -> runtime-gated.
  const size_t FIXED = 23096832, VAR4 = 52070400;
  const bool big = (FIXED + VAR4) * sizeof(float) <= ws_size;

  float* xy4     = alloc(2359296);
  float* xf      = xy4;
  float* yf      = xy4 + 1179648;
  float* enc4    = alloc(589824);
  float* xenc    = enc4;
  float* yenc    = enc4 + 294912;
  float* offsets4= alloc(165888);
  float* featw4  = alloc(1631232);
  float* featw24 = alloc(1631232);
  float* wb1     = alloc(147456);
  float* wb2     = alloc(36864);
  float* wb3     = alloc(36864);
  float* fw1     = alloc(1024);
  float* fw2     = alloc(1024);
  float* deform4 = alloc(2359296);
  float* sn1     = alloc(1179648);
  float* sn2     = alloc(589824);
  float* sw4     = alloc(9216);
  ushort_t *defw_h[3], *defw_l[3];
  for (int i = 0; i < 3; ++i) {
    defw_h[i] = (ushort_t*)alloc(1179648);
    defw_l[i] = (ushort_t*)alloc(1179648);
  }
  ushort_t *offw_h[4], *offw_l[4];
  for (int i = 0; i < 4; ++i) {
    offw_h[i] = (ushort_t*)alloc(41472);
    offw_l[i] = (ushort_t*)alloc(41472);
  }
  ushort_t* wxf_h = (ushort_t*)alloc(1179648);
  ushort_t* wxf_l = (ushort_t*)alloc(1179648);
  ushort_t* s1w_h = (ushort_t*)alloc(147456);
  ushort_t* s1w_l = (ushort_t*)alloc(147456);
  ushort_t* s2w_h = (ushort_t*)alloc(36864);
  ushort_t* s2w_l = (ushort_t*)alloc(36864);
  ushort_t* w0a_h = (ushort_t*)alloc(144384);
  ushort_t* w0a_l = (ushort_t*)alloc(144384);
  ushort_t* w1a_h = (ushort_t*)alloc(144384);
  ushort_t* w1a_l = (ushort_t*)alloc(144384);
  ushort_t* w0b_h = (ushort_t*)alloc(51200);
  ushort_t* w0b_l = (ushort_t*)alloc(51200);
  ushort_t* w1b_h = (ushort_t*)alloc(51200);
  ushort_t* w1b_l = (ushort_t*)alloc(51200);
  ushort_t* w0c_h = (ushort_t*)alloc(50976);
  ushort_t* w0c_l = (ushort_t*)alloc(50976);
  ushort_t* w1c_h = (ushort_t*)alloc(73728);
  ushort_t* w1c_l = (ushort_t*)alloc(73728);
  ushort_t* e0w_h = (ushort_t*)alloc(8192);
  ushort_t* e0w_l = (ushort_t*)alloc(8192);
  ushort_t* e1w_h = (ushort_t*)alloc(8192);
  ushort_t* e1w_l = (ushort_t*)alloc(8192);
  ushort_t* s3w_h = (ushort_t*)alloc(288);
  ushort_t* s3w_l = (ushort_t*)alloc(288);
  ushort_t* wxad_h = (ushort_t*)alloc(577728);
  ushort_t* wxad_l = (ushort_t*)alloc(577728);
  // variable-size stsn buffers
  float* featA = alloc(big ? 4718592 : 2359296);
  float* featB = alloc(big ? 4718592 : 2359296);
  float* offbN = alloc(big ? 165888 : 82944);
  ushort_t* cols_h = (ushort_t*)alloc(big ? 21233664 : 10616832);
  ushort_t* cols_l = (ushort_t*)alloc(big ? 21233664 : 10616832);
  if (used * sizeof(float) > ws_size) return;

  auto mfma = [&](const ushort_t* Ah, const ushort_t* Al, float* Cmat, int M,
                  int K, int abatch, int relu, int ks, int nb) {
    if (ks > 1)
      hipMemsetAsync(Cmat, 0, (size_t)nb * M * 2304 * sizeof(float), stream);
    dim3 grid(2304 / 64, (M + 127) / 128, nb * ks);
    k_mfma_nt<<<grid, 256, 0, stream>>>(Ah, Al, cols_h, cols_l, Cmat, M, 2304, K,
                                        abatch, relu, ks);
  };
  auto off_conv = [&](const ushort_t* Ah, const ushort_t* Al, const float* src,
                      float* Cmat, int C, int nb) {
    hipMemsetAsync(Cmat, 0, (size_t)nb * 18 * HW * sizeof(float), stream);
    dim3 grid(36, 1, nb * 8);
    k_off_mfma<<<grid, 256, 0, stream>>>(Ah, Al, src, Cmat, 18, C, 8);
  };
  auto im2col = [&](const float* src, const float* off, int C, int nb, int relu) {
    dim3 grid(36, C * 9 / 144, nb);
    if (off == nullptr)
      k_im2col2<1><<<grid, 256, 0, stream>>>(src, nullptr, cols_h, cols_l, C, relu);
    else
      k_im2col2<0><<<grid, 256, 0, stream>>>(src, off, cols_h, cols_l, C, relu);
  };
  auto im2col_g = [&](const float* src, int C, int Hin, int Win, int Hout,
                      int Wout, int Ksz, int stridec, int pad, int KP, int nb,
                      int relu) {
    dim3 grid((Hout * Wout + 63) / 64, (C + 3) / 4, nb);
    k_im2col_g<<<grid, 256, 0, stream>>>(src, cols_h, cols_l, C, Hin, Win, Hout,
                                         Wout, Ksz, stridec, pad, KP, relu);
  };
  auto gemm_sk = [&](const ushort_t* Ah, const ushort_t* Al, const float* bias,
                     float* Cmat, int M, int N, int KP, int kslices, int relu,
                     int nb) {
    int Nc = ((N + 63) / 64) * 64;
    if (kslices > 1)
      hipMemsetAsync(Cmat, 0, (size_t)nb * M * N * sizeof(float), stream);
    dim3 grid(Nc / 64, (M + 31) / 32, nb * kslices);
    k_gemm_sk<<<grid, 256, 0, stream>>>(Ah, Al, cols_h, cols_l, bias, Cmat, M,
                                        N, Nc, KP, kslices, relu);
  };

  // ---- weight conversions (merged) ----
  k_w2bz3<<<dim3((2359296 + 255) / 256, 1, 3), 256, 0, stream>>>(
      def_w[0], def_w[1], def_w[2], defw_h[0], defw_h[1], defw_h[2],
      defw_l[0], defw_l[1], defw_l[2], 2359296);
  k_w2bz4<<<dim3((82944 + 255) / 256, 1, 4), 256, 0, stream>>>(
      off_w[0], off_w[1], off_w[2], off_w[3], offw_h[0], offw_h[1], offw_h[2],
      offw_h[3], offw_l[0], offw_l[1], offw_l[2], offw_l[3], 82944);
  k_w2b<<<(294912 + 255) / 256, 256, 0, stream>>>(s1w, s1w_h, s1w_l, 294912);
  k_w2b<<<(73728 + 255) / 256, 256, 0, stream>>>(s2w, s2w_h, s2w_l, 73728);
  k_w2b_padz2<<<dim3((64 * 4512 + 255) / 256, 1, 2), 256, 0, stream>>>(
      w0a, w1a, w0a_h, w1a_h, w0a_l, w1a_l, 64, 64, 4425, 4512);
  k_w2b_padz2<<<dim3((64 * 1600 + 255) / 256, 1, 2), 256, 0, stream>>>(
      w0b, w1b, w0b_h, w1b_h, w0b_l, w1b_l, 64, 64, 1600, 1600);
  k_w2b_padz2<<<dim3((256 * 576 + 255) / 256, 1, 2), 256, 0, stream>>>(
      w0c, w1c, w0c_h, w1c_h, w0c_l, w1c_l, 177, 256, 576, 576);
  k_w2b_padz2<<<dim3((64 * 256 + 255) / 256, 1, 2), 256, 0, stream>>>(
      enc0_w, enc1_w, e0w_h, e1w_h, e0w_l, e1w_l, 64, 64, 256, 256);
  k_w2b_pad<<<(576 + 255) / 256, 256, 0, stream>>>(s3w, s3w_h, s3w_l, 1, 576, 576);

  // ---- split + encoders ----
  k_split_xy<<<4608, 256, 0, stream>>>(inp, xf, yf);
  im2col_g(xf, 256, 48, 48, 48, 48, 1, 1, 0, 256, BN, 0);
  gemm_sk(e0w_h, e0w_l, enc0_b, xenc, 64, 2304, 256, 1, 0, BN);
  im2col_g(yf, 256, 48, 48, 48, 48, 1, 1, 0, 256, BN, 0);
  gemm_sk(e1w_h, e1w_l, enc1_b, yenc, 64, 2304, 256, 1, 0, BN);

  // ---- stsn_offset: batch-4 merged chain if scratch allows, else batch-2 ---
  if (big) {
    k_concat512_4<<<(4 * 512 * HW) / 256, 256, 0, stream>>>(xy4, featA);
    float* cur = featA;
    float* nxt = featB;
    for (int i = 0; i < 3; ++i) {
      off_conv(offw_h[i], offw_l[i], cur, offbN, 512, 4);
      im2col(cur, offbN, 512, 4, 0);
      mfma(defw_h[i], defw_l[i], nxt, 512, 4608, 0, 0, 4, 4);
      float* tmp = cur; cur = nxt; nxt = tmp;
    }
    off_conv(offw_h[3], offw_l[3], cur, offsets4, 512, 4);
  } else {
    auto stsn = [&](const float* srcA, const float* srcB, float* offset_out) {
      k_concat512<<<(BN * 512 * HW) / 256, 256, 0, stream>>>(srcA, srcB, featA);
      float* cur = featA;
      float* nxt = featB;
      for (int i = 0; i < 3; ++i) {
        off_conv(offw_h[i], offw_l[i], cur, offbN, 512, BN);
        im2col(cur, offbN, 512, BN, 0);
        mfma(defw_h[i], defw_l[i], nxt, 512, 4608, 0, 0, 4, BN);
        float* tmp = cur; cur = nxt; nxt = tmp;
      }
      off_conv(offw_h[3], offw_l[3], cur, offset_out, 512, BN);
    };
    stsn(xf, yf, offsets4);
    stsn(yf, yf, offsets4 + 2 * 18 * HW);
  }

  // ---- astsn_weight + adaptive deform conv (batch-4) ----
  // relu_in: apply relu while reading fin (fused; fin stored raw).
  auto branch = [&](const float* fin, int relu_in, const ushort_t* wah,
                    const ushort_t* wal, const ushort_t* wbh, const ushort_t* wbl,
                    const ushort_t* wch, const ushort_t* wcl, int Mout,
                    float* fwout) {
    im2col_g(fin, 177, 48, 48, 24, 24, 5, 2, 2, 4512, 4, relu_in);
    gemm_sk(wah, wal, nullptr, wb1, 64, 576, 4512, 8, 0, 4);
    im2col_g(wb1, 64, 24, 24, 12, 12, 5, 2, 2, 1600, 4, 1);
    gemm_sk(wbh, wbl, nullptr, wb2, 64, 144, 1600, 4, 0, 4);
    im2col_g(wb2, 64, 12, 12, 6, 6, 3, 2, 1, 576, 4, 1);
    gemm_sk(wch, wcl, nullptr, wb3, Mout, 36, 576, 2, 0, 4);
    k_mean<<<(4 * Mout + 255) / 256, 256, 0, stream>>>(wb3, fwout, 4 * Mout, 36);
  };

  k_correlation4<<<(4 * 49 * HW + 255) / 256, 256, 0, stream>>>(R0, T0, featw4);
  k_pack_enc4<<<(4 * 64 * HW + 255) / 256, 256, 0, stream>>>(enc4, featw4);
  branch(featw4, 0, w0a_h, w0a_l, w0b_h, w0b_l, w0c_h, w0c_l, 177, fw1);
  k_w2b_fw_pad<<<(4 * 177 * 1632 + 255) / 256, 256, 0, stream>>>(
      wx_w, wx_b, fw1, wxad_h, wxad_l, 177, 1593, 1632, 4);
  im2col_g(featw4, 177, 48, 48, 48, 48, 3, 1, 1, 1632, 4, 0);
  mfma(wxad_h, wxad_l, featw24, 177, 1632, 1, 0, 2, 4);
  // featw24 stored raw; relu fused into branch's first im2col (relu_in=1)
  branch(featw24, 1, w1a_h, w1a_l, w1b_h, w1b_l, w1c_h, w1c_l, 256, fw2);
  k_w2b_fw<<<(4 * 256 * 2304 + 255) / 256, 256, 0, stream>>>(
      wxf_w, wxf_b, fw2, wxf_h, wxf_l, 256, 2304, 4);
  im2col(xy4, offsets4, 256, 4, 0);
  mfma(wxf_h, wxf_l, deform4, 256, 2304, 1, 0, 2, 4);

  // ---- s_net (batch-4); relu fused into the following im2col ----
  im2col(deform4, nullptr, 256, 4, 0);
  mfma(s1w_h, s1w_l, sn1, 128, 2304, 0, 0, 4, 4);
  im2col(sn1, nullptr, 128, 4, 1);
  mfma(s2w_h, s2w_l, sn2, 64, 1152, 0, 0, 4, 4);
  im2col_g(sn2, 64, 48, 48, 48, 48, 3, 1, 1, 576, 4, 1);
  gemm_sk(s3w_h, s3w_l, nullptr, sw4, 1, 2304, 576, 1, 1, 4);

  // ---- blend ----
  k_blend<<<4608, 256, 0, stream>>>(deform4, deform4 + 2 * 256 * HW, sw4,
                                    sw4 + 2 * HW, (float*)d_out);
}